// Round 1
// baseline (5433.679 us; speedup 1.0000x reference)
//
#include <hip/hip_runtime.h>
#include <math.h>

#define B_ 256
#define S_ 51
#define NN (B_*S_)            // 13056 nodes
#define DEG_ 50
#define EE (NN*DEG_)          // 652800 edges
#define NEG_SLOPE 0.01f
#define EPS_ 1e-12f

#define A_SIZE (NN*128)       // 1671168
#define E_OFF  A_SIZE
#define POS_OFF (A_SIZE + EE)
#define ORI_OFF (POS_OFF + B_*3)

__device__ __forceinline__ float act_apply(float v, int ACT) {
    if (ACT == 1) return fmaxf(v, 0.0f);
    if (ACT == 2) return v > 0.0f ? v : NEG_SLOPE * v;
    return v;
}

// ---------------- generic fp32 tiled GEMM: C = act(A@W + bias [+ C]) ----------------
// 64x64 tile, BK=32, 256 threads, 4x4 per thread.
template<int ACT, int ACC>
__global__ __launch_bounds__(256) void gemm_kernel(
    const float* __restrict__ A, int lda,
    const float* __restrict__ W, int ldw,
    const float* __restrict__ bias,
    float* __restrict__ C, int ldc,
    int M, int K, int N)
{
    __shared__ float As[32][68];   // [kk][r] (A tile transposed), padded
    __shared__ float Ws[32][68];   // [kk][c], padded

    const int tid = threadIdx.x;
    const int tx = tid & 15;       // 16 col-groups
    const int ty = tid >> 4;       // 16 row-groups
    const int m0 = blockIdx.x * 64;
    const int n0 = blockIdx.y * 64;

    float acc[4][4];
#pragma unroll
    for (int i = 0; i < 4; ++i)
#pragma unroll
        for (int j = 0; j < 4; ++j) acc[i][j] = 0.0f;

    const int ktiles = (K + 31) >> 5;
    for (int kt = 0; kt < ktiles; ++kt) {
        const int k0 = kt << 5;
        // stage A tile: 64 rows x 32 k  (coalesced along k)
#pragma unroll
        for (int it = 0; it < 8; ++it) {
            int idx = tid + it * 256;          // 0..2047
            int kk = idx & 31;
            int r  = idx >> 5;
            float v = 0.0f;
            int gr = m0 + r, gk = k0 + kk;
            if (gr < M && gk < K) v = A[(size_t)gr * lda + gk];
            As[kk][r] = v;
        }
        // stage W tile: 32 k x 64 cols (coalesced along cols)
#pragma unroll
        for (int it = 0; it < 8; ++it) {
            int idx = tid + it * 256;
            int c  = idx & 63;
            int kk = idx >> 6;
            float v = 0.0f;
            int gk = k0 + kk, gc = n0 + c;
            if (gk < K && gc < N) v = W[(size_t)gk * ldw + gc];
            Ws[kk][c] = v;
        }
        __syncthreads();
#pragma unroll
        for (int kk = 0; kk < 32; ++kk) {
            float4 av = *(const float4*)&As[kk][ty * 4];
            float4 wv = *(const float4*)&Ws[kk][tx * 4];
            float a[4] = {av.x, av.y, av.z, av.w};
            float w[4] = {wv.x, wv.y, wv.z, wv.w};
#pragma unroll
            for (int i = 0; i < 4; ++i)
#pragma unroll
                for (int j = 0; j < 4; ++j)
                    acc[i][j] = fmaf(a[i], w[j], acc[i][j]);
        }
        __syncthreads();
    }

#pragma unroll
    for (int i = 0; i < 4; ++i) {
        int row = m0 + ty * 4 + i;
        if (row >= M) continue;
#pragma unroll
        for (int j = 0; j < 4; ++j) {
            int col = n0 + tx * 4 + j;
            if (col >= N) continue;
            float v = acc[i][j];
            if (bias) v += bias[col];
            if (ACC) v += C[(size_t)row * ldc + col];
            C[(size_t)row * ldc + col] = act_apply(v, ACT);
        }
    }
}

// ---------------- edge gather: d = xn[src] - xn[dst] ----------------
__global__ __launch_bounds__(256) void gather_diff_kernel(
    const float* __restrict__ xn, const int* __restrict__ src, const int* __restrict__ dst,
    float* __restrict__ dbuf, int e0, int ec)
{
    int idx = blockIdx.x * 256 + threadIdx.x;   // over ec*64 float4s
    if (idx >= ec * 64) return;
    int ei = idx >> 6;
    int f4 = idx & 63;
    int e = e0 + ei;
    const float4* ps = (const float4*)(xn + (size_t)src[e] * 256);
    const float4* pd = (const float4*)(xn + (size_t)dst[e] * 256);
    float4 a = ps[f4], b = pd[f4];
    float4 r;
    r.x = a.x - b.x; r.y = a.y - b.y; r.z = a.z - b.z; r.w = a.w - b.w;
    ((float4*)(dbuf + (size_t)ei * 256))[f4] = r;
}

// ---------------- edge tail: e = sigmoid(s3@ew4+eb4); scatter msg ----------------
__global__ __launch_bounds__(256) void edge_tail_kernel(
    const float* __restrict__ s3, const float* __restrict__ ew4, const float* __restrict__ eb4,
    const float* __restrict__ xn, const int* __restrict__ src, const int* __restrict__ dst,
    float* __restrict__ e_out, float* __restrict__ neigh_sum, float* __restrict__ deg,
    int e0, int ec)
{
    int lane = threadIdx.x & 63;
    int wid  = threadIdx.x >> 6;
    int ei = blockIdx.x * 4 + wid;
    if (ei >= ec) return;
    int e = e0 + ei;
    float v = s3[(size_t)ei * 64 + lane] * ew4[lane];
#pragma unroll
    for (int off = 32; off > 0; off >>= 1) v += __shfl_down(v, off);
    float ev = __shfl(v, 0);
    ev = 1.0f / (1.0f + expf(-(ev + eb4[0])));
    int sn = src[e], dn = dst[e];
    if (lane == 0) {
        e_out[e] = ev;
        atomicAdd(deg + dn, 1.0f);
    }
    const float* xs = xn + (size_t)sn * 256;
    float* ns = neigh_sum + (size_t)dn * 256;
#pragma unroll
    for (int it = 0; it < 4; ++it) {
        int f = it * 64 + lane;
        atomicAdd(ns + f, ev * xs[f]);
    }
}

// ---------------- neigh = neigh_sum / max(deg,1) ----------------
__global__ __launch_bounds__(256) void neigh_div_kernel(
    const float* __restrict__ neigh_sum, const float* __restrict__ deg,
    float* __restrict__ neigh)
{
    int idx = blockIdx.x * 256 + threadIdx.x;
    if (idx >= NN * 256) return;
    float d = fmaxf(deg[idx >> 8], 1.0f);
    neigh[idx] = neigh_sum[idx] / d;
}

// ---------------- pose head: est = A_pre[b,0,:]@decw + decb ----------------
__global__ __launch_bounds__(128) void pose_kernel(
    const float* __restrict__ A_pre, const float* __restrict__ decw,
    const float* __restrict__ decb, float* __restrict__ pos, float* __restrict__ ori)
{
    __shared__ float arow[128];
    int b = blockIdx.x;
    arow[threadIdx.x] = A_pre[(size_t)(b * S_) * 128 + threadIdx.x];
    __syncthreads();
    int t = threadIdx.x;
    if (t < 7) {
        float s = decb[t];
        for (int c = 0; c < 128; ++c) s = fmaf(arow[c], decw[c * 7 + t], s);
        if (t < 3) pos[b * 3 + t] = s;
        else       ori[b * 4 + (t - 3)] = s;
    }
}

// ---------------- A = lrelu(A_pre); A /= max(||A||_S, eps) ----------------
__global__ __launch_bounds__(128) void norm_kernel(
    const float* __restrict__ A_pre, float* __restrict__ out)
{
    int b = blockIdx.x;
    int c = threadIdx.x;
    size_t base = (size_t)b * S_ * 128 + c;
    float ss = 0.0f;
    for (int s = 0; s < S_; ++s) {
        float v = A_pre[base + (size_t)s * 128];
        v = v > 0.0f ? v : NEG_SLOPE * v;
        ss = fmaf(v, v, ss);
    }
    float nrm = fmaxf(sqrtf(ss), EPS_);
    float inv = 1.0f / nrm;
    for (int s = 0; s < S_; ++s) {
        float v = A_pre[base + (size_t)s * 128];
        v = v > 0.0f ? v : NEG_SLOPE * v;
        out[base + (size_t)s * 128] = v * inv;
    }
}

extern "C" void kernel_launch(void* const* d_in, const int* in_sizes, int n_in,
                              void* d_out, int out_size, void* d_ws, size_t ws_size,
                              hipStream_t stream) {
    const float* x      = (const float*)d_in[0];
    const float* x_pose = (const float*)d_in[1];
    const float* m2w1 = (const float*)d_in[2];
    const float* m2b1 = (const float*)d_in[3];
    const float* m2w2 = (const float*)d_in[4];
    const float* m2b2 = (const float*)d_in[5];
    const float* m2w3 = (const float*)d_in[6];
    const float* m2b3 = (const float*)d_in[7];
    const float* m3w1 = (const float*)d_in[8];
    const float* m3b1 = (const float*)d_in[9];
    const float* m3w2 = (const float*)d_in[10];
    const float* m3b2 = (const float*)d_in[11];
    const float* m3w3 = (const float*)d_in[12];
    const float* m3b3 = (const float*)d_in[13];
    const float* encw = (const float*)d_in[14];
    const float* encb = (const float*)d_in[15];
    const float* ew1  = (const float*)d_in[16];
    const float* eb1  = (const float*)d_in[17];
    const float* ew2  = (const float*)d_in[18];
    const float* eb2  = (const float*)d_in[19];
    const float* ew3  = (const float*)d_in[20];
    const float* eb3  = (const float*)d_in[21];
    const float* ew4  = (const float*)d_in[22];
    const float* eb4  = (const float*)d_in[23];
    const float* wself  = (const float*)d_in[24];
    const float* wneigh = (const float*)d_in[25];
    const float* sageb  = (const float*)d_in[26];
    const float* decw = (const float*)d_in[27];
    const float* decb = (const float*)d_in[28];
    const int* esrc = (const int*)d_in[29];
    const int* edst = (const int*)d_in[30];
    float* out = (float*)d_out;

    float* ws = (float*)d_ws;
    size_t off = 0;
    auto alloc = [&](size_t n) { float* p = ws + off; off += n; return p; };
    float* xn        = alloc((size_t)NN * 256);
    float* t1        = alloc((size_t)NN * 256);   // also reused as neigh
    float* t2        = alloc((size_t)NN * 128);
    float* hcat      = alloc((size_t)NN * 128);
    float* p1        = alloc((size_t)NN * 16);
    float* p2        = alloc((size_t)NN * 32);
    float* neigh_sum = alloc((size_t)NN * 256);
    float* deg       = alloc((size_t)NN);          // adjacent to neigh_sum
    float* A_pre     = alloc((size_t)NN * 128);
    size_t node_floats = off;

    // edge chunking (deterministic given ws_size)
    long long avail = (long long)(ws_size / 4) - (long long)node_floats;
    const long long PER_EDGE = 256 + 256 + 128 + 64;   // d, s1, s2, s3
    long long ecmax = avail / PER_EDGE;
    if (ecmax > EE) ecmax = EE;
    if (ecmax < 1) ecmax = 1;
    int nchunk = (int)((EE + ecmax - 1) / ecmax);
    long long ec = (EE + nchunk - 1) / nchunk;
    float* dbuf = ws + off;
    float* s1   = dbuf + ec * 256;
    float* s2   = s1 + ec * 256;
    float* s3   = s2 + ec * 128;

    auto gemm = [&](const float* A, int lda, const float* W, int ldw, const float* bias,
                    float* C, int ldc, int M, int K, int N, int act, int acc) {
        dim3 g((M + 63) / 64, (N + 63) / 64), b(256, 1, 1);
        if (acc == 0 && act == 0)
            gemm_kernel<0,0><<<g, b, 0, stream>>>(A, lda, W, ldw, bias, C, ldc, M, K, N);
        else if (acc == 0 && act == 1)
            gemm_kernel<1,0><<<g, b, 0, stream>>>(A, lda, W, ldw, bias, C, ldc, M, K, N);
        else if (acc == 0 && act == 2)
            gemm_kernel<2,0><<<g, b, 0, stream>>>(A, lda, W, ldw, bias, C, ldc, M, K, N);
        else
            gemm_kernel<0,1><<<g, b, 0, stream>>>(A, lda, W, ldw, bias, C, ldc, M, K, N);
    };

    // zero neigh_sum + deg (adjacent)
    hipMemsetAsync(neigh_sum, 0, ((size_t)NN * 256 + NN) * sizeof(float), stream);

    // node MLPs
    gemm(x,      512, m2w1, 256, m2b1, t1,       256, NN, 512, 256, 1, 0);
    gemm(t1,     256, m2w2, 128, m2b2, t2,       128, NN, 256, 128, 1, 0);
    gemm(t2,     128, m2w3,  64, m2b3, hcat + 0, 128, NN, 128,  64, 1, 0);
    gemm(x_pose,   7, m3w1,  16, m3b1, p1,        16, NN,   7,  16, 1, 0);
    gemm(p1,      16, m3w2,  32, m3b2, p2,        32, NN,  16,  32, 1, 0);
    gemm(p2,      32, m3w3,  64, m3b3, hcat + 64,128, NN,  32,  64, 1, 0);
    gemm(hcat,   128, encw, 256, encb, xn,       256, NN, 128, 256, 1, 0);

    // edge pipeline, chunked
    for (int c = 0; c < nchunk; ++c) {
        long long e0 = (long long)c * ec;
        int ecc = (int)((e0 + ec <= EE) ? ec : (EE - e0));
        int nthr = ecc * 64;
        gather_diff_kernel<<<(nthr + 255) / 256, 256, 0, stream>>>(
            xn, esrc, edst, dbuf, (int)e0, ecc);
        gemm(dbuf, 256, ew1, 256, eb1, s1, 256, ecc, 256, 256, 2, 0);
        gemm(s1,   256, ew2, 128, eb2, s2, 128, ecc, 256, 128, 2, 0);
        gemm(s2,   128, ew3,  64, eb3, s3,  64, ecc, 128,  64, 2, 0);
        edge_tail_kernel<<<(ecc + 3) / 4, 256, 0, stream>>>(
            s3, ew4, eb4, xn, esrc, edst, out + E_OFF, neigh_sum, deg, (int)e0, ecc);
    }

    // neigh = neigh_sum / max(deg,1)  (reuse t1)
    {
        int total = NN * 256;
        neigh_div_kernel<<<(total + 255) / 256, 256, 0, stream>>>(neigh_sum, deg, t1);
    }

    // A_pre = xn@wself + sageb; A_pre += neigh@wneigh
    gemm(xn, 256, wself, 128, sageb,   A_pre, 128, NN, 256, 128, 0, 0);
    gemm(t1, 256, wneigh, 128, nullptr, A_pre, 128, NN, 256, 128, 0, 1);

    // pose head (only s=0 rows)
    pose_kernel<<<B_, 128, 0, stream>>>(A_pre, decw, decb, out + POS_OFF, out + ORI_OFF);

    // A = lrelu(A_pre) normalized over S
    norm_kernel<<<B_, 128, 0, stream>>>(A_pre, out);
}

// Round 3
// 1696.746 us; speedup vs baseline: 3.2024x; 3.2024x over previous
//
#include <hip/hip_runtime.h>
#include <math.h>

#define B_ 256
#define S_ 51
#define NN (B_*S_)            // 13056 nodes
#define DEG_ 50
#define EE (NN*DEG_)          // 652800 edges (multiple of 128)
#define NEG_SLOPE 0.01f
#define EPS_ 1e-12f

#define A_SIZE (NN*128)
#define E_OFF  A_SIZE
#define POS_OFF (A_SIZE + EE)
#define ORI_OFF (POS_OFF + B_*3)

typedef __bf16 bf16x8 __attribute__((ext_vector_type(8)));
typedef float  f32x4  __attribute__((ext_vector_type(4)));

typedef __attribute__((address_space(1))) const void GVoid;
typedef __attribute__((address_space(3))) void LVoid;

__device__ __forceinline__ float act_apply(float v, int ACT) {
    if (ACT == 1) return fmaxf(v, 0.0f);
    if (ACT == 2) return v > 0.0f ? v : NEG_SLOPE * v;
    return v;
}

// ---------------- fp32 tiled GEMM (node pipeline) ----------------
template<int ACT, int ACC>
__global__ __launch_bounds__(256) void gemm_kernel(
    const float* __restrict__ A, int lda,
    const float* __restrict__ W, int ldw,
    const float* __restrict__ bias,
    float* __restrict__ C, int ldc,
    int M, int K, int N)
{
    __shared__ float As[32][68];
    __shared__ float Ws[32][68];

    const int tid = threadIdx.x;
    const int tx = tid & 15;
    const int ty = tid >> 4;
    const int m0 = blockIdx.x * 64;
    const int n0 = blockIdx.y * 64;

    float acc[4][4];
#pragma unroll
    for (int i = 0; i < 4; ++i)
#pragma unroll
        for (int j = 0; j < 4; ++j) acc[i][j] = 0.0f;

    const int ktiles = (K + 31) >> 5;
    for (int kt = 0; kt < ktiles; ++kt) {
        const int k0 = kt << 5;
#pragma unroll
        for (int it = 0; it < 8; ++it) {
            int idx = tid + it * 256;
            int kk = idx & 31;
            int r  = idx >> 5;
            float v = 0.0f;
            int gr = m0 + r, gk = k0 + kk;
            if (gr < M && gk < K) v = A[(size_t)gr * lda + gk];
            As[kk][r] = v;
        }
#pragma unroll
        for (int it = 0; it < 8; ++it) {
            int idx = tid + it * 256;
            int c  = idx & 63;
            int kk = idx >> 6;
            float v = 0.0f;
            int gk = k0 + kk, gc = n0 + c;
            if (gk < K && gc < N) v = W[(size_t)gk * ldw + gc];
            Ws[kk][c] = v;
        }
        __syncthreads();
#pragma unroll
        for (int kk = 0; kk < 32; ++kk) {
            float4 av = *(const float4*)&As[kk][ty * 4];
            float4 wv = *(const float4*)&Ws[kk][tx * 4];
            float a[4] = {av.x, av.y, av.z, av.w};
            float w[4] = {wv.x, wv.y, wv.z, wv.w};
#pragma unroll
            for (int i = 0; i < 4; ++i)
#pragma unroll
                for (int j = 0; j < 4; ++j)
                    acc[i][j] = fmaf(a[i], w[j], acc[i][j]);
        }
        __syncthreads();
    }

#pragma unroll
    for (int i = 0; i < 4; ++i) {
        int row = m0 + ty * 4 + i;
        if (row >= M) continue;
#pragma unroll
        for (int j = 0; j < 4; ++j) {
            int col = n0 + tx * 4 + j;
            if (col >= N) continue;
            float v = acc[i][j];
            if (bias) v += bias[col];
            if (ACC) v += C[(size_t)row * ldc + col];
            C[(size_t)row * ldc + col] = act_apply(v, ACT);
        }
    }
}

// ---------------- weight pack: W[K][N] fp32 -> MFMA-fragment-ordered bf16 ----------------
// flat idx t = ((cf*(K/32) + kt)*64 + lane)*8 + j
// holds W[kt*32 + (lane>>4)*8 + j][cf*16 + (lane&15)]
__global__ __launch_bounds__(256) void pack_w_kernel(
    const float* __restrict__ W, __bf16* __restrict__ Wp, int K, int N)
{
    int t = blockIdx.x * 256 + threadIdx.x;
    if (t >= K * N) return;
    int j    = t & 7;
    int lane = (t >> 3) & 63;
    int rkt  = t >> 9;
    int KT = K >> 5;
    int kt = rkt % KT;
    int cf = rkt / KT;
    int k = kt * 32 + (lane >> 4) * 8 + j;
    int n = cf * 16 + (lane & 15);
    Wp[t] = (__bf16)W[(size_t)k * N + n];
}

// ---------------- bf16 MFMA edge GEMM: C = lrelu(A@W + bias), all bf16 I/O ----------------
// BM=128, 256 threads (4 waves), wave w owns rows w*32..w*32+31.
// LDS A-tile: 128 rows x 4 slots x 16B, slot sl holds kb = sl ^ ((r>>1)&3).
template<int K, int N, int BN>
__global__ __launch_bounds__(256) void edge_gemm_kernel(
    const __bf16* __restrict__ A, const __bf16* __restrict__ Wp,
    const float* __restrict__ bias, __bf16* __restrict__ C)
{
    constexpr int NCF = BN / 16;
    __shared__ __bf16 As[128 * 32];   // 8 KB

    const int tid  = threadIdx.x;
    const int lane = tid & 63;
    const int w    = tid >> 6;
    const int lg   = lane >> 4;   // k-group
    const int li   = lane & 15;
    const int n_blk = blockIdx.x * BN;
    const int m_blk = blockIdx.y * 128;

    f32x4 acc[2][NCF];
#pragma unroll
    for (int mf = 0; mf < 2; ++mf)
#pragma unroll
        for (int cf = 0; cf < NCF; ++cf)
#pragma unroll
            for (int r = 0; r < 4; ++r) acc[mf][cf][r] = 0.0f;

    const __bf16* WpBase = Wp + ((size_t)(n_blk / 16) * (K / 32)) * 512 + (size_t)lane * 8;

    for (int kt = 0; kt < K / 32; ++kt) {
        // ---- stage A tile via global_load_lds (linear dest, inverse-swizzled source) ----
#pragma unroll
        for (int i = 0; i < 2; ++i) {
            int slot0 = i * 256 + w * 64;          // wave-uniform 16B-slot base
            int s  = slot0 + lane;
            int r  = s >> 2;
            int sl = s & 3;
            int kb = sl ^ ((r >> 1) & 3);
            const __bf16* g = A + (size_t)(m_blk + r) * K + kt * 32 + kb * 8;
            __builtin_amdgcn_global_load_lds((GVoid*)g,
                                             (LVoid*)((char*)As + (size_t)slot0 * 16),
                                             16, 0, 0);
        }
        // ---- B fragments: direct global->reg from packed weights (L2-resident) ----
        bf16x8 bf[NCF];
        const __bf16* Wb = WpBase + (size_t)kt * 512;
#pragma unroll
        for (int cf = 0; cf < NCF; ++cf)
            bf[cf] = *(const bf16x8*)(Wb + (size_t)cf * (K / 32) * 512);

        __syncthreads();   // drains vmcnt -> As + bf ready

        // ---- A fragments from LDS (swizzled read) ----
        bf16x8 af[2];
#pragma unroll
        for (int mf = 0; mf < 2; ++mf) {
            int row = w * 32 + mf * 16 + li;
            int sl  = lg ^ ((row >> 1) & 3);
            af[mf] = *(const bf16x8*)((const char*)As + (size_t)row * 64 + sl * 16);
        }
#pragma unroll
        for (int mf = 0; mf < 2; ++mf)
#pragma unroll
            for (int cf = 0; cf < NCF; ++cf)
                acc[mf][cf] = __builtin_amdgcn_mfma_f32_16x16x32_bf16(
                    af[mf], bf[cf], acc[mf][cf], 0, 0, 0);
        __syncthreads();   // As reusable next kt
    }

    // ---- epilogue: bias + lrelu, row-major bf16 store ----
    float bv[NCF];
#pragma unroll
    for (int cf = 0; cf < NCF; ++cf) bv[cf] = bias[n_blk + cf * 16 + li];
#pragma unroll
    for (int mf = 0; mf < 2; ++mf) {
        int row0 = m_blk + w * 32 + mf * 16 + lg * 4;
#pragma unroll
        for (int cf = 0; cf < NCF; ++cf) {
            int col = n_blk + cf * 16 + li;
#pragma unroll
            for (int r = 0; r < 4; ++r) {
                float v = acc[mf][cf][r] + bv[cf];
                v = v > 0.0f ? v : NEG_SLOPE * v;
                C[(size_t)(row0 + r) * N + col] = (__bf16)v;
            }
        }
    }
}

// ---------------- edge gather: dbuf = bf16(xn[src] - xn[dst]), row-major ----------------
__global__ __launch_bounds__(256) void gather_diff_bf16_kernel(
    const float* __restrict__ xn, const int* __restrict__ src, const int* __restrict__ dst,
    __bf16* __restrict__ dbuf, int e0, int ec)
{
    int idx = blockIdx.x * 256 + threadIdx.x;   // ec*32 chunks of 8
    if (idx >= ec * 32) return;
    int ei = idx >> 5;
    int c  = idx & 31;
    int e = e0 + ei;
    const float4* ps = (const float4*)(xn + (size_t)src[e] * 256) + c * 2;
    const float4* pd = (const float4*)(xn + (size_t)dst[e] * 256) + c * 2;
    float4 a0 = ps[0], a1 = ps[1];
    float4 b0 = pd[0], b1 = pd[1];
    bf16x8 o;
    o[0] = (__bf16)(a0.x - b0.x); o[1] = (__bf16)(a0.y - b0.y);
    o[2] = (__bf16)(a0.z - b0.z); o[3] = (__bf16)(a0.w - b0.w);
    o[4] = (__bf16)(a1.x - b1.x); o[5] = (__bf16)(a1.y - b1.y);
    o[6] = (__bf16)(a1.z - b1.z); o[7] = (__bf16)(a1.w - b1.w);
    *(bf16x8*)(dbuf + (size_t)ei * 256 + c * 8) = o;
}

// ---------------- edge tail: e = sigmoid(s3@ew4+eb4); scatter msg ----------------
__global__ __launch_bounds__(256) void edge_tail_kernel(
    const __bf16* __restrict__ s3, const float* __restrict__ ew4, const float* __restrict__ eb4,
    const float* __restrict__ xn, const int* __restrict__ src, const int* __restrict__ dst,
    float* __restrict__ e_out, float* __restrict__ neigh_sum, float* __restrict__ deg,
    int e0, int ec)
{
    int lane = threadIdx.x & 63;
    int wid  = threadIdx.x >> 6;
    int ei = blockIdx.x * 4 + wid;
    if (ei >= ec) return;
    int e = e0 + ei;
    float v = (float)s3[(size_t)ei * 64 + lane] * ew4[lane];
#pragma unroll
    for (int off = 32; off > 0; off >>= 1) v += __shfl_down(v, off);
    float ev = __shfl(v, 0);
    ev = 1.0f / (1.0f + expf(-(ev + eb4[0])));
    int sn = src[e], dn = dst[e];
    if (lane == 0) {
        e_out[e] = ev;
        atomicAdd(deg + dn, 1.0f);
    }
    const float* xs = xn + (size_t)sn * 256;
    float* ns = neigh_sum + (size_t)dn * 256;
#pragma unroll
    for (int it = 0; it < 4; ++it) {
        int f = it * 64 + lane;
        atomicAdd(ns + f, ev * xs[f]);
    }
}

// ---------------- neigh = neigh_sum / max(deg,1) ----------------
__global__ __launch_bounds__(256) void neigh_div_kernel(
    const float* __restrict__ neigh_sum, const float* __restrict__ deg,
    float* __restrict__ neigh)
{
    int idx = blockIdx.x * 256 + threadIdx.x;
    if (idx >= NN * 256) return;
    float d = fmaxf(deg[idx >> 8], 1.0f);
    neigh[idx] = neigh_sum[idx] / d;
}

// ---------------- pose head ----------------
__global__ __launch_bounds__(128) void pose_kernel(
    const float* __restrict__ A_pre, const float* __restrict__ decw,
    const float* __restrict__ decb, float* __restrict__ pos, float* __restrict__ ori)
{
    __shared__ float arow[128];
    int b = blockIdx.x;
    arow[threadIdx.x] = A_pre[(size_t)(b * S_) * 128 + threadIdx.x];
    __syncthreads();
    int t = threadIdx.x;
    if (t < 7) {
        float s = decb[t];
        for (int c = 0; c < 128; ++c) s = fmaf(arow[c], decw[c * 7 + t], s);
        if (t < 3) pos[b * 3 + t] = s;
        else       ori[b * 4 + (t - 3)] = s;
    }
}

// ---------------- A = lrelu(A_pre); A /= max(||A||_S, eps) ----------------
__global__ __launch_bounds__(128) void norm_kernel(
    const float* __restrict__ A_pre, float* __restrict__ out)
{
    int b = blockIdx.x;
    int c = threadIdx.x;
    size_t base = (size_t)b * S_ * 128 + c;
    float ss = 0.0f;
    for (int s = 0; s < S_; ++s) {
        float v = A_pre[base + (size_t)s * 128];
        v = v > 0.0f ? v : NEG_SLOPE * v;
        ss = fmaf(v, v, ss);
    }
    float nrm = fmaxf(sqrtf(ss), EPS_);
    float inv = 1.0f / nrm;
    for (int s = 0; s < S_; ++s) {
        float v = A_pre[base + (size_t)s * 128];
        v = v > 0.0f ? v : NEG_SLOPE * v;
        out[base + (size_t)s * 128] = v * inv;
    }
}

extern "C" void kernel_launch(void* const* d_in, const int* in_sizes, int n_in,
                              void* d_out, int out_size, void* d_ws, size_t ws_size,
                              hipStream_t stream) {
    const float* x      = (const float*)d_in[0];
    const float* x_pose = (const float*)d_in[1];
    const float* m2w1 = (const float*)d_in[2];
    const float* m2b1 = (const float*)d_in[3];
    const float* m2w2 = (const float*)d_in[4];
    const float* m2b2 = (const float*)d_in[5];
    const float* m2w3 = (const float*)d_in[6];
    const float* m2b3 = (const float*)d_in[7];
    const float* m3w1 = (const float*)d_in[8];
    const float* m3b1 = (const float*)d_in[9];
    const float* m3w2 = (const float*)d_in[10];
    const float* m3b2 = (const float*)d_in[11];
    const float* m3w3 = (const float*)d_in[12];
    const float* m3b3 = (const float*)d_in[13];
    const float* encw = (const float*)d_in[14];
    const float* encb = (const float*)d_in[15];
    const float* ew1  = (const float*)d_in[16];
    const float* eb1  = (const float*)d_in[17];
    const float* ew2  = (const float*)d_in[18];
    const float* eb2  = (const float*)d_in[19];
    const float* ew3  = (const float*)d_in[20];
    const float* eb3  = (const float*)d_in[21];
    const float* ew4  = (const float*)d_in[22];
    const float* eb4  = (const float*)d_in[23];
    const float* wself  = (const float*)d_in[24];
    const float* wneigh = (const float*)d_in[25];
    const float* sageb  = (const float*)d_in[26];
    const float* decw = (const float*)d_in[27];
    const float* decb = (const float*)d_in[28];
    const int* esrc = (const int*)d_in[29];
    const int* edst = (const int*)d_in[30];
    float* out = (float*)d_out;

    float* ws = (float*)d_ws;
    size_t off = 0;
    auto alloc = [&](size_t n) { float* p = ws + off; off += n; return p; };
    float* xn        = alloc((size_t)NN * 256);
    float* t1        = alloc((size_t)NN * 256);
    float* t2        = alloc((size_t)NN * 128);
    float* hcat      = alloc((size_t)NN * 128);
    float* p1        = alloc((size_t)NN * 16);
    float* p2        = alloc((size_t)NN * 32);
    float* neigh_sum = alloc((size_t)NN * 256);
    float* deg       = alloc((size_t)NN);
    float* A_pre     = alloc((size_t)NN * 128);
    size_t node_floats = off;

    // bf16 region: packed weights then edge buffers
    __bf16* wp1 = (__bf16*)((char*)d_ws + node_floats * 4);
    __bf16* wp2 = wp1 + 256 * 256;
    __bf16* wp3 = wp2 + 256 * 128;
    const size_t pack_elems = 256 * 256 + 256 * 128 + 128 * 64;

    long long avail_bytes = (long long)ws_size - (long long)node_floats * 4
                          - (long long)pack_elems * 2;
    const long long PER_EDGE_B = (256 + 256 + 128 + 64) * 2;   // 1408 bytes
    long long ecmax = avail_bytes / PER_EDGE_B;
    ecmax = (ecmax / 128) * 128;
    if (ecmax > EE) ecmax = EE;
    if (ecmax < 128) ecmax = 128;
    int nchunk = (int)((EE + ecmax - 1) / ecmax);
    long long ec = ((EE + nchunk - 1) / nchunk + 127) / 128 * 128;

    __bf16* dbuf = wp3 + 128 * 64;
    __bf16* s1   = dbuf + ec * 256;
    __bf16* s2   = s1 + ec * 256;
    __bf16* s3   = s2 + ec * 128;

    auto gemm = [&](const float* A, int lda, const float* W, int ldw, const float* bias,
                    float* C, int ldc, int M, int K, int N, int act, int acc) {
        dim3 g((M + 63) / 64, (N + 63) / 64), b(256, 1, 1);
        if (acc == 0 && act == 0)
            gemm_kernel<0,0><<<g, b, 0, stream>>>(A, lda, W, ldw, bias, C, ldc, M, K, N);
        else if (acc == 0 && act == 1)
            gemm_kernel<1,0><<<g, b, 0, stream>>>(A, lda, W, ldw, bias, C, ldc, M, K, N);
        else if (acc == 0 && act == 2)
            gemm_kernel<2,0><<<g, b, 0, stream>>>(A, lda, W, ldw, bias, C, ldc, M, K, N);
        else
            gemm_kernel<0,1><<<g, b, 0, stream>>>(A, lda, W, ldw, bias, C, ldc, M, K, N);
    };

    hipMemsetAsync(neigh_sum, 0, ((size_t)NN * 256 + NN) * sizeof(float), stream);

    // pack edge weights to bf16 MFMA layout
    pack_w_kernel<<<(256 * 256 + 255) / 256, 256, 0, stream>>>(ew1, wp1, 256, 256);
    pack_w_kernel<<<(256 * 128 + 255) / 256, 256, 0, stream>>>(ew2, wp2, 256, 128);
    pack_w_kernel<<<(128 * 64 + 255) / 256, 256, 0, stream>>>(ew3, wp3, 128, 64);

    // node MLPs (fp32)
    gemm(x,      512, m2w1, 256, m2b1, t1,       256, NN, 512, 256, 1, 0);
    gemm(t1,     256, m2w2, 128, m2b2, t2,       128, NN, 256, 128, 1, 0);
    gemm(t2,     128, m2w3,  64, m2b3, hcat + 0, 128, NN, 128,  64, 1, 0);
    gemm(x_pose,   7, m3w1,  16, m3b1, p1,        16, NN,   7,  16, 1, 0);
    gemm(p1,      16, m3w2,  32, m3b2, p2,        32, NN,  16,  32, 1, 0);
    gemm(p2,      32, m3w3,  64, m3b3, hcat + 64,128, NN,  32,  64, 1, 0);
    gemm(hcat,   128, encw, 256, encb, xn,       256, NN, 128, 256, 1, 0);

    // edge pipeline, chunked, bf16 MFMA
    for (int c = 0; c < nchunk; ++c) {
        long long e0 = (long long)c * ec;
        int ecc = (int)((e0 + ec <= EE) ? ec : (EE - e0));   // multiple of 128
        gather_diff_bf16_kernel<<<(ecc * 32 + 255) / 256, 256, 0, stream>>>(
            xn, esrc, edst, dbuf, (int)e0, ecc);
        dim3 b(256, 1, 1);
        edge_gemm_kernel<256, 256, 128><<<dim3(2, ecc / 128), b, 0, stream>>>(dbuf, wp1, eb1, s1);
        edge_gemm_kernel<256, 128, 128><<<dim3(1, ecc / 128), b, 0, stream>>>(s1,   wp2, eb2, s2);
        edge_gemm_kernel<128,  64,  64><<<dim3(1, ecc / 128), b, 0, stream>>>(s2,   wp3, eb3, s3);
        edge_tail_kernel<<<(ecc + 3) / 4, 256, 0, stream>>>(
            s3, ew4, eb4, xn, esrc, edst, out + E_OFF, neigh_sum, deg, (int)e0, ecc);
    }

    // neigh = neigh_sum / max(deg,1)  (reuse t1)
    {
        int total = NN * 256;
        neigh_div_kernel<<<(total + 255) / 256, 256, 0, stream>>>(neigh_sum, deg, t1);
    }

    // A_pre = xn@wself + sageb; A_pre += neigh@wneigh  (fp32)
    gemm(xn, 256, wself, 128, sageb,   A_pre, 128, NN, 256, 128, 0, 0);
    gemm(t1, 256, wneigh, 128, nullptr, A_pre, 128, NN, 256, 128, 0, 1);

    pose_kernel<<<B_, 128, 0, stream>>>(A_pre, decw, decb, out + POS_OFF, out + ORI_OFF);
    norm_kernel<<<B_, 128, 0, stream>>>(A_pre, out);
}

// Round 6
// 1524.916 us; speedup vs baseline: 3.5633x; 1.1127x over previous
//
#include <hip/hip_runtime.h>
#include <math.h>

#define B_ 256
#define S_ 51
#define NN (B_*S_)            // 13056 nodes = 102*128
#define DEG_ 50
#define EE (NN*DEG_)          // 652800 edges
#define NEG_SLOPE 0.01f
#define EPS_ 1e-12f

#define A_SIZE (NN*128)
#define E_OFF  A_SIZE
#define POS_OFF (A_SIZE + EE)
#define ORI_OFF (POS_OFF + B_*3)

typedef __bf16 bf16x8 __attribute__((ext_vector_type(8)));
typedef __bf16 bf16x4 __attribute__((ext_vector_type(4)));
typedef float  f32x4  __attribute__((ext_vector_type(4)));

typedef __attribute__((address_space(1))) const void GVoid;
typedef __attribute__((address_space(3))) void LVoid;

__device__ __forceinline__ float act_apply(float v, int ACT) {
    if (ACT == 1) return fmaxf(v, 0.0f);
    if (ACT == 2) return v > 0.0f ? v : NEG_SLOPE * v;
    return v;
}

// ---------------- fp32 tiled GEMM (tiny pose layers only) ----------------
template<int ACT, int ACC>
__global__ __launch_bounds__(256) void gemm_kernel(
    const float* __restrict__ A, int lda,
    const float* __restrict__ W, int ldw,
    const float* __restrict__ bias,
    float* __restrict__ C, int ldc,
    int M, int K, int N)
{
    __shared__ float As[32][68];
    __shared__ float Ws[32][68];

    const int tid = threadIdx.x;
    const int tx = tid & 15;
    const int ty = tid >> 4;
    const int m0 = blockIdx.x * 64;
    const int n0 = blockIdx.y * 64;

    float acc[4][4];
#pragma unroll
    for (int i = 0; i < 4; ++i)
#pragma unroll
        for (int j = 0; j < 4; ++j) acc[i][j] = 0.0f;

    const int ktiles = (K + 31) >> 5;
    for (int kt = 0; kt < ktiles; ++kt) {
        const int k0 = kt << 5;
#pragma unroll
        for (int it = 0; it < 8; ++it) {
            int idx = tid + it * 256;
            int kk = idx & 31;
            int r  = idx >> 5;
            float v = 0.0f;
            int gr = m0 + r, gk = k0 + kk;
            if (gr < M && gk < K) v = A[(size_t)gr * lda + gk];
            As[kk][r] = v;
        }
#pragma unroll
        for (int it = 0; it < 8; ++it) {
            int idx = tid + it * 256;
            int c  = idx & 63;
            int kk = idx >> 6;
            float v = 0.0f;
            int gk = k0 + kk, gc = n0 + c;
            if (gk < K && gc < N) v = W[(size_t)gk * ldw + gc];
            Ws[kk][c] = v;
        }
        __syncthreads();
#pragma unroll
        for (int kk = 0; kk < 32; ++kk) {
            float4 av = *(const float4*)&As[kk][ty * 4];
            float4 wv = *(const float4*)&Ws[kk][tx * 4];
            float a[4] = {av.x, av.y, av.z, av.w};
            float w[4] = {wv.x, wv.y, wv.z, wv.w};
#pragma unroll
            for (int i = 0; i < 4; ++i)
#pragma unroll
                for (int j = 0; j < 4; ++j)
                    acc[i][j] = fmaf(a[i], w[j], acc[i][j]);
        }
        __syncthreads();
    }

#pragma unroll
    for (int i = 0; i < 4; ++i) {
        int row = m0 + ty * 4 + i;
        if (row >= M) continue;
#pragma unroll
        for (int j = 0; j < 4; ++j) {
            int col = n0 + tx * 4 + j;
            if (col >= N) continue;
            float v = acc[i][j];
            if (bias) v += bias[col];
            if (ACC) v += C[(size_t)row * ldc + col];
            C[(size_t)row * ldc + col] = act_apply(v, ACT);
        }
    }
}

// ---------------- weight pack: W[K][N] fp32 -> MFMA-fragment-ordered bf16 ----------------
// flat idx t = ((cf*(K/32) + kt)*64 + lane)*8 + j
// holds W[kt*32 + (lane>>4)*8 + j][cf*16 + (lane&15)]
__global__ __launch_bounds__(256) void pack_w_kernel(
    const float* __restrict__ W, __bf16* __restrict__ Wp, int K, int N)
{
    int t = blockIdx.x * 256 + threadIdx.x;
    if (t >= K * N) return;
    int j    = t & 7;
    int lane = (t >> 3) & 63;
    int rkt  = t >> 9;
    int KT = K >> 5;
    int kt = rkt % KT;
    int cf = rkt / KT;
    int k = kt * 32 + (lane >> 4) * 8 + j;
    int n = cf * 16 + (lane & 15);
    Wp[t] = (__bf16)W[(size_t)k * N + n];
}

// same, but hi/lo split pair (fp32-equivalent precision)
__global__ __launch_bounds__(256) void pack_w2_kernel(
    const float* __restrict__ W, __bf16* __restrict__ Wph, __bf16* __restrict__ Wpl,
    int K, int N)
{
    int t = blockIdx.x * 256 + threadIdx.x;
    if (t >= K * N) return;
    int j    = t & 7;
    int lane = (t >> 3) & 63;
    int rkt  = t >> 9;
    int KT = K >> 5;
    int kt = rkt % KT;
    int cf = rkt / KT;
    int k = kt * 32 + (lane >> 4) * 8 + j;
    int n = cf * 16 + (lane & 15);
    float v = W[(size_t)k * N + n];
    __bf16 h = (__bf16)v;
    Wph[t] = h;
    Wpl[t] = (__bf16)(v - (float)h);
}

// ---------------- bf16 MFMA edge GEMM (round-2 proven): C = lrelu(A@W+bias) ----------------
template<int K, int N, int BN>
__global__ __launch_bounds__(256) void edge_gemm_kernel(
    const __bf16* __restrict__ A, const __bf16* __restrict__ Wp,
    const float* __restrict__ bias, __bf16* __restrict__ C)
{
    constexpr int NCF = BN / 16;
    __shared__ __bf16 As[128 * 32];   // 8 KB

    const int tid  = threadIdx.x;
    const int lane = tid & 63;
    const int w    = tid >> 6;
    const int lg   = lane >> 4;
    const int li   = lane & 15;
    const int n_blk = blockIdx.x * BN;
    const int m_blk = blockIdx.y * 128;

    f32x4 acc[2][NCF];
#pragma unroll
    for (int mf = 0; mf < 2; ++mf)
#pragma unroll
        for (int cf = 0; cf < NCF; ++cf)
#pragma unroll
            for (int r = 0; r < 4; ++r) acc[mf][cf][r] = 0.0f;

    const __bf16* WpBase = Wp + ((size_t)(n_blk / 16) * (K / 32)) * 512 + (size_t)lane * 8;

    for (int kt = 0; kt < K / 32; ++kt) {
#pragma unroll
        for (int i = 0; i < 2; ++i) {
            int slot0 = i * 256 + w * 64;
            int s  = slot0 + lane;
            int r  = s >> 2;
            int sl = s & 3;
            int kb = sl ^ ((r >> 1) & 3);
            const __bf16* g = A + (size_t)(m_blk + r) * K + kt * 32 + kb * 8;
            __builtin_amdgcn_global_load_lds((GVoid*)g,
                                             (LVoid*)((char*)As + (size_t)slot0 * 16),
                                             16, 0, 0);
        }
        bf16x8 bf[NCF];
        const __bf16* Wb = WpBase + (size_t)kt * 512;
#pragma unroll
        for (int cf = 0; cf < NCF; ++cf)
            bf[cf] = *(const bf16x8*)(Wb + (size_t)cf * (K / 32) * 512);

        __syncthreads();

        bf16x8 af[2];
#pragma unroll
        for (int mf = 0; mf < 2; ++mf) {
            int row = w * 32 + mf * 16 + li;
            int sl  = lg ^ ((row >> 1) & 3);
            af[mf] = *(const bf16x8*)((const char*)As + (size_t)row * 64 + sl * 16);
        }
#pragma unroll
        for (int mf = 0; mf < 2; ++mf)
#pragma unroll
            for (int cf = 0; cf < NCF; ++cf)
                acc[mf][cf] = __builtin_amdgcn_mfma_f32_16x16x32_bf16(
                    af[mf], bf[cf], acc[mf][cf], 0, 0, 0);
        __syncthreads();
    }

    float bv[NCF];
#pragma unroll
    for (int cf = 0; cf < NCF; ++cf) bv[cf] = bias[n_blk + cf * 16 + li];
#pragma unroll
    for (int mf = 0; mf < 2; ++mf) {
        int row0 = m_blk + w * 32 + mf * 16 + lg * 4;
#pragma unroll
        for (int cf = 0; cf < NCF; ++cf) {
            int col = n_blk + cf * 16 + li;
#pragma unroll
            for (int r = 0; r < 4; ++r) {
                float v = acc[mf][cf][r] + bv[cf];
                v = v > 0.0f ? v : NEG_SLOPE * v;
                C[(size_t)(row0 + r) * N + col] = (__bf16)v;
            }
        }
    }
}

// ---------------- split-bf16 MFMA GEMM (fp32-equivalent precision, node path) ----------------
// A = Ah + Al (hi/lo bf16), W = Wh + Wl (packed hi/lo). 3 MFMA: ah*wh + ah*wl + al*wh.
// OUT bit0: write fp32 Cf; bit1: write hi/lo Ch/Cl. ACC: Cf += (before act).
// Same staging/swizzle structure as edge_gemm_kernel (proven), duplicated for the lo tile.
template<int K, int BN, int ACT, int OUT, int ACC>
__global__ __launch_bounds__(256) void mmx_kernel(
    const __bf16* __restrict__ Ah, const __bf16* __restrict__ Al,
    const __bf16* __restrict__ Wph, const __bf16* __restrict__ Wpl,
    const float* __restrict__ bias,
    float* __restrict__ Cf, __bf16* __restrict__ Ch, __bf16* __restrict__ Cl, int ldc)
{
    constexpr int NCF = BN / 16;
    __shared__ __bf16 AsH[128 * 32];
    __shared__ __bf16 AsL[128 * 32];

    const int tid  = threadIdx.x;
    const int lane = tid & 63;
    const int w    = tid >> 6;
    const int lg   = lane >> 4;
    const int li   = lane & 15;
    const int n_blk = blockIdx.x * BN;
    const int m_blk = blockIdx.y * 128;

    f32x4 acc[2][NCF];
#pragma unroll
    for (int mf = 0; mf < 2; ++mf)
#pragma unroll
        for (int cf = 0; cf < NCF; ++cf)
#pragma unroll
            for (int r = 0; r < 4; ++r) acc[mf][cf][r] = 0.0f;

    const size_t wbase = ((size_t)(n_blk / 16) * (K / 32)) * 512 + (size_t)lane * 8;

    for (int kt = 0; kt < K / 32; ++kt) {
#pragma unroll
        for (int i = 0; i < 2; ++i) {
            int slot0 = i * 256 + w * 64;
            int s  = slot0 + lane;
            int r  = s >> 2;
            int sl = s & 3;
            int kb = sl ^ ((r >> 1) & 3);
            size_t goff = (size_t)(m_blk + r) * K + kt * 32 + kb * 8;
            __builtin_amdgcn_global_load_lds((GVoid*)(Ah + goff),
                                             (LVoid*)((char*)AsH + (size_t)slot0 * 16),
                                             16, 0, 0);
            __builtin_amdgcn_global_load_lds((GVoid*)(Al + goff),
                                             (LVoid*)((char*)AsL + (size_t)slot0 * 16),
                                             16, 0, 0);
        }
        bf16x8 bfh[NCF], bfl[NCF];
        const size_t wo = wbase + (size_t)kt * 512;
#pragma unroll
        for (int cf = 0; cf < NCF; ++cf) {
            size_t o = wo + (size_t)cf * (K / 32) * 512;
            bfh[cf] = *(const bf16x8*)(Wph + o);
            bfl[cf] = *(const bf16x8*)(Wpl + o);
        }

        __syncthreads();

        bf16x8 afh[2], afl[2];
#pragma unroll
        for (int mf = 0; mf < 2; ++mf) {
            int row = w * 32 + mf * 16 + li;
            int sl  = lg ^ ((row >> 1) & 3);
            afh[mf] = *(const bf16x8*)((const char*)AsH + (size_t)row * 64 + sl * 16);
            afl[mf] = *(const bf16x8*)((const char*)AsL + (size_t)row * 64 + sl * 16);
        }
#pragma unroll
        for (int mf = 0; mf < 2; ++mf)
#pragma unroll
            for (int cf = 0; cf < NCF; ++cf) {
                acc[mf][cf] = __builtin_amdgcn_mfma_f32_16x16x32_bf16(
                    afh[mf], bfh[cf], acc[mf][cf], 0, 0, 0);
                acc[mf][cf] = __builtin_amdgcn_mfma_f32_16x16x32_bf16(
                    afh[mf], bfl[cf], acc[mf][cf], 0, 0, 0);
                acc[mf][cf] = __builtin_amdgcn_mfma_f32_16x16x32_bf16(
                    afl[mf], bfh[cf], acc[mf][cf], 0, 0, 0);
            }
        __syncthreads();
    }

    float bv[NCF];
#pragma unroll
    for (int cf = 0; cf < NCF; ++cf) bv[cf] = bias ? bias[n_blk + cf * 16 + li] : 0.0f;
#pragma unroll
    for (int mf = 0; mf < 2; ++mf) {
        int row0 = m_blk + w * 32 + mf * 16 + lg * 4;
#pragma unroll
        for (int cf = 0; cf < NCF; ++cf) {
            int col = n_blk + cf * 16 + li;
#pragma unroll
            for (int r = 0; r < 4; ++r) {
                float v = acc[mf][cf][r] + bv[cf];
                size_t idx = (size_t)(row0 + r) * ldc + col;
                if (ACC) v += Cf[idx];
                v = act_apply(v, ACT);
                if (OUT & 1) Cf[idx] = v;
                if (OUT & 2) {
                    __bf16 h = (__bf16)v;
                    Ch[idx] = h;
                    Cl[idx] = (__bf16)(v - (float)h);
                }
            }
        }
    }
}

// ---------------- fp32 -> hi/lo bf16 split (8 elems/thread) ----------------
__global__ __launch_bounds__(256) void split_bf16_kernel(
    const float* __restrict__ in, __bf16* __restrict__ hi, __bf16* __restrict__ lo, int n8)
{
    int i = blockIdx.x * 256 + threadIdx.x;
    if (i >= n8) return;
    const float4* p = (const float4*)in + (size_t)i * 2;
    float4 a = p[0], b = p[1];
    float v[8] = {a.x, a.y, a.z, a.w, b.x, b.y, b.z, b.w};
    bf16x8 oh, ol;
#pragma unroll
    for (int j = 0; j < 8; ++j) {
        __bf16 h = (__bf16)v[j];
        oh[j] = h;
        ol[j] = (__bf16)(v[j] - (float)h);
    }
    *(bf16x8*)(hi + (size_t)i * 8) = oh;
    *(bf16x8*)(lo + (size_t)i * 8) = ol;
}

// ---------------- edge gather (round-2 proven): dbuf = bf16(xn[src]-xn[dst]), fp32 xn ----------------
__global__ __launch_bounds__(256) void gather_diff_kernel(
    const float* __restrict__ xn, const int* __restrict__ src, const int* __restrict__ dst,
    __bf16* __restrict__ dbuf, int e0, int ec)
{
    int idx = blockIdx.x * 256 + threadIdx.x;   // ec*32 chunks of 8
    if (idx >= ec * 32) return;
    int ei = idx >> 5;
    int c  = idx & 31;
    int e = e0 + ei;
    const float4* ps = (const float4*)(xn + (size_t)src[e] * 256) + c * 2;
    const float4* pd = (const float4*)(xn + (size_t)dst[e] * 256) + c * 2;
    float4 a0 = ps[0], a1 = ps[1];
    float4 b0 = pd[0], b1 = pd[1];
    bf16x8 o;
    o[0] = (__bf16)(a0.x - b0.x); o[1] = (__bf16)(a0.y - b0.y);
    o[2] = (__bf16)(a0.z - b0.z); o[3] = (__bf16)(a0.w - b0.w);
    o[4] = (__bf16)(a1.x - b1.x); o[5] = (__bf16)(a1.y - b1.y);
    o[6] = (__bf16)(a1.z - b1.z); o[7] = (__bf16)(a1.w - b1.w);
    *(bf16x8*)(dbuf + (size_t)ei * 256 + c * 8) = o;
}

// ---------------- edge tail: e = sigmoid(s3@ew4+eb4); scatter msg ----------------
__global__ __launch_bounds__(256) void edge_tail_kernel(
    const __bf16* __restrict__ s3, const float* __restrict__ ew4, const float* __restrict__ eb4,
    const float* __restrict__ xn, const int* __restrict__ src, const int* __restrict__ dst,
    float* __restrict__ e_out, float* __restrict__ neigh_sum, float* __restrict__ deg,
    int e0, int ec)
{
    int lane = threadIdx.x & 63;
    int wid  = threadIdx.x >> 6;
    int ei = blockIdx.x * 4 + wid;
    if (ei >= ec) return;
    int e = e0 + ei;
    float v = (float)s3[(size_t)ei * 64 + lane] * ew4[lane];
#pragma unroll
    for (int off = 32; off > 0; off >>= 1) v += __shfl_down(v, off);
    float ev = __shfl(v, 0);
    ev = 1.0f / (1.0f + expf(-(ev + eb4[0])));
    int sn = src[e], dn = dst[e];
    if (lane == 0) {
        e_out[e] = ev;
        atomicAdd(deg + dn, 1.0f);
    }
    const float* xs = xn + (size_t)sn * 256;
    float* ns = neigh_sum + (size_t)dn * 256;
#pragma unroll
    for (int it = 0; it < 4; ++it) {
        int f = it * 64 + lane;
        atomicAdd(ns + f, ev * xs[f]);
    }
}

// ---------------- neigh hi/lo = split(neigh_sum / max(deg,1)) ----------------
__global__ __launch_bounds__(256) void neigh_div2_kernel(
    const float* __restrict__ neigh_sum, const float* __restrict__ deg,
    __bf16* __restrict__ nh, __bf16* __restrict__ nl)
{
    int idx = blockIdx.x * 256 + threadIdx.x;   // NN*64, 4 elems each
    if (idx >= NN * 64) return;
    float d = fmaxf(deg[idx >> 6], 1.0f);
    float4 v = ((const float4*)neigh_sum)[idx];
    float vv[4] = {v.x / d, v.y / d, v.z / d, v.w / d};
    bf16x4 oh, ol;
#pragma unroll
    for (int j = 0; j < 4; ++j) {
        __bf16 h = (__bf16)vv[j];
        oh[j] = h;
        ol[j] = (__bf16)(vv[j] - (float)h);
    }
    *((bf16x4*)nh + idx) = oh;
    *((bf16x4*)nl + idx) = ol;
}

// ---------------- pose head ----------------
__global__ __launch_bounds__(128) void pose_kernel(
    const float* __restrict__ A_pre, const float* __restrict__ decw,
    const float* __restrict__ decb, float* __restrict__ pos, float* __restrict__ ori)
{
    __shared__ float arow[128];
    int b = blockIdx.x;
    arow[threadIdx.x] = A_pre[(size_t)(b * S_) * 128 + threadIdx.x];
    __syncthreads();
    int t = threadIdx.x;
    if (t < 7) {
        float s = decb[t];
        for (int c = 0; c < 128; ++c) s = fmaf(arow[c], decw[c * 7 + t], s);
        if (t < 3) pos[b * 3 + t] = s;
        else       ori[b * 4 + (t - 3)] = s;
    }
}

// ---------------- A = lrelu(A_pre); A /= max(||A||_S, eps) ----------------
__global__ __launch_bounds__(128) void norm_kernel(
    const float* __restrict__ A_pre, float* __restrict__ out)
{
    int b = blockIdx.x;
    int c = threadIdx.x;
    size_t base = (size_t)b * S_ * 128 + c;
    float ss = 0.0f;
    for (int s = 0; s < S_; ++s) {
        float v = A_pre[base + (size_t)s * 128];
        v = v > 0.0f ? v : NEG_SLOPE * v;
        ss = fmaf(v, v, ss);
    }
    float nrm = fmaxf(sqrtf(ss), EPS_);
    float inv = 1.0f / nrm;
    for (int s = 0; s < S_; ++s) {
        float v = A_pre[base + (size_t)s * 128];
        v = v > 0.0f ? v : NEG_SLOPE * v;
        out[base + (size_t)s * 128] = v * inv;
    }
}

extern "C" void kernel_launch(void* const* d_in, const int* in_sizes, int n_in,
                              void* d_out, int out_size, void* d_ws, size_t ws_size,
                              hipStream_t stream) {
    const float* x      = (const float*)d_in[0];
    const float* x_pose = (const float*)d_in[1];
    const float* m2w1 = (const float*)d_in[2];
    const float* m2b1 = (const float*)d_in[3];
    const float* m2w2 = (const float*)d_in[4];
    const float* m2b2 = (const float*)d_in[5];
    const float* m2w3 = (const float*)d_in[6];
    const float* m2b3 = (const float*)d_in[7];
    const float* m3w1 = (const float*)d_in[8];
    const float* m3b1 = (const float*)d_in[9];
    const float* m3w2 = (const float*)d_in[10];
    const float* m3b2 = (const float*)d_in[11];
    const float* m3w3 = (const float*)d_in[12];
    const float* m3b3 = (const float*)d_in[13];
    const float* encw = (const float*)d_in[14];
    const float* encb = (const float*)d_in[15];
    const float* ew1  = (const float*)d_in[16];
    const float* eb1  = (const float*)d_in[17];
    const float* ew2  = (const float*)d_in[18];
    const float* eb2  = (const float*)d_in[19];
    const float* ew3  = (const float*)d_in[20];
    const float* eb3  = (const float*)d_in[21];
    const float* ew4  = (const float*)d_in[22];
    const float* eb4  = (const float*)d_in[23];
    const float* wself  = (const float*)d_in[24];
    const float* wneigh = (const float*)d_in[25];
    const float* sageb  = (const float*)d_in[26];
    const float* decw = (const float*)d_in[27];
    const float* decb = (const float*)d_in[28];
    const int* esrc = (const int*)d_in[29];
    const int* edst = (const int*)d_in[30];
    float* out = (float*)d_out;

    // ---- workspace layout (byte allocator, 16B aligned) ----
    char* base = (char*)d_ws;
    size_t off = 0;
    auto alloc = [&](size_t bytes) { char* p = base + off; off += (bytes + 15) & ~15ULL; return p; };
    // fp32 buffers
    float* xn        = (float*)alloc((size_t)NN * 256 * 4);
    float* neigh_sum = (float*)alloc((size_t)NN * 256 * 4);
    float* deg       = (float*)alloc((size_t)NN * 4);
    float* A_pre     = (float*)alloc((size_t)NN * 128 * 4);
    float* p1        = (float*)alloc((size_t)NN * 16 * 4);
    float* p2        = (float*)alloc((size_t)NN * 32 * 4);
    // hi/lo bf16 activation pairs (node path, fp32-equivalent precision)
    __bf16* xh   = (__bf16*)alloc((size_t)NN * 512 * 2);
    __bf16* xl   = (__bf16*)alloc((size_t)NN * 512 * 2);
    __bf16* t1h  = (__bf16*)alloc((size_t)NN * 256 * 2);
    __bf16* t1l  = (__bf16*)alloc((size_t)NN * 256 * 2);
    __bf16* t2h  = (__bf16*)alloc((size_t)NN * 128 * 2);
    __bf16* t2l  = (__bf16*)alloc((size_t)NN * 128 * 2);
    __bf16* hch  = (__bf16*)alloc((size_t)NN * 128 * 2);
    __bf16* hcl  = (__bf16*)alloc((size_t)NN * 128 * 2);
    __bf16* p2h  = (__bf16*)alloc((size_t)NN * 32 * 2);
    __bf16* p2l  = (__bf16*)alloc((size_t)NN * 32 * 2);
    __bf16* xnh  = (__bf16*)alloc((size_t)NN * 256 * 2);
    __bf16* xnl  = (__bf16*)alloc((size_t)NN * 256 * 2);
    __bf16* ngh  = (__bf16*)alloc((size_t)NN * 256 * 2);
    __bf16* ngl  = (__bf16*)alloc((size_t)NN * 256 * 2);
    // packed weights: node (hi/lo pairs)
    __bf16* wpn1h = (__bf16*)alloc((size_t)512 * 256 * 2);
    __bf16* wpn1l = (__bf16*)alloc((size_t)512 * 256 * 2);
    __bf16* wpn2h = (__bf16*)alloc((size_t)256 * 128 * 2);
    __bf16* wpn2l = (__bf16*)alloc((size_t)256 * 128 * 2);
    __bf16* wpn3h = (__bf16*)alloc((size_t)128 * 64 * 2);
    __bf16* wpn3l = (__bf16*)alloc((size_t)128 * 64 * 2);
    __bf16* wpp3h = (__bf16*)alloc((size_t)32 * 64 * 2);
    __bf16* wpp3l = (__bf16*)alloc((size_t)32 * 64 * 2);
    __bf16* wpenh = (__bf16*)alloc((size_t)128 * 256 * 2);
    __bf16* wpenl = (__bf16*)alloc((size_t)128 * 256 * 2);
    __bf16* wpsfh = (__bf16*)alloc((size_t)256 * 128 * 2);
    __bf16* wpsfl = (__bf16*)alloc((size_t)256 * 128 * 2);
    __bf16* wpngh = (__bf16*)alloc((size_t)256 * 128 * 2);
    __bf16* wpngl = (__bf16*)alloc((size_t)256 * 128 * 2);
    // packed weights: edge (single bf16, proven)
    __bf16* wpe1 = (__bf16*)alloc((size_t)256 * 256 * 2);
    __bf16* wpe2 = (__bf16*)alloc((size_t)256 * 128 * 2);
    __bf16* wpe3 = (__bf16*)alloc((size_t)128 * 64 * 2);

    // edge chunking (deterministic given ws_size)
    long long avail_bytes = (long long)ws_size - (long long)off;
    const long long PER_EDGE_B = (256 + 256 + 128 + 64) * 2;   // 1408 bytes
    long long ecmax = avail_bytes / PER_EDGE_B;
    ecmax = (ecmax / 128) * 128;
    if (ecmax > EE) ecmax = EE;
    if (ecmax < 128) ecmax = 128;
    int nchunk = (int)((EE + ecmax - 1) / ecmax);
    long long ec = ((EE + nchunk - 1) / nchunk + 127) / 128 * 128;

    __bf16* dbuf = (__bf16*)(base + off);
    __bf16* s1   = dbuf + ec * 256;
    __bf16* s2   = s1 + ec * 256;
    __bf16* s3   = s2 + ec * 128;

    hipMemsetAsync(neigh_sum, 0, (size_t)NN * 256 * sizeof(float), stream);
    hipMemsetAsync(deg, 0, (size_t)NN * sizeof(float), stream);

    // pack node weights (hi/lo)
    pack_w2_kernel<<<(512*256+255)/256, 256, 0, stream>>>(m2w1, wpn1h, wpn1l, 512, 256);
    pack_w2_kernel<<<(256*128+255)/256, 256, 0, stream>>>(m2w2, wpn2h, wpn2l, 256, 128);
    pack_w2_kernel<<<(128*64 +255)/256, 256, 0, stream>>>(m2w3, wpn3h, wpn3l, 128, 64);
    pack_w2_kernel<<<(32*64  +255)/256, 256, 0, stream>>>(m3w3, wpp3h, wpp3l, 32, 64);
    pack_w2_kernel<<<(128*256+255)/256, 256, 0, stream>>>(encw, wpenh, wpenl, 128, 256);
    pack_w2_kernel<<<(256*128+255)/256, 256, 0, stream>>>(wself, wpsfh, wpsfl, 256, 128);
    pack_w2_kernel<<<(256*128+255)/256, 256, 0, stream>>>(wneigh, wpngh, wpngl, 256, 128);
    // pack edge weights (single bf16)
    pack_w_kernel<<<(256*256+255)/256, 256, 0, stream>>>(ew1, wpe1, 256, 256);
    pack_w_kernel<<<(256*128+255)/256, 256, 0, stream>>>(ew2, wpe2, 256, 128);
    pack_w_kernel<<<(128*64 +255)/256, 256, 0, stream>>>(ew3, wpe3, 128, 64);

    // split x -> hi/lo
    split_bf16_kernel<<<(NN*512/8 + 255)/256, 256, 0, stream>>>(x, xh, xl, NN*512/8);

    const dim3 blk(256, 1, 1);
    const int MB = NN / 128;   // 102

    // node MLP branch (split-bf16 MFMA, fp32-equivalent)
    mmx_kernel<512,64,1,2,0><<<dim3(4, MB), blk, 0, stream>>>(xh, xl, wpn1h, wpn1l, m2b1, nullptr, t1h, t1l, 256);
    mmx_kernel<256,64,1,2,0><<<dim3(2, MB), blk, 0, stream>>>(t1h, t1l, wpn2h, wpn2l, m2b2, nullptr, t2h, t2l, 128);
    mmx_kernel<128,64,1,2,0><<<dim3(1, MB), blk, 0, stream>>>(t2h, t2l, wpn3h, wpn3l, m2b3, nullptr, hch, hcl, 128);

    // pose branch: tiny fp32 layers, split, then MFMA layer 3 into hcat cols 64..127
    gemm_kernel<1,0><<<dim3((NN+63)/64, 1), blk, 0, stream>>>(x_pose, 7,  m3w1, 16, m3b1, p1, 16, NN, 7, 16);
    gemm_kernel<1,0><<<dim3((NN+63)/64, 1), blk, 0, stream>>>(p1,    16,  m3w2, 32, m3b2, p2, 32, NN, 16, 32);
    split_bf16_kernel<<<(NN*32/8 + 255)/256, 256, 0, stream>>>(p2, p2h, p2l, NN*32/8);
    mmx_kernel< 32,64,1,2,0><<<dim3(1, MB), blk, 0, stream>>>(p2h, p2l, wpp3h, wpp3l, m3b3, nullptr, hch + 64, hcl + 64, 128);

    // encoder: fp32 xn (for gather/scatter) + hi/lo xn (for SAGE)
    mmx_kernel<128,64,1,3,0><<<dim3(4, MB), blk, 0, stream>>>(hch, hcl, wpenh, wpenl, encb, xn, xnh, xnl, 256);

    // edge pipeline, chunked, bf16 MFMA (round-2 proven form)
    for (int c = 0; c < nchunk; ++c) {
        long long e0 = (long long)c * ec;
        int ecc = (int)((e0 + ec <= EE) ? ec : (EE - e0));   // multiple of 128
        gather_diff_kernel<<<(ecc * 32 + 255) / 256, 256, 0, stream>>>(
            xn, esrc, edst, dbuf, (int)e0, ecc);
        edge_gemm_kernel<256, 256, 128><<<dim3(2, ecc / 128), blk, 0, stream>>>(dbuf, wpe1, eb1, s1);
        edge_gemm_kernel<256, 128, 128><<<dim3(1, ecc / 128), blk, 0, stream>>>(s1,   wpe2, eb2, s2);
        edge_gemm_kernel<128,  64,  64><<<dim3(1, ecc / 128), blk, 0, stream>>>(s2,   wpe3, eb3, s3);
        edge_tail_kernel<<<(ecc + 3) / 4, 256, 0, stream>>>(
            s3, ew4, eb4, xn, esrc, edst, out + E_OFF, neigh_sum, deg, (int)e0, ecc);
    }

    // neigh hi/lo = split(neigh_sum / max(deg,1))
    neigh_div2_kernel<<<(NN*64 + 255)/256, 256, 0, stream>>>(neigh_sum, deg, ngh, ngl);

    // SAGE: A_pre = xn@wself + sageb; A_pre += neigh@wneigh  (split MFMA, fp32 out)
    mmx_kernel<256,64,0,1,0><<<dim3(2, MB), blk, 0, stream>>>(xnh, xnl, wpsfh, wpsfl, sageb,  A_pre, nullptr, nullptr, 128);
    mmx_kernel<256,64,0,1,1><<<dim3(2, MB), blk, 0, stream>>>(ngh, ngl, wpngh, wpngl, nullptr, A_pre, nullptr, nullptr, 128);

    pose_kernel<<<B_, 128, 0, stream>>>(A_pre, decw, decb, out + POS_OFF, out + ORI_OFF);
    norm_kernel<<<B_, 128, 0, stream>>>(A_pre, out);
}

// Round 7
// 1172.737 us; speedup vs baseline: 4.6333x; 1.3003x over previous
//
#include <hip/hip_runtime.h>
#include <math.h>

#define B_ 256
#define S_ 51
#define NN (B_*S_)            // 13056 nodes = 102*128
#define DEG_ 50
#define EE (NN*DEG_)          // 652800 edges
#define NEG_SLOPE 0.01f
#define EPS_ 1e-12f

#define A_SIZE (NN*128)
#define E_OFF  A_SIZE
#define POS_OFF (A_SIZE + EE)
#define ORI_OFF (POS_OFF + B_*3)

typedef __bf16 bf16x8 __attribute__((ext_vector_type(8)));
typedef __bf16 bf16x4 __attribute__((ext_vector_type(4)));
typedef float  f32x4  __attribute__((ext_vector_type(4)));

typedef __attribute__((address_space(1))) const void GVoid;
typedef __attribute__((address_space(3))) void LVoid;

__device__ __forceinline__ float act_apply(float v, int ACT) {
    if (ACT == 1) return fmaxf(v, 0.0f);
    if (ACT == 2) return v > 0.0f ? v : NEG_SLOPE * v;
    return v;
}

// ---------------- fp32 tiled GEMM (tiny pose layers only) ----------------
template<int ACT, int ACC>
__global__ __launch_bounds__(256) void gemm_kernel(
    const float* __restrict__ A, int lda,
    const float* __restrict__ W, int ldw,
    const float* __restrict__ bias,
    float* __restrict__ C, int ldc,
    int M, int K, int N)
{
    __shared__ float As[32][68];
    __shared__ float Ws[32][68];

    const int tid = threadIdx.x;
    const int tx = tid & 15;
    const int ty = tid >> 4;
    const int m0 = blockIdx.x * 64;
    const int n0 = blockIdx.y * 64;

    float acc[4][4];
#pragma unroll
    for (int i = 0; i < 4; ++i)
#pragma unroll
        for (int j = 0; j < 4; ++j) acc[i][j] = 0.0f;

    const int ktiles = (K + 31) >> 5;
    for (int kt = 0; kt < ktiles; ++kt) {
        const int k0 = kt << 5;
#pragma unroll
        for (int it = 0; it < 8; ++it) {
            int idx = tid + it * 256;
            int kk = idx & 31;
            int r  = idx >> 5;
            float v = 0.0f;
            int gr = m0 + r, gk = k0 + kk;
            if (gr < M && gk < K) v = A[(size_t)gr * lda + gk];
            As[kk][r] = v;
        }
#pragma unroll
        for (int it = 0; it < 8; ++it) {
            int idx = tid + it * 256;
            int c  = idx & 63;
            int kk = idx >> 6;
            float v = 0.0f;
            int gk = k0 + kk, gc = n0 + c;
            if (gk < K && gc < N) v = W[(size_t)gk * ldw + gc];
            Ws[kk][c] = v;
        }
        __syncthreads();
#pragma unroll
        for (int kk = 0; kk < 32; ++kk) {
            float4 av = *(const float4*)&As[kk][ty * 4];
            float4 wv = *(const float4*)&Ws[kk][tx * 4];
            float a[4] = {av.x, av.y, av.z, av.w};
            float w[4] = {wv.x, wv.y, wv.z, wv.w};
#pragma unroll
            for (int i = 0; i < 4; ++i)
#pragma unroll
                for (int j = 0; j < 4; ++j)
                    acc[i][j] = fmaf(a[i], w[j], acc[i][j]);
        }
        __syncthreads();
    }

#pragma unroll
    for (int i = 0; i < 4; ++i) {
        int row = m0 + ty * 4 + i;
        if (row >= M) continue;
#pragma unroll
        for (int j = 0; j < 4; ++j) {
            int col = n0 + tx * 4 + j;
            if (col >= N) continue;
            float v = acc[i][j];
            if (bias) v += bias[col];
            if (ACC) v += C[(size_t)row * ldc + col];
            C[(size_t)row * ldc + col] = act_apply(v, ACT);
        }
    }
}

// ---------------- weight pack: W[K][N] fp32 -> MFMA-fragment-ordered bf16 ----------------
__global__ __launch_bounds__(256) void pack_w_kernel(
    const float* __restrict__ W, __bf16* __restrict__ Wp, int K, int N)
{
    int t = blockIdx.x * 256 + threadIdx.x;
    if (t >= K * N) return;
    int j    = t & 7;
    int lane = (t >> 3) & 63;
    int rkt  = t >> 9;
    int KT = K >> 5;
    int kt = rkt % KT;
    int cf = rkt / KT;
    int k = kt * 32 + (lane >> 4) * 8 + j;
    int n = cf * 16 + (lane & 15);
    Wp[t] = (__bf16)W[(size_t)k * N + n];
}

// same, but hi/lo split pair (fp32-equivalent precision)
__global__ __launch_bounds__(256) void pack_w2_kernel(
    const float* __restrict__ W, __bf16* __restrict__ Wph, __bf16* __restrict__ Wpl,
    int K, int N)
{
    int t = blockIdx.x * 256 + threadIdx.x;
    if (t >= K * N) return;
    int j    = t & 7;
    int lane = (t >> 3) & 63;
    int rkt  = t >> 9;
    int KT = K >> 5;
    int kt = rkt % KT;
    int cf = rkt / KT;
    int k = kt * 32 + (lane >> 4) * 8 + j;
    int n = cf * 16 + (lane & 15);
    float v = W[(size_t)k * N + n];
    __bf16 h = (__bf16)v;
    Wph[t] = h;
    Wpl[t] = (__bf16)(v - (float)h);
}

// ---------------- bf16 MFMA edge GEMM (proven): C = lrelu(A@W+bias) ----------------
template<int K, int N, int BN>
__global__ __launch_bounds__(256) void edge_gemm_kernel(
    const __bf16* __restrict__ A, const __bf16* __restrict__ Wp,
    const float* __restrict__ bias, __bf16* __restrict__ C)
{
    constexpr int NCF = BN / 16;
    __shared__ __bf16 As[128 * 32];   // 8 KB

    const int tid  = threadIdx.x;
    const int lane = tid & 63;
    const int w    = tid >> 6;
    const int lg   = lane >> 4;
    const int li   = lane & 15;
    const int n_blk = blockIdx.x * BN;
    const int m_blk = blockIdx.y * 128;

    f32x4 acc[2][NCF];
#pragma unroll
    for (int mf = 0; mf < 2; ++mf)
#pragma unroll
        for (int cf = 0; cf < NCF; ++cf)
#pragma unroll
            for (int r = 0; r < 4; ++r) acc[mf][cf][r] = 0.0f;

    const __bf16* WpBase = Wp + ((size_t)(n_blk / 16) * (K / 32)) * 512 + (size_t)lane * 8;

    for (int kt = 0; kt < K / 32; ++kt) {
#pragma unroll
        for (int i = 0; i < 2; ++i) {
            int slot0 = i * 256 + w * 64;
            int s  = slot0 + lane;
            int r  = s >> 2;
            int sl = s & 3;
            int kb = sl ^ ((r >> 1) & 3);
            const __bf16* g = A + (size_t)(m_blk + r) * K + kt * 32 + kb * 8;
            __builtin_amdgcn_global_load_lds((GVoid*)g,
                                             (LVoid*)((char*)As + (size_t)slot0 * 16),
                                             16, 0, 0);
        }
        bf16x8 bf[NCF];
        const __bf16* Wb = WpBase + (size_t)kt * 512;
#pragma unroll
        for (int cf = 0; cf < NCF; ++cf)
            bf[cf] = *(const bf16x8*)(Wb + (size_t)cf * (K / 32) * 512);

        __syncthreads();

        bf16x8 af[2];
#pragma unroll
        for (int mf = 0; mf < 2; ++mf) {
            int row = w * 32 + mf * 16 + li;
            int sl  = lg ^ ((row >> 1) & 3);
            af[mf] = *(const bf16x8*)((const char*)As + (size_t)row * 64 + sl * 16);
        }
#pragma unroll
        for (int mf = 0; mf < 2; ++mf)
#pragma unroll
            for (int cf = 0; cf < NCF; ++cf)
                acc[mf][cf] = __builtin_amdgcn_mfma_f32_16x16x32_bf16(
                    af[mf], bf[cf], acc[mf][cf], 0, 0, 0);
        __syncthreads();
    }

    float bv[NCF];
#pragma unroll
    for (int cf = 0; cf < NCF; ++cf) bv[cf] = bias[n_blk + cf * 16 + li];
#pragma unroll
    for (int mf = 0; mf < 2; ++mf) {
        int row0 = m_blk + w * 32 + mf * 16 + lg * 4;
#pragma unroll
        for (int cf = 0; cf < NCF; ++cf) {
            int col = n_blk + cf * 16 + li;
#pragma unroll
            for (int r = 0; r < 4; ++r) {
                float v = acc[mf][cf][r] + bv[cf];
                v = v > 0.0f ? v : NEG_SLOPE * v;
                C[(size_t)(row0 + r) * N + col] = (__bf16)v;
            }
        }
    }
}

// ---------------- split-bf16 MFMA GEMM (fp32-equivalent precision, node path) ----------------
template<int K, int BN, int ACT, int OUT, int ACC>
__global__ __launch_bounds__(256) void mmx_kernel(
    const __bf16* __restrict__ Ah, const __bf16* __restrict__ Al,
    const __bf16* __restrict__ Wph, const __bf16* __restrict__ Wpl,
    const float* __restrict__ bias,
    float* __restrict__ Cf, __bf16* __restrict__ Ch, __bf16* __restrict__ Cl, int ldc)
{
    constexpr int NCF = BN / 16;
    __shared__ __bf16 AsH[128 * 32];
    __shared__ __bf16 AsL[128 * 32];

    const int tid  = threadIdx.x;
    const int lane = tid & 63;
    const int w    = tid >> 6;
    const int lg   = lane >> 4;
    const int li   = lane & 15;
    const int n_blk = blockIdx.x * BN;
    const int m_blk = blockIdx.y * 128;

    f32x4 acc[2][NCF];
#pragma unroll
    for (int mf = 0; mf < 2; ++mf)
#pragma unroll
        for (int cf = 0; cf < NCF; ++cf)
#pragma unroll
            for (int r = 0; r < 4; ++r) acc[mf][cf][r] = 0.0f;

    const size_t wbase = ((size_t)(n_blk / 16) * (K / 32)) * 512 + (size_t)lane * 8;

    for (int kt = 0; kt < K / 32; ++kt) {
#pragma unroll
        for (int i = 0; i < 2; ++i) {
            int slot0 = i * 256 + w * 64;
            int s  = slot0 + lane;
            int r  = s >> 2;
            int sl = s & 3;
            int kb = sl ^ ((r >> 1) & 3);
            size_t goff = (size_t)(m_blk + r) * K + kt * 32 + kb * 8;
            __builtin_amdgcn_global_load_lds((GVoid*)(Ah + goff),
                                             (LVoid*)((char*)AsH + (size_t)slot0 * 16),
                                             16, 0, 0);
            __builtin_amdgcn_global_load_lds((GVoid*)(Al + goff),
                                             (LVoid*)((char*)AsL + (size_t)slot0 * 16),
                                             16, 0, 0);
        }
        bf16x8 bfh[NCF], bfl[NCF];
        const size_t wo = wbase + (size_t)kt * 512;
#pragma unroll
        for (int cf = 0; cf < NCF; ++cf) {
            size_t o = wo + (size_t)cf * (K / 32) * 512;
            bfh[cf] = *(const bf16x8*)(Wph + o);
            bfl[cf] = *(const bf16x8*)(Wpl + o);
        }

        __syncthreads();

        bf16x8 afh[2], afl[2];
#pragma unroll
        for (int mf = 0; mf < 2; ++mf) {
            int row = w * 32 + mf * 16 + li;
            int sl  = lg ^ ((row >> 1) & 3);
            afh[mf] = *(const bf16x8*)((const char*)AsH + (size_t)row * 64 + sl * 16);
            afl[mf] = *(const bf16x8*)((const char*)AsL + (size_t)row * 64 + sl * 16);
        }
#pragma unroll
        for (int mf = 0; mf < 2; ++mf)
#pragma unroll
            for (int cf = 0; cf < NCF; ++cf) {
                acc[mf][cf] = __builtin_amdgcn_mfma_f32_16x16x32_bf16(
                    afh[mf], bfh[cf], acc[mf][cf], 0, 0, 0);
                acc[mf][cf] = __builtin_amdgcn_mfma_f32_16x16x32_bf16(
                    afh[mf], bfl[cf], acc[mf][cf], 0, 0, 0);
                acc[mf][cf] = __builtin_amdgcn_mfma_f32_16x16x32_bf16(
                    afl[mf], bfh[cf], acc[mf][cf], 0, 0, 0);
            }
        __syncthreads();
    }

    float bv[NCF];
#pragma unroll
    for (int cf = 0; cf < NCF; ++cf) bv[cf] = bias ? bias[n_blk + cf * 16 + li] : 0.0f;
#pragma unroll
    for (int mf = 0; mf < 2; ++mf) {
        int row0 = m_blk + w * 32 + mf * 16 + lg * 4;
#pragma unroll
        for (int cf = 0; cf < NCF; ++cf) {
            int col = n_blk + cf * 16 + li;
#pragma unroll
            for (int r = 0; r < 4; ++r) {
                float v = acc[mf][cf][r] + bv[cf];
                size_t idx = (size_t)(row0 + r) * ldc + col;
                if (ACC) v += Cf[idx];
                v = act_apply(v, ACT);
                if (OUT & 1) Cf[idx] = v;
                if (OUT & 2) {
                    __bf16 h = (__bf16)v;
                    Ch[idx] = h;
                    Cl[idx] = (__bf16)(v - (float)h);
                }
            }
        }
    }
}

// ---------------- fp32 -> hi/lo bf16 split (8 elems/thread) ----------------
__global__ __launch_bounds__(256) void split_bf16_kernel(
    const float* __restrict__ in, __bf16* __restrict__ hi, __bf16* __restrict__ lo, int n8)
{
    int i = blockIdx.x * 256 + threadIdx.x;
    if (i >= n8) return;
    const float4* p = (const float4*)in + (size_t)i * 2;
    float4 a = p[0], b = p[1];
    float v[8] = {a.x, a.y, a.z, a.w, b.x, b.y, b.z, b.w};
    bf16x8 oh, ol;
#pragma unroll
    for (int j = 0; j < 8; ++j) {
        __bf16 h = (__bf16)v[j];
        oh[j] = h;
        ol[j] = (__bf16)(v[j] - (float)h);
    }
    *(bf16x8*)(hi + (size_t)i * 8) = oh;
    *(bf16x8*)(lo + (size_t)i * 8) = ol;
}

// ---------------- edge gather: dbuf = bf16(xn[src]-xn[dst]), fp32 xn ----------------
__global__ __launch_bounds__(256) void gather_diff_kernel(
    const float* __restrict__ xn, const int* __restrict__ src, const int* __restrict__ dst,
    __bf16* __restrict__ dbuf, int e0, int ec)
{
    int idx = blockIdx.x * 256 + threadIdx.x;   // ec*32 chunks of 8
    if (idx >= ec * 32) return;
    int ei = idx >> 5;
    int c  = idx & 31;
    int e = e0 + ei;
    const float4* ps = (const float4*)(xn + (size_t)src[e] * 256) + c * 2;
    const float4* pd = (const float4*)(xn + (size_t)dst[e] * 256) + c * 2;
    float4 a0 = ps[0], a1 = ps[1];
    float4 b0 = pd[0], b1 = pd[1];
    bf16x8 o;
    o[0] = (__bf16)(a0.x - b0.x); o[1] = (__bf16)(a0.y - b0.y);
    o[2] = (__bf16)(a0.z - b0.z); o[3] = (__bf16)(a0.w - b0.w);
    o[4] = (__bf16)(a1.x - b1.x); o[5] = (__bf16)(a1.y - b1.y);
    o[6] = (__bf16)(a1.z - b1.z); o[7] = (__bf16)(a1.w - b1.w);
    *(bf16x8*)(dbuf + (size_t)ei * 256 + c * 8) = o;
}

// ---------------- e-compute: e = sigmoid(s3@ew4 + eb4) (no scatter) ----------------
__global__ __launch_bounds__(256) void e_compute_kernel(
    const __bf16* __restrict__ s3, const float* __restrict__ ew4, const float* __restrict__ eb4,
    float* __restrict__ e_out, int e0, int ec)
{
    int lane = threadIdx.x & 63;
    int wid  = threadIdx.x >> 6;
    int ei = blockIdx.x * 4 + wid;
    if (ei >= ec) return;
    float v = (float)s3[(size_t)ei * 64 + lane] * ew4[lane];
#pragma unroll
    for (int off = 32; off > 0; off >>= 1) v += __shfl_down(v, off);
    if (lane == 0) {
        float ev = 1.0f / (1.0f + expf(-(v + eb4[0])));
        e_out[e0 + ei] = ev;
    }
}

// ---------------- CSR build: histogram / scan / scatter ----------------
__global__ __launch_bounds__(256) void hist_kernel(
    const int* __restrict__ dst, int* __restrict__ counts)
{
    int e = blockIdx.x * 256 + threadIdx.x;
    if (e < EE) atomicAdd(&counts[dst[e]], 1);
}

__global__ __launch_bounds__(1024) void scan_kernel(
    const int* __restrict__ counts, int* __restrict__ row_start, int* __restrict__ cursor)
{
    __shared__ int buf[1024];
    __shared__ int carry_s;
    int tid = threadIdx.x;
    if (tid == 0) carry_s = 0;
    __syncthreads();
    for (int t0 = 0; t0 < NN; t0 += 1024) {
        int i = t0 + tid;
        int v = (i < NN) ? counts[i] : 0;
        buf[tid] = v;
        __syncthreads();
        int c = carry_s;
        for (int o = 1; o < 1024; o <<= 1) {
            int u = (tid >= o) ? buf[tid - o] : 0;
            __syncthreads();
            buf[tid] += u;
            __syncthreads();
        }
        int excl = buf[tid] - v;
        if (i < NN) { row_start[i] = c + excl; cursor[i] = c + excl; }
        int total = buf[1023];
        __syncthreads();
        if (tid == 0) carry_s = c + total;
        __syncthreads();
    }
}

__global__ __launch_bounds__(256) void scatter_kernel(
    const int* __restrict__ src, const int* __restrict__ dst,
    const float* __restrict__ e_out, int* __restrict__ cursor, int2* __restrict__ bucket)
{
    int e = blockIdx.x * 256 + threadIdx.x;
    if (e >= EE) return;
    int d = dst[e];
    int pos = atomicAdd(&cursor[d], 1);
    bucket[pos] = make_int2(src[e], __float_as_int(e_out[e]));
}

// ---------------- neigh gather: one block per node, thread = feature ----------------
__global__ __launch_bounds__(256) void neigh_gather_kernel(
    const float* __restrict__ xn, const int2* __restrict__ bucket,
    const int* __restrict__ row_start, const int* __restrict__ counts,
    __bf16* __restrict__ nh, __bf16* __restrict__ nl)
{
    __shared__ int2 eb[128];
    int n = blockIdx.x;
    int f = threadIdx.x;
    int s0 = row_start[n];
    int cnt = counts[n];
    float acc = 0.0f;
    for (int t = 0; t < cnt; t += 128) {
        int m = (cnt - t < 128) ? (cnt - t) : 128;
        __syncthreads();
        if (f < m) eb[f] = bucket[s0 + t + f];
        __syncthreads();
        for (int i = 0; i < m; ++i) {
            int2 p = eb[i];
            acc = fmaf(__int_as_float(p.y), xn[(size_t)p.x * 256 + f], acc);
        }
    }
    float dv = (float)(cnt > 0 ? cnt : 1);
    float v = acc / dv;
    __bf16 h = (__bf16)v;
    nh[(size_t)n * 256 + f] = h;
    nl[(size_t)n * 256 + f] = (__bf16)(v - (float)h);
}

// ---------------- pose head ----------------
__global__ __launch_bounds__(128) void pose_kernel(
    const float* __restrict__ A_pre, const float* __restrict__ decw,
    const float* __restrict__ decb, float* __restrict__ pos, float* __restrict__ ori)
{
    __shared__ float arow[128];
    int b = blockIdx.x;
    arow[threadIdx.x] = A_pre[(size_t)(b * S_) * 128 + threadIdx.x];
    __syncthreads();
    int t = threadIdx.x;
    if (t < 7) {
        float s = decb[t];
        for (int c = 0; c < 128; ++c) s = fmaf(arow[c], decw[c * 7 + t], s);
        if (t < 3) pos[b * 3 + t] = s;
        else       ori[b * 4 + (t - 3)] = s;
    }
}

// ---------------- A = lrelu(A_pre); A /= max(||A||_S, eps) ----------------
__global__ __launch_bounds__(128) void norm_kernel(
    const float* __restrict__ A_pre, float* __restrict__ out)
{
    int b = blockIdx.x;
    int c = threadIdx.x;
    size_t base = (size_t)b * S_ * 128 + c;
    float ss = 0.0f;
    for (int s = 0; s < S_; ++s) {
        float v = A_pre[base + (size_t)s * 128];
        v = v > 0.0f ? v : NEG_SLOPE * v;
        ss = fmaf(v, v, ss);
    }
    float nrm = fmaxf(sqrtf(ss), EPS_);
    float inv = 1.0f / nrm;
    for (int s = 0; s < S_; ++s) {
        float v = A_pre[base + (size_t)s * 128];
        v = v > 0.0f ? v : NEG_SLOPE * v;
        out[base + (size_t)s * 128] = v * inv;
    }
}

extern "C" void kernel_launch(void* const* d_in, const int* in_sizes, int n_in,
                              void* d_out, int out_size, void* d_ws, size_t ws_size,
                              hipStream_t stream) {
    const float* x      = (const float*)d_in[0];
    const float* x_pose = (const float*)d_in[1];
    const float* m2w1 = (const float*)d_in[2];
    const float* m2b1 = (const float*)d_in[3];
    const float* m2w2 = (const float*)d_in[4];
    const float* m2b2 = (const float*)d_in[5];
    const float* m2w3 = (const float*)d_in[6];
    const float* m2b3 = (const float*)d_in[7];
    const float* m3w1 = (const float*)d_in[8];
    const float* m3b1 = (const float*)d_in[9];
    const float* m3w2 = (const float*)d_in[10];
    const float* m3b2 = (const float*)d_in[11];
    const float* m3w3 = (const float*)d_in[12];
    const float* m3b3 = (const float*)d_in[13];
    const float* encw = (const float*)d_in[14];
    const float* encb = (const float*)d_in[15];
    const float* ew1  = (const float*)d_in[16];
    const float* eb1  = (const float*)d_in[17];
    const float* ew2  = (const float*)d_in[18];
    const float* eb2  = (const float*)d_in[19];
    const float* ew3  = (const float*)d_in[20];
    const float* eb3  = (const float*)d_in[21];
    const float* ew4  = (const float*)d_in[22];
    const float* eb4  = (const float*)d_in[23];
    const float* wself  = (const float*)d_in[24];
    const float* wneigh = (const float*)d_in[25];
    const float* sageb  = (const float*)d_in[26];
    const float* decw = (const float*)d_in[27];
    const float* decb = (const float*)d_in[28];
    const int* esrc = (const int*)d_in[29];
    const int* edst = (const int*)d_in[30];
    float* out = (float*)d_out;

    // ---- workspace layout (byte allocator, 16B aligned) ----
    char* base = (char*)d_ws;
    size_t off = 0;
    auto alloc = [&](size_t bytes) { char* p = base + off; off += (bytes + 15) & ~15ULL; return p; };
    // fp32 buffers
    float* xn        = (float*)alloc((size_t)NN * 256 * 4);
    float* A_pre     = (float*)alloc((size_t)NN * 128 * 4);
    float* p1        = (float*)alloc((size_t)NN * 16 * 4);
    float* p2        = (float*)alloc((size_t)NN * 32 * 4);
    // CSR buffers
    int*  counts    = (int*)alloc((size_t)NN * 4);
    int*  row_start = (int*)alloc((size_t)NN * 4);
    int*  cursor    = (int*)alloc((size_t)NN * 4);
    int2* bucket    = (int2*)alloc((size_t)EE * 8);
    // hi/lo bf16 activation pairs (node path, fp32-equivalent precision)
    __bf16* xh   = (__bf16*)alloc((size_t)NN * 512 * 2);
    __bf16* xl   = (__bf16*)alloc((size_t)NN * 512 * 2);
    __bf16* t1h  = (__bf16*)alloc((size_t)NN * 256 * 2);
    __bf16* t1l  = (__bf16*)alloc((size_t)NN * 256 * 2);
    __bf16* t2h  = (__bf16*)alloc((size_t)NN * 128 * 2);
    __bf16* t2l  = (__bf16*)alloc((size_t)NN * 128 * 2);
    __bf16* hch  = (__bf16*)alloc((size_t)NN * 128 * 2);
    __bf16* hcl  = (__bf16*)alloc((size_t)NN * 128 * 2);
    __bf16* p2h  = (__bf16*)alloc((size_t)NN * 32 * 2);
    __bf16* p2l  = (__bf16*)alloc((size_t)NN * 32 * 2);
    __bf16* xnh  = (__bf16*)alloc((size_t)NN * 256 * 2);
    __bf16* xnl  = (__bf16*)alloc((size_t)NN * 256 * 2);
    __bf16* ngh  = (__bf16*)alloc((size_t)NN * 256 * 2);
    __bf16* ngl  = (__bf16*)alloc((size_t)NN * 256 * 2);
    // packed weights: node (hi/lo pairs)
    __bf16* wpn1h = (__bf16*)alloc((size_t)512 * 256 * 2);
    __bf16* wpn1l = (__bf16*)alloc((size_t)512 * 256 * 2);
    __bf16* wpn2h = (__bf16*)alloc((size_t)256 * 128 * 2);
    __bf16* wpn2l = (__bf16*)alloc((size_t)256 * 128 * 2);
    __bf16* wpn3h = (__bf16*)alloc((size_t)128 * 64 * 2);
    __bf16* wpn3l = (__bf16*)alloc((size_t)128 * 64 * 2);
    __bf16* wpp3h = (__bf16*)alloc((size_t)32 * 64 * 2);
    __bf16* wpp3l = (__bf16*)alloc((size_t)32 * 64 * 2);
    __bf16* wpenh = (__bf16*)alloc((size_t)128 * 256 * 2);
    __bf16* wpenl = (__bf16*)alloc((size_t)128 * 256 * 2);
    __bf16* wpsfh = (__bf16*)alloc((size_t)256 * 128 * 2);
    __bf16* wpsfl = (__bf16*)alloc((size_t)256 * 128 * 2);
    __bf16* wpngh = (__bf16*)alloc((size_t)256 * 128 * 2);
    __bf16* wpngl = (__bf16*)alloc((size_t)256 * 128 * 2);
    // packed weights: edge (single bf16, proven)
    __bf16* wpe1 = (__bf16*)alloc((size_t)256 * 256 * 2);
    __bf16* wpe2 = (__bf16*)alloc((size_t)256 * 128 * 2);
    __bf16* wpe3 = (__bf16*)alloc((size_t)128 * 64 * 2);

    // edge chunking (deterministic given ws_size)
    long long avail_bytes = (long long)ws_size - (long long)off;
    const long long PER_EDGE_B = (256 + 256 + 128 + 64) * 2;   // 1408 bytes
    long long ecmax = avail_bytes / PER_EDGE_B;
    ecmax = (ecmax / 128) * 128;
    if (ecmax > EE) ecmax = EE;
    if (ecmax < 128) ecmax = 128;
    int nchunk = (int)((EE + ecmax - 1) / ecmax);
    long long ec = ((EE + nchunk - 1) / nchunk + 127) / 128 * 128;

    __bf16* dbuf = (__bf16*)(base + off);
    __bf16* s1   = dbuf + ec * 256;
    __bf16* s2   = s1 + ec * 256;
    __bf16* s3   = s2 + ec * 128;

    hipMemsetAsync(counts, 0, (size_t)NN * sizeof(int), stream);

    // pack node weights (hi/lo)
    pack_w2_kernel<<<(512*256+255)/256, 256, 0, stream>>>(m2w1, wpn1h, wpn1l, 512, 256);
    pack_w2_kernel<<<(256*128+255)/256, 256, 0, stream>>>(m2w2, wpn2h, wpn2l, 256, 128);
    pack_w2_kernel<<<(128*64 +255)/256, 256, 0, stream>>>(m2w3, wpn3h, wpn3l, 128, 64);
    pack_w2_kernel<<<(32*64  +255)/256, 256, 0, stream>>>(m3w3, wpp3h, wpp3l, 32, 64);
    pack_w2_kernel<<<(128*256+255)/256, 256, 0, stream>>>(encw, wpenh, wpenl, 128, 256);
    pack_w2_kernel<<<(256*128+255)/256, 256, 0, stream>>>(wself, wpsfh, wpsfl, 256, 128);
    pack_w2_kernel<<<(256*128+255)/256, 256, 0, stream>>>(wneigh, wpngh, wpngl, 256, 128);
    // pack edge weights (single bf16)
    pack_w_kernel<<<(256*256+255)/256, 256, 0, stream>>>(ew1, wpe1, 256, 256);
    pack_w_kernel<<<(256*128+255)/256, 256, 0, stream>>>(ew2, wpe2, 256, 128);
    pack_w_kernel<<<(128*64 +255)/256, 256, 0, stream>>>(ew3, wpe3, 128, 64);

    // split x -> hi/lo
    split_bf16_kernel<<<(NN*512/8 + 255)/256, 256, 0, stream>>>(x, xh, xl, NN*512/8);

    const dim3 blk(256, 1, 1);
    const int MB = NN / 128;   // 102

    // node MLP branch (split-bf16 MFMA, fp32-equivalent)
    mmx_kernel<512,64,1,2,0><<<dim3(4, MB), blk, 0, stream>>>(xh, xl, wpn1h, wpn1l, m2b1, nullptr, t1h, t1l, 256);
    mmx_kernel<256,64,1,2,0><<<dim3(2, MB), blk, 0, stream>>>(t1h, t1l, wpn2h, wpn2l, m2b2, nullptr, t2h, t2l, 128);
    mmx_kernel<128,64,1,2,0><<<dim3(1, MB), blk, 0, stream>>>(t2h, t2l, wpn3h, wpn3l, m2b3, nullptr, hch, hcl, 128);

    // pose branch: tiny fp32 layers, split, then MFMA layer 3 into hcat cols 64..127
    gemm_kernel<1,0><<<dim3((NN+63)/64, 1), blk, 0, stream>>>(x_pose, 7,  m3w1, 16, m3b1, p1, 16, NN, 7, 16);
    gemm_kernel<1,0><<<dim3((NN+63)/64, 1), blk, 0, stream>>>(p1,    16,  m3w2, 32, m3b2, p2, 32, NN, 16, 32);
    split_bf16_kernel<<<(NN*32/8 + 255)/256, 256, 0, stream>>>(p2, p2h, p2l, NN*32/8);
    mmx_kernel< 32,64,1,2,0><<<dim3(1, MB), blk, 0, stream>>>(p2h, p2l, wpp3h, wpp3l, m3b3, nullptr, hch + 64, hcl + 64, 128);

    // encoder: fp32 xn (for gather) + hi/lo xn (for SAGE)
    mmx_kernel<128,64,1,3,0><<<dim3(4, MB), blk, 0, stream>>>(hch, hcl, wpenh, wpenl, encb, xn, xnh, xnl, 256);

    // edge pipeline, chunked, bf16 MFMA; tail only computes e (no atomics)
    for (int c = 0; c < nchunk; ++c) {
        long long e0 = (long long)c * ec;
        int ecc = (int)((e0 + ec <= EE) ? ec : (EE - e0));   // multiple of 128
        gather_diff_kernel<<<(ecc * 32 + 255) / 256, 256, 0, stream>>>(
            xn, esrc, edst, dbuf, (int)e0, ecc);
        edge_gemm_kernel<256, 256, 128><<<dim3(2, ecc / 128), blk, 0, stream>>>(dbuf, wpe1, eb1, s1);
        edge_gemm_kernel<256, 128, 128><<<dim3(1, ecc / 128), blk, 0, stream>>>(s1,   wpe2, eb2, s2);
        edge_gemm_kernel<128,  64,  64><<<dim3(1, ecc / 128), blk, 0, stream>>>(s2,   wpe3, eb3, s3);
        e_compute_kernel<<<(ecc + 3) / 4, 256, 0, stream>>>(
            s3, ew4, eb4, out + E_OFF, (int)e0, ecc);
    }

    // CSR build + gather-based segment mean (replaces atomic scatter)
    hist_kernel<<<(EE + 255) / 256, 256, 0, stream>>>(edst, counts);
    scan_kernel<<<1, 1024, 0, stream>>>(counts, row_start, cursor);
    scatter_kernel<<<(EE + 255) / 256, 256, 0, stream>>>(esrc, edst, out + E_OFF, cursor, bucket);
    neigh_gather_kernel<<<NN, 256, 0, stream>>>(xn, bucket, row_start, counts, ngh, ngl);

    // SAGE: A_pre = xn@wself + sageb; A_pre += neigh@wneigh  (split MFMA, fp32 out)
    mmx_kernel<256,64,0,1,0><<<dim3(2, MB), blk, 0, stream>>>(xnh, xnl, wpsfh, wpsfl, sageb,  A_pre, nullptr, nullptr, 128);
    mmx_kernel<256,64,0,1,1><<<dim3(2, MB), blk, 0, stream>>>(ngh, ngl, wpngh, wpngl, nullptr, A_pre, nullptr, nullptr, 128);

    pose_kernel<<<B_, 128, 0, stream>>>(A_pre, decw, decb, out + POS_OFF, out + ORI_OFF);
    norm_kernel<<<B_, 128, 0, stream>>>(A_pre, out);
}

// Round 8
// 820.724 us; speedup vs baseline: 6.6206x; 1.4289x over previous
//
#include <hip/hip_runtime.h>
#include <math.h>

#define B_ 256
#define S_ 51
#define NN (B_*S_)            // 13056 nodes = 102*128
#define DEG_ 50
#define EE (NN*DEG_)          // 652800 edges
#define NEG_SLOPE 0.01f
#define EPS_ 1e-12f

#define A_SIZE (NN*128)
#define E_OFF  A_SIZE
#define POS_OFF (A_SIZE + EE)
#define ORI_OFF (POS_OFF + B_*3)

typedef __bf16 bf16x8 __attribute__((ext_vector_type(8)));
typedef __bf16 bf16x4 __attribute__((ext_vector_type(4)));
typedef float  f32x4  __attribute__((ext_vector_type(4)));

typedef __attribute__((address_space(1))) const void GVoid;
typedef __attribute__((address_space(3))) void LVoid;

__device__ __forceinline__ float act_apply(float v, int ACT) {
    if (ACT == 1) return fmaxf(v, 0.0f);
    if (ACT == 2) return v > 0.0f ? v : NEG_SLOPE * v;
    return v;
}

// ---------------- fp32 tiled GEMM (tiny pose layers only) ----------------
template<int ACT, int ACC>
__global__ __launch_bounds__(256) void gemm_kernel(
    const float* __restrict__ A, int lda,
    const float* __restrict__ W, int ldw,
    const float* __restrict__ bias,
    float* __restrict__ C, int ldc,
    int M, int K, int N)
{
    __shared__ float As[32][68];
    __shared__ float Ws[32][68];

    const int tid = threadIdx.x;
    const int tx = tid & 15;
    const int ty = tid >> 4;
    const int m0 = blockIdx.x * 64;
    const int n0 = blockIdx.y * 64;

    float acc[4][4];
#pragma unroll
    for (int i = 0; i < 4; ++i)
#pragma unroll
        for (int j = 0; j < 4; ++j) acc[i][j] = 0.0f;

    const int ktiles = (K + 31) >> 5;
    for (int kt = 0; kt < ktiles; ++kt) {
        const int k0 = kt << 5;
#pragma unroll
        for (int it = 0; it < 8; ++it) {
            int idx = tid + it * 256;
            int kk = idx & 31;
            int r  = idx >> 5;
            float v = 0.0f;
            int gr = m0 + r, gk = k0 + kk;
            if (gr < M && gk < K) v = A[(size_t)gr * lda + gk];
            As[kk][r] = v;
        }
#pragma unroll
        for (int it = 0; it < 8; ++it) {
            int idx = tid + it * 256;
            int c  = idx & 63;
            int kk = idx >> 6;
            float v = 0.0f;
            int gk = k0 + kk, gc = n0 + c;
            if (gk < K && gc < N) v = W[(size_t)gk * ldw + gc];
            Ws[kk][c] = v;
        }
        __syncthreads();
#pragma unroll
        for (int kk = 0; kk < 32; ++kk) {
            float4 av = *(const float4*)&As[kk][ty * 4];
            float4 wv = *(const float4*)&Ws[kk][tx * 4];
            float a[4] = {av.x, av.y, av.z, av.w};
            float w[4] = {wv.x, wv.y, wv.z, wv.w};
#pragma unroll
            for (int i = 0; i < 4; ++i)
#pragma unroll
                for (int j = 0; j < 4; ++j)
                    acc[i][j] = fmaf(a[i], w[j], acc[i][j]);
        }
        __syncthreads();
    }

#pragma unroll
    for (int i = 0; i < 4; ++i) {
        int row = m0 + ty * 4 + i;
        if (row >= M) continue;
#pragma unroll
        for (int j = 0; j < 4; ++j) {
            int col = n0 + tx * 4 + j;
            if (col >= N) continue;
            float v = acc[i][j];
            if (bias) v += bias[col];
            if (ACC) v += C[(size_t)row * ldc + col];
            C[(size_t)row * ldc + col] = act_apply(v, ACT);
        }
    }
}

// ---------------- weight pack: W[K][N] fp32 -> MFMA-fragment-ordered bf16 ----------------
__global__ __launch_bounds__(256) void pack_w_kernel(
    const float* __restrict__ W, __bf16* __restrict__ Wp, int K, int N)
{
    int t = blockIdx.x * 256 + threadIdx.x;
    if (t >= K * N) return;
    int j    = t & 7;
    int lane = (t >> 3) & 63;
    int rkt  = t >> 9;
    int KT = K >> 5;
    int kt = rkt % KT;
    int cf = rkt / KT;
    int k = kt * 32 + (lane >> 4) * 8 + j;
    int n = cf * 16 + (lane & 15);
    Wp[t] = (__bf16)W[(size_t)k * N + n];
}

// same, but hi/lo split pair (fp32-equivalent precision)
__global__ __launch_bounds__(256) void pack_w2_kernel(
    const float* __restrict__ W, __bf16* __restrict__ Wph, __bf16* __restrict__ Wpl,
    int K, int N)
{
    int t = blockIdx.x * 256 + threadIdx.x;
    if (t >= K * N) return;
    int j    = t & 7;
    int lane = (t >> 3) & 63;
    int rkt  = t >> 9;
    int KT = K >> 5;
    int kt = rkt % KT;
    int cf = rkt / KT;
    int k = kt * 32 + (lane >> 4) * 8 + j;
    int n = cf * 16 + (lane & 15);
    float v = W[(size_t)k * N + n];
    __bf16 h = (__bf16)v;
    Wph[t] = h;
    Wpl[t] = (__bf16)(v - (float)h);
}

// ---------------- bf16 MFMA edge GEMM (proven): C = lrelu(A@W+bias) ----------------
template<int K, int N, int BN>
__global__ __launch_bounds__(256) void edge_gemm_kernel(
    const __bf16* __restrict__ A, const __bf16* __restrict__ Wp,
    const float* __restrict__ bias, __bf16* __restrict__ C)
{
    constexpr int NCF = BN / 16;
    __shared__ __bf16 As[128 * 32];   // 8 KB

    const int tid  = threadIdx.x;
    const int lane = tid & 63;
    const int w    = tid >> 6;
    const int lg   = lane >> 4;
    const int li   = lane & 15;
    const int n_blk = blockIdx.x * BN;
    const int m_blk = blockIdx.y * 128;

    f32x4 acc[2][NCF];
#pragma unroll
    for (int mf = 0; mf < 2; ++mf)
#pragma unroll
        for (int cf = 0; cf < NCF; ++cf)
#pragma unroll
            for (int r = 0; r < 4; ++r) acc[mf][cf][r] = 0.0f;

    const __bf16* WpBase = Wp + ((size_t)(n_blk / 16) * (K / 32)) * 512 + (size_t)lane * 8;

    for (int kt = 0; kt < K / 32; ++kt) {
#pragma unroll
        for (int i = 0; i < 2; ++i) {
            int slot0 = i * 256 + w * 64;
            int s  = slot0 + lane;
            int r  = s >> 2;
            int sl = s & 3;
            int kb = sl ^ ((r >> 1) & 3);
            const __bf16* g = A + (size_t)(m_blk + r) * K + kt * 32 + kb * 8;
            __builtin_amdgcn_global_load_lds((GVoid*)g,
                                             (LVoid*)((char*)As + (size_t)slot0 * 16),
                                             16, 0, 0);
        }
        bf16x8 bf[NCF];
        const __bf16* Wb = WpBase + (size_t)kt * 512;
#pragma unroll
        for (int cf = 0; cf < NCF; ++cf)
            bf[cf] = *(const bf16x8*)(Wb + (size_t)cf * (K / 32) * 512);

        __syncthreads();

        bf16x8 af[2];
#pragma unroll
        for (int mf = 0; mf < 2; ++mf) {
            int row = w * 32 + mf * 16 + li;
            int sl  = lg ^ ((row >> 1) & 3);
            af[mf] = *(const bf16x8*)((const char*)As + (size_t)row * 64 + sl * 16);
        }
#pragma unroll
        for (int mf = 0; mf < 2; ++mf)
#pragma unroll
            for (int cf = 0; cf < NCF; ++cf)
                acc[mf][cf] = __builtin_amdgcn_mfma_f32_16x16x32_bf16(
                    af[mf], bf[cf], acc[mf][cf], 0, 0, 0);
        __syncthreads();
    }

    float bv[NCF];
#pragma unroll
    for (int cf = 0; cf < NCF; ++cf) bv[cf] = bias[n_blk + cf * 16 + li];
#pragma unroll
    for (int mf = 0; mf < 2; ++mf) {
        int row0 = m_blk + w * 32 + mf * 16 + lg * 4;
#pragma unroll
        for (int cf = 0; cf < NCF; ++cf) {
            int col = n_blk + cf * 16 + li;
#pragma unroll
            for (int r = 0; r < 4; ++r) {
                float v = acc[mf][cf][r] + bv[cf];
                v = v > 0.0f ? v : NEG_SLOPE * v;
                C[(size_t)(row0 + r) * N + col] = (__bf16)v;
            }
        }
    }
}

// ---------------- Y = A @ W, fp32 out, no bias/act (node-level L1 via linearity) ----------------
template<int K, int BN>
__global__ __launch_bounds__(256) void ygemm_kernel(
    const __bf16* __restrict__ A, const __bf16* __restrict__ Wp,
    float* __restrict__ C, int ldc)
{
    constexpr int NCF = BN / 16;
    __shared__ __bf16 As[128 * 32];

    const int tid  = threadIdx.x;
    const int lane = tid & 63;
    const int w    = tid >> 6;
    const int lg   = lane >> 4;
    const int li   = lane & 15;
    const int n_blk = blockIdx.x * BN;
    const int m_blk = blockIdx.y * 128;

    f32x4 acc[2][NCF];
#pragma unroll
    for (int mf = 0; mf < 2; ++mf)
#pragma unroll
        for (int cf = 0; cf < NCF; ++cf)
#pragma unroll
            for (int r = 0; r < 4; ++r) acc[mf][cf][r] = 0.0f;

    const __bf16* WpBase = Wp + ((size_t)(n_blk / 16) * (K / 32)) * 512 + (size_t)lane * 8;

    for (int kt = 0; kt < K / 32; ++kt) {
#pragma unroll
        for (int i = 0; i < 2; ++i) {
            int slot0 = i * 256 + w * 64;
            int s  = slot0 + lane;
            int r  = s >> 2;
            int sl = s & 3;
            int kb = sl ^ ((r >> 1) & 3);
            const __bf16* g = A + (size_t)(m_blk + r) * K + kt * 32 + kb * 8;
            __builtin_amdgcn_global_load_lds((GVoid*)g,
                                             (LVoid*)((char*)As + (size_t)slot0 * 16),
                                             16, 0, 0);
        }
        bf16x8 bf[NCF];
        const __bf16* Wb = WpBase + (size_t)kt * 512;
#pragma unroll
        for (int cf = 0; cf < NCF; ++cf)
            bf[cf] = *(const bf16x8*)(Wb + (size_t)cf * (K / 32) * 512);

        __syncthreads();

        bf16x8 af[2];
#pragma unroll
        for (int mf = 0; mf < 2; ++mf) {
            int row = w * 32 + mf * 16 + li;
            int sl  = lg ^ ((row >> 1) & 3);
            af[mf] = *(const bf16x8*)((const char*)As + (size_t)row * 64 + sl * 16);
        }
#pragma unroll
        for (int mf = 0; mf < 2; ++mf)
#pragma unroll
            for (int cf = 0; cf < NCF; ++cf)
                acc[mf][cf] = __builtin_amdgcn_mfma_f32_16x16x32_bf16(
                    af[mf], bf[cf], acc[mf][cf], 0, 0, 0);
        __syncthreads();
    }

#pragma unroll
    for (int mf = 0; mf < 2; ++mf) {
        int row0 = m_blk + w * 32 + mf * 16 + lg * 4;
#pragma unroll
        for (int cf = 0; cf < NCF; ++cf) {
            int col = n_blk + cf * 16 + li;
#pragma unroll
            for (int r = 0; r < 4; ++r)
                C[(size_t)(row0 + r) * ldc + col] = acc[mf][cf][r];
        }
    }
}

// ---------------- L3 + dot + sigmoid fused: e = sigmoid(lrelu(s2@ew3+eb3)@ew4+eb4) ----------------
// K=128, N=BN=64 (single n-block). Per block: 128 edges.
__global__ __launch_bounds__(256) void edge_l3e_kernel(
    const __bf16* __restrict__ A, const __bf16* __restrict__ Wp,
    const float* __restrict__ eb3, const float* __restrict__ ew4,
    const float* __restrict__ eb4, float* __restrict__ e_out, int e0)
{
    constexpr int K = 128, NCF = 4;
    __shared__ __bf16 As[128 * 32];

    const int tid  = threadIdx.x;
    const int lane = tid & 63;
    const int w    = tid >> 6;
    const int lg   = lane >> 4;
    const int li   = lane & 15;
    const int m_blk = blockIdx.y * 128;

    f32x4 acc[2][NCF];
#pragma unroll
    for (int mf = 0; mf < 2; ++mf)
#pragma unroll
        for (int cf = 0; cf < NCF; ++cf)
#pragma unroll
            for (int r = 0; r < 4; ++r) acc[mf][cf][r] = 0.0f;

    const __bf16* WpBase = Wp + (size_t)lane * 8;

    for (int kt = 0; kt < K / 32; ++kt) {
#pragma unroll
        for (int i = 0; i < 2; ++i) {
            int slot0 = i * 256 + w * 64;
            int s  = slot0 + lane;
            int r  = s >> 2;
            int sl = s & 3;
            int kb = sl ^ ((r >> 1) & 3);
            const __bf16* g = A + (size_t)(m_blk + r) * K + kt * 32 + kb * 8;
            __builtin_amdgcn_global_load_lds((GVoid*)g,
                                             (LVoid*)((char*)As + (size_t)slot0 * 16),
                                             16, 0, 0);
        }
        bf16x8 bf[NCF];
        const __bf16* Wb = WpBase + (size_t)kt * 512;
#pragma unroll
        for (int cf = 0; cf < NCF; ++cf)
            bf[cf] = *(const bf16x8*)(Wb + (size_t)cf * (K / 32) * 512);

        __syncthreads();

        bf16x8 af[2];
#pragma unroll
        for (int mf = 0; mf < 2; ++mf) {
            int row = w * 32 + mf * 16 + li;
            int sl  = lg ^ ((row >> 1) & 3);
            af[mf] = *(const bf16x8*)((const char*)As + (size_t)row * 64 + sl * 16);
        }
#pragma unroll
        for (int mf = 0; mf < 2; ++mf)
#pragma unroll
            for (int cf = 0; cf < NCF; ++cf)
                acc[mf][cf] = __builtin_amdgcn_mfma_f32_16x16x32_bf16(
                    af[mf], bf[cf], acc[mf][cf], 0, 0, 0);
        __syncthreads();
    }

    // epilogue: s3 = lrelu(acc + eb3); partial dot with ew4; 16-lane reduce; sigmoid
    float p[2][4];
#pragma unroll
    for (int mf = 0; mf < 2; ++mf)
#pragma unroll
        for (int r = 0; r < 4; ++r) p[mf][r] = 0.0f;
#pragma unroll
    for (int cf = 0; cf < NCF; ++cf) {
        int col = cf * 16 + li;
        float b3 = eb3[col];
        float w4 = ew4[col];
#pragma unroll
        for (int mf = 0; mf < 2; ++mf)
#pragma unroll
            for (int r = 0; r < 4; ++r) {
                float v = acc[mf][cf][r] + b3;
                v = v > 0.0f ? v : NEG_SLOPE * v;
                p[mf][r] = fmaf(v, w4, p[mf][r]);
            }
    }
#pragma unroll
    for (int mf = 0; mf < 2; ++mf)
#pragma unroll
        for (int r = 0; r < 4; ++r) {
#pragma unroll
            for (int m = 1; m < 16; m <<= 1)
                p[mf][r] += __shfl_xor(p[mf][r], m, 16);
        }
    if (li == 0) {
        float b4 = eb4[0];
#pragma unroll
        for (int mf = 0; mf < 2; ++mf)
#pragma unroll
            for (int r = 0; r < 4; ++r) {
                int ei = m_blk + w * 32 + mf * 16 + lg * 4 + r;
                float ev = 1.0f / (1.0f + expf(-(p[mf][r] + b4)));
                e_out[e0 + ei] = ev;
            }
    }
}

// ---------------- split-bf16 MFMA GEMM (fp32-equivalent precision, node path) ----------------
template<int K, int BN, int ACT, int OUT, int ACC>
__global__ __launch_bounds__(256) void mmx_kernel(
    const __bf16* __restrict__ Ah, const __bf16* __restrict__ Al,
    const __bf16* __restrict__ Wph, const __bf16* __restrict__ Wpl,
    const float* __restrict__ bias,
    float* __restrict__ Cf, __bf16* __restrict__ Ch, __bf16* __restrict__ Cl, int ldc)
{
    constexpr int NCF = BN / 16;
    __shared__ __bf16 AsH[128 * 32];
    __shared__ __bf16 AsL[128 * 32];

    const int tid  = threadIdx.x;
    const int lane = tid & 63;
    const int w    = tid >> 6;
    const int lg   = lane >> 4;
    const int li   = lane & 15;
    const int n_blk = blockIdx.x * BN;
    const int m_blk = blockIdx.y * 128;

    f32x4 acc[2][NCF];
#pragma unroll
    for (int mf = 0; mf < 2; ++mf)
#pragma unroll
        for (int cf = 0; cf < NCF; ++cf)
#pragma unroll
            for (int r = 0; r < 4; ++r) acc[mf][cf][r] = 0.0f;

    const size_t wbase = ((size_t)(n_blk / 16) * (K / 32)) * 512 + (size_t)lane * 8;

    for (int kt = 0; kt < K / 32; ++kt) {
#pragma unroll
        for (int i = 0; i < 2; ++i) {
            int slot0 = i * 256 + w * 64;
            int s  = slot0 + lane;
            int r  = s >> 2;
            int sl = s & 3;
            int kb = sl ^ ((r >> 1) & 3);
            size_t goff = (size_t)(m_blk + r) * K + kt * 32 + kb * 8;
            __builtin_amdgcn_global_load_lds((GVoid*)(Ah + goff),
                                             (LVoid*)((char*)AsH + (size_t)slot0 * 16),
                                             16, 0, 0);
            __builtin_amdgcn_global_load_lds((GVoid*)(Al + goff),
                                             (LVoid*)((char*)AsL + (size_t)slot0 * 16),
                                             16, 0, 0);
        }
        bf16x8 bfh[NCF], bfl[NCF];
        const size_t wo = wbase + (size_t)kt * 512;
#pragma unroll
        for (int cf = 0; cf < NCF; ++cf) {
            size_t o = wo + (size_t)cf * (K / 32) * 512;
            bfh[cf] = *(const bf16x8*)(Wph + o);
            bfl[cf] = *(const bf16x8*)(Wpl + o);
        }

        __syncthreads();

        bf16x8 afh[2], afl[2];
#pragma unroll
        for (int mf = 0; mf < 2; ++mf) {
            int row = w * 32 + mf * 16 + li;
            int sl  = lg ^ ((row >> 1) & 3);
            afh[mf] = *(const bf16x8*)((const char*)AsH + (size_t)row * 64 + sl * 16);
            afl[mf] = *(const bf16x8*)((const char*)AsL + (size_t)row * 64 + sl * 16);
        }
#pragma unroll
        for (int mf = 0; mf < 2; ++mf)
#pragma unroll
            for (int cf = 0; cf < NCF; ++cf) {
                acc[mf][cf] = __builtin_amdgcn_mfma_f32_16x16x32_bf16(
                    afh[mf], bfh[cf], acc[mf][cf], 0, 0, 0);
                acc[mf][cf] = __builtin_amdgcn_mfma_f32_16x16x32_bf16(
                    afh[mf], bfl[cf], acc[mf][cf], 0, 0, 0);
                acc[mf][cf] = __builtin_amdgcn_mfma_f32_16x16x32_bf16(
                    afl[mf], bfh[cf], acc[mf][cf], 0, 0, 0);
            }
        __syncthreads();
    }

    float bv[NCF];
#pragma unroll
    for (int cf = 0; cf < NCF; ++cf) bv[cf] = bias ? bias[n_blk + cf * 16 + li] : 0.0f;
#pragma unroll
    for (int mf = 0; mf < 2; ++mf) {
        int row0 = m_blk + w * 32 + mf * 16 + lg * 4;
#pragma unroll
        for (int cf = 0; cf < NCF; ++cf) {
            int col = n_blk + cf * 16 + li;
#pragma unroll
            for (int r = 0; r < 4; ++r) {
                float v = acc[mf][cf][r] + bv[cf];
                size_t idx = (size_t)(row0 + r) * ldc + col;
                if (ACC) v += Cf[idx];
                v = act_apply(v, ACT);
                if (OUT & 1) Cf[idx] = v;
                if (OUT & 2) {
                    __bf16 h = (__bf16)v;
                    Ch[idx] = h;
                    Cl[idx] = (__bf16)(v - (float)h);
                }
            }
        }
    }
}

// ---------------- fp32 -> hi/lo bf16 split (8 elems/thread) ----------------
__global__ __launch_bounds__(256) void split_bf16_kernel(
    const float* __restrict__ in, __bf16* __restrict__ hi, __bf16* __restrict__ lo, int n8)
{
    int i = blockIdx.x * 256 + threadIdx.x;
    if (i >= n8) return;
    const float4* p = (const float4*)in + (size_t)i * 2;
    float4 a = p[0], b = p[1];
    float v[8] = {a.x, a.y, a.z, a.w, b.x, b.y, b.z, b.w};
    bf16x8 oh, ol;
#pragma unroll
    for (int j = 0; j < 8; ++j) {
        __bf16 h = (__bf16)v[j];
        oh[j] = h;
        ol[j] = (__bf16)(v[j] - (float)h);
    }
    *(bf16x8*)(hi + (size_t)i * 8) = oh;
    *(bf16x8*)(lo + (size_t)i * 8) = ol;
}

// ---------------- gather + L1 epilogue: s1 = bf16(lrelu(Y[src]-Y[dst]+eb1)) ----------------
__global__ __launch_bounds__(256) void gather_s1_kernel(
    const float* __restrict__ Y, const float* __restrict__ eb1,
    const int* __restrict__ src, const int* __restrict__ dst,
    __bf16* __restrict__ s1, int e0, int ec)
{
    int idx = blockIdx.x * 256 + threadIdx.x;   // ec*32 chunks of 8
    if (idx >= ec * 32) return;
    int ei = idx >> 5;
    int c  = idx & 31;
    int e = e0 + ei;
    const float4* ps = (const float4*)(Y + (size_t)src[e] * 256) + c * 2;
    const float4* pd = (const float4*)(Y + (size_t)dst[e] * 256) + c * 2;
    const float4* pb = (const float4*)eb1 + c * 2;
    float4 a0 = ps[0], a1 = ps[1];
    float4 b0 = pd[0], b1 = pd[1];
    float4 e0v = pb[0], e1v = pb[1];
    float v[8] = {a0.x - b0.x + e0v.x, a0.y - b0.y + e0v.y,
                  a0.z - b0.z + e0v.z, a0.w - b0.w + e0v.w,
                  a1.x - b1.x + e1v.x, a1.y - b1.y + e1v.y,
                  a1.z - b1.z + e1v.z, a1.w - b1.w + e1v.w};
    bf16x8 o;
#pragma unroll
    for (int j = 0; j < 8; ++j) {
        float t = v[j] > 0.0f ? v[j] : NEG_SLOPE * v[j];
        o[j] = (__bf16)t;
    }
    *(bf16x8*)(s1 + (size_t)ei * 256 + c * 8) = o;
}

// ---------------- CSR build: histogram / scan / scatter ----------------
__global__ __launch_bounds__(256) void hist_kernel(
    const int* __restrict__ dst, int* __restrict__ counts)
{
    int e = blockIdx.x * 256 + threadIdx.x;
    if (e < EE) atomicAdd(&counts[dst[e]], 1);
}

__global__ __launch_bounds__(1024) void scan_kernel(
    const int* __restrict__ counts, int* __restrict__ row_start, int* __restrict__ cursor)
{
    __shared__ int buf[1024];
    __shared__ int carry_s;
    int tid = threadIdx.x;
    if (tid == 0) carry_s = 0;
    __syncthreads();
    for (int t0 = 0; t0 < NN; t0 += 1024) {
        int i = t0 + tid;
        int v = (i < NN) ? counts[i] : 0;
        buf[tid] = v;
        __syncthreads();
        int c = carry_s;
        for (int o = 1; o < 1024; o <<= 1) {
            int u = (tid >= o) ? buf[tid - o] : 0;
            __syncthreads();
            buf[tid] += u;
            __syncthreads();
        }
        int excl = buf[tid] - v;
        if (i < NN) { row_start[i] = c + excl; cursor[i] = c + excl; }
        int total = buf[1023];
        __syncthreads();
        if (tid == 0) carry_s = c + total;
        __syncthreads();
    }
}

__global__ __launch_bounds__(256) void scatter_kernel(
    const int* __restrict__ src, const int* __restrict__ dst,
    const float* __restrict__ e_out, int* __restrict__ cursor, int2* __restrict__ bucket)
{
    int e = blockIdx.x * 256 + threadIdx.x;
    if (e >= EE) return;
    int d = dst[e];
    int pos = atomicAdd(&cursor[d], 1);
    bucket[pos] = make_int2(src[e], __float_as_int(e_out[e]));
}

// ---------------- neigh gather: one block per node, thread = feature ----------------
__global__ __launch_bounds__(256) void neigh_gather_kernel(
    const float* __restrict__ xn, const int2* __restrict__ bucket,
    const int* __restrict__ row_start, const int* __restrict__ counts,
    __bf16* __restrict__ nh, __bf16* __restrict__ nl)
{
    __shared__ int2 eb[128];
    int n = blockIdx.x;
    int f = threadIdx.x;
    int s0 = row_start[n];
    int cnt = counts[n];
    float acc = 0.0f;
    for (int t = 0; t < cnt; t += 128) {
        int m = (cnt - t < 128) ? (cnt - t) : 128;
        __syncthreads();
        if (f < m) eb[f] = bucket[s0 + t + f];
        __syncthreads();
        for (int i = 0; i < m; ++i) {
            int2 p = eb[i];
            acc = fmaf(__int_as_float(p.y), xn[(size_t)p.x * 256 + f], acc);
        }
    }
    float dv = (float)(cnt > 0 ? cnt : 1);
    float v = acc / dv;
    __bf16 h = (__bf16)v;
    nh[(size_t)n * 256 + f] = h;
    nl[(size_t)n * 256 + f] = (__bf16)(v - (float)h);
}

// ---------------- pose head ----------------
__global__ __launch_bounds__(128) void pose_kernel(
    const float* __restrict__ A_pre, const float* __restrict__ decw,
    const float* __restrict__ decb, float* __restrict__ pos, float* __restrict__ ori)
{
    __shared__ float arow[128];
    int b = blockIdx.x;
    arow[threadIdx.x] = A_pre[(size_t)(b * S_) * 128 + threadIdx.x];
    __syncthreads();
    int t = threadIdx.x;
    if (t < 7) {
        float s = decb[t];
        for (int c = 0; c < 128; ++c) s = fmaf(arow[c], decw[c * 7 + t], s);
        if (t < 3) pos[b * 3 + t] = s;
        else       ori[b * 4 + (t - 3)] = s;
    }
}

// ---------------- A = lrelu(A_pre); A /= max(||A||_S, eps) ----------------
__global__ __launch_bounds__(128) void norm_kernel(
    const float* __restrict__ A_pre, float* __restrict__ out)
{
    int b = blockIdx.x;
    int c = threadIdx.x;
    size_t base = (size_t)b * S_ * 128 + c;
    float ss = 0.0f;
    for (int s = 0; s < S_; ++s) {
        float v = A_pre[base + (size_t)s * 128];
        v = v > 0.0f ? v : NEG_SLOPE * v;
        ss = fmaf(v, v, ss);
    }
    float nrm = fmaxf(sqrtf(ss), EPS_);
    float inv = 1.0f / nrm;
    for (int s = 0; s < S_; ++s) {
        float v = A_pre[base + (size_t)s * 128];
        v = v > 0.0f ? v : NEG_SLOPE * v;
        out[base + (size_t)s * 128] = v * inv;
    }
}

extern "C" void kernel_launch(void* const* d_in, const int* in_sizes, int n_in,
                              void* d_out, int out_size, void* d_ws, size_t ws_size,
                              hipStream_t stream) {
    const float* x      = (const float*)d_in[0];
    const float* x_pose = (const float*)d_in[1];
    const float* m2w1 = (const float*)d_in[2];
    const float* m2b1 = (const float*)d_in[3];
    const float* m2w2 = (const float*)d_in[4];
    const float* m2b2 = (const float*)d_in[5];
    const float* m2w3 = (const float*)d_in[6];
    const float* m2b3 = (const float*)d_in[7];
    const float* m3w1 = (const float*)d_in[8];
    const float* m3b1 = (const float*)d_in[9];
    const float* m3w2 = (const float*)d_in[10];
    const float* m3b2 = (const float*)d_in[11];
    const float* m3w3 = (const float*)d_in[12];
    const float* m3b3 = (const float*)d_in[13];
    const float* encw = (const float*)d_in[14];
    const float* encb = (const float*)d_in[15];
    const float* ew1  = (const float*)d_in[16];
    const float* eb1  = (const float*)d_in[17];
    const float* ew2  = (const float*)d_in[18];
    const float* eb2  = (const float*)d_in[19];
    const float* ew3  = (const float*)d_in[20];
    const float* eb3  = (const float*)d_in[21];
    const float* ew4  = (const float*)d_in[22];
    const float* eb4  = (const float*)d_in[23];
    const float* wself  = (const float*)d_in[24];
    const float* wneigh = (const float*)d_in[25];
    const float* sageb  = (const float*)d_in[26];
    const float* decw = (const float*)d_in[27];
    const float* decb = (const float*)d_in[28];
    const int* esrc = (const int*)d_in[29];
    const int* edst = (const int*)d_in[30];
    float* out = (float*)d_out;

    // ---- workspace layout (byte allocator, 16B aligned) ----
    char* base = (char*)d_ws;
    size_t off = 0;
    auto alloc = [&](size_t bytes) { char* p = base + off; off += (bytes + 15) & ~15ULL; return p; };
    // fp32 buffers
    float* xn        = (float*)alloc((size_t)NN * 256 * 4);
    float* Y         = (float*)alloc((size_t)NN * 256 * 4);
    float* A_pre     = (float*)alloc((size_t)NN * 128 * 4);
    float* p1        = (float*)alloc((size_t)NN * 16 * 4);
    float* p2        = (float*)alloc((size_t)NN * 32 * 4);
    // CSR buffers
    int*  counts    = (int*)alloc((size_t)NN * 4);
    int*  row_start = (int*)alloc((size_t)NN * 4);
    int*  cursor    = (int*)alloc((size_t)NN * 4);
    int2* bucket    = (int2*)alloc((size_t)EE * 8);
    // hi/lo bf16 activation pairs (node path, fp32-equivalent precision)
    __bf16* xh   = (__bf16*)alloc((size_t)NN * 512 * 2);
    __bf16* xl   = (__bf16*)alloc((size_t)NN * 512 * 2);
    __bf16* t1h  = (__bf16*)alloc((size_t)NN * 256 * 2);
    __bf16* t1l  = (__bf16*)alloc((size_t)NN * 256 * 2);
    __bf16* t2h  = (__bf16*)alloc((size_t)NN * 128 * 2);
    __bf16* t2l  = (__bf16*)alloc((size_t)NN * 128 * 2);
    __bf16* hch  = (__bf16*)alloc((size_t)NN * 128 * 2);
    __bf16* hcl  = (__bf16*)alloc((size_t)NN * 128 * 2);
    __bf16* p2h  = (__bf16*)alloc((size_t)NN * 32 * 2);
    __bf16* p2l  = (__bf16*)alloc((size_t)NN * 32 * 2);
    __bf16* xnh  = (__bf16*)alloc((size_t)NN * 256 * 2);
    __bf16* xnl  = (__bf16*)alloc((size_t)NN * 256 * 2);
    __bf16* ngh  = (__bf16*)alloc((size_t)NN * 256 * 2);
    __bf16* ngl  = (__bf16*)alloc((size_t)NN * 256 * 2);
    // packed weights: node (hi/lo pairs)
    __bf16* wpn1h = (__bf16*)alloc((size_t)512 * 256 * 2);
    __bf16* wpn1l = (__bf16*)alloc((size_t)512 * 256 * 2);
    __bf16* wpn2h = (__bf16*)alloc((size_t)256 * 128 * 2);
    __bf16* wpn2l = (__bf16*)alloc((size_t)256 * 128 * 2);
    __bf16* wpn3h = (__bf16*)alloc((size_t)128 * 64 * 2);
    __bf16* wpn3l = (__bf16*)alloc((size_t)128 * 64 * 2);
    __bf16* wpp3h = (__bf16*)alloc((size_t)32 * 64 * 2);
    __bf16* wpp3l = (__bf16*)alloc((size_t)32 * 64 * 2);
    __bf16* wpenh = (__bf16*)alloc((size_t)128 * 256 * 2);
    __bf16* wpenl = (__bf16*)alloc((size_t)128 * 256 * 2);
    __bf16* wpsfh = (__bf16*)alloc((size_t)256 * 128 * 2);
    __bf16* wpsfl = (__bf16*)alloc((size_t)256 * 128 * 2);
    __bf16* wpngh = (__bf16*)alloc((size_t)256 * 128 * 2);
    __bf16* wpngl = (__bf16*)alloc((size_t)256 * 128 * 2);
    // packed weights: edge (single bf16, proven)
    __bf16* wpe1 = (__bf16*)alloc((size_t)256 * 256 * 2);
    __bf16* wpe2 = (__bf16*)alloc((size_t)256 * 128 * 2);
    __bf16* wpe3 = (__bf16*)alloc((size_t)128 * 64 * 2);

    // edge chunking (deterministic given ws_size): per-edge = s1(256) + s2(128) bf16
    long long avail_bytes = (long long)ws_size - (long long)off;
    const long long PER_EDGE_B = (256 + 128) * 2;   // 768 bytes
    long long ecmax = avail_bytes / PER_EDGE_B;
    ecmax = (ecmax / 128) * 128;
    if (ecmax > EE) ecmax = EE;
    if (ecmax < 128) ecmax = 128;
    int nchunk = (int)((EE + ecmax - 1) / ecmax);
    long long ec = ((EE + nchunk - 1) / nchunk + 127) / 128 * 128;

    __bf16* s1 = (__bf16*)(base + off);
    __bf16* s2 = s1 + ec * 256;

    hipMemsetAsync(counts, 0, (size_t)NN * sizeof(int), stream);

    // pack node weights (hi/lo)
    pack_w2_kernel<<<(512*256+255)/256, 256, 0, stream>>>(m2w1, wpn1h, wpn1l, 512, 256);
    pack_w2_kernel<<<(256*128+255)/256, 256, 0, stream>>>(m2w2, wpn2h, wpn2l, 256, 128);
    pack_w2_kernel<<<(128*64 +255)/256, 256, 0, stream>>>(m2w3, wpn3h, wpn3l, 128, 64);
    pack_w2_kernel<<<(32*64  +255)/256, 256, 0, stream>>>(m3w3, wpp3h, wpp3l, 32, 64);
    pack_w2_kernel<<<(128*256+255)/256, 256, 0, stream>>>(encw, wpenh, wpenl, 128, 256);
    pack_w2_kernel<<<(256*128+255)/256, 256, 0, stream>>>(wself, wpsfh, wpsfl, 256, 128);
    pack_w2_kernel<<<(256*128+255)/256, 256, 0, stream>>>(wneigh, wpngh, wpngl, 256, 128);
    // pack edge weights (single bf16)
    pack_w_kernel<<<(256*256+255)/256, 256, 0, stream>>>(ew1, wpe1, 256, 256);
    pack_w_kernel<<<(256*128+255)/256, 256, 0, stream>>>(ew2, wpe2, 256, 128);
    pack_w_kernel<<<(128*64 +255)/256, 256, 0, stream>>>(ew3, wpe3, 128, 64);

    // split x -> hi/lo
    split_bf16_kernel<<<(NN*512/8 + 255)/256, 256, 0, stream>>>(x, xh, xl, NN*512/8);

    const dim3 blk(256, 1, 1);
    const int MB = NN / 128;   // 102

    // node MLP branch (split-bf16 MFMA, fp32-equivalent)
    mmx_kernel<512,64,1,2,0><<<dim3(4, MB), blk, 0, stream>>>(xh, xl, wpn1h, wpn1l, m2b1, nullptr, t1h, t1l, 256);
    mmx_kernel<256,64,1,2,0><<<dim3(2, MB), blk, 0, stream>>>(t1h, t1l, wpn2h, wpn2l, m2b2, nullptr, t2h, t2l, 128);
    mmx_kernel<128,64,1,2,0><<<dim3(1, MB), blk, 0, stream>>>(t2h, t2l, wpn3h, wpn3l, m2b3, nullptr, hch, hcl, 128);

    // pose branch: tiny fp32 layers, split, then MFMA layer 3 into hcat cols 64..127
    gemm_kernel<1,0><<<dim3((NN+63)/64, 1), blk, 0, stream>>>(x_pose, 7,  m3w1, 16, m3b1, p1, 16, NN, 7, 16);
    gemm_kernel<1,0><<<dim3((NN+63)/64, 1), blk, 0, stream>>>(p1,    16,  m3w2, 32, m3b2, p2, 32, NN, 16, 32);
    split_bf16_kernel<<<(NN*32/8 + 255)/256, 256, 0, stream>>>(p2, p2h, p2l, NN*32/8);
    mmx_kernel< 32,64,1,2,0><<<dim3(1, MB), blk, 0, stream>>>(p2h, p2l, wpp3h, wpp3l, m3b3, nullptr, hch + 64, hcl + 64, 128);

    // encoder: fp32 xn (for neigh gather) + hi/lo xn (for SAGE, Y)
    mmx_kernel<128,64,1,3,0><<<dim3(4, MB), blk, 0, stream>>>(hch, hcl, wpenh, wpenl, encb, xn, xnh, xnl, 256);

    // Y = xn @ ew1 (node-level, replaces edge-level L1 GEMM via linearity)
    ygemm_kernel<256,128><<<dim3(2, MB), blk, 0, stream>>>(xnh, wpe1, Y, 256);

    // edge pipeline, chunked: gather->s1, L2 GEMM, fused L3+dot+sigmoid
    for (int c = 0; c < nchunk; ++c) {
        long long e0 = (long long)c * ec;
        int ecc = (int)((e0 + ec <= EE) ? ec : (EE - e0));   // multiple of 128
        gather_s1_kernel<<<(ecc * 32 + 255) / 256, 256, 0, stream>>>(
            Y, eb1, esrc, edst, s1, (int)e0, ecc);
        edge_gemm_kernel<256, 128, 128><<<dim3(1, ecc / 128), blk, 0, stream>>>(s1, wpe2, eb2, s2);
        edge_l3e_kernel<<<dim3(1, ecc / 128), blk, 0, stream>>>(
            s2, wpe3, eb3, ew4, eb4, out + E_OFF, (int)e0);
    }

    // CSR build + gather-based segment mean
    hist_kernel<<<(EE + 255) / 256, 256, 0, stream>>>(edst, counts);
    scan_kernel<<<1, 1024, 0, stream>>>(counts, row_start, cursor);
    scatter_kernel<<<(EE + 255) / 256, 256, 0, stream>>>(esrc, edst, out + E_OFF, cursor, bucket);
    neigh_gather_kernel<<<NN, 256, 0, stream>>>(xn, bucket, row_start, counts, ngh, ngl);

    // SAGE: A_pre = xn@wself + sageb; A_pre += neigh@wneigh  (split MFMA, fp32 out)
    mmx_kernel<256,64,0,1,0><<<dim3(2, MB), blk, 0, stream>>>(xnh, xnl, wpsfh, wpsfl, sageb,  A_pre, nullptr, nullptr, 128);
    mmx_kernel<256,64,0,1,1><<<dim3(2, MB), blk, 0, stream>>>(ngh, ngl, wpngh, wpngl, nullptr, A_pre, nullptr, nullptr, 128);

    pose_kernel<<<B_, 128, 0, stream>>>(A_pre, decw, decb, out + POS_OFF, out + ORI_OFF);
    norm_kernel<<<B_, 128, 0, stream>>>(A_pre, out);
}

// Round 9
// 632.684 us; speedup vs baseline: 8.5883x; 1.2972x over previous
//
#include <hip/hip_runtime.h>
#include <math.h>

#define B_ 256
#define S_ 51
#define NN (B_*S_)            // 13056 nodes = 102*128
#define DEG_ 50
#define EE (NN*DEG_)          // 652800 edges
#define NEG_SLOPE 0.01f
#define EPS_ 1e-12f

#define A_SIZE (NN*128)
#define E_OFF  A_SIZE
#define POS_OFF (A_SIZE + EE)
#define ORI_OFF (POS_OFF + B_*3)

typedef __bf16 bf16x8 __attribute__((ext_vector_type(8)));
typedef __bf16 bf16x4 __attribute__((ext_vector_type(4)));
typedef float  f32x4  __attribute__((ext_vector_type(4)));

typedef __attribute__((address_space(1))) const void GVoid;
typedef __attribute__((address_space(3))) void LVoid;

__device__ __forceinline__ float act_apply(float v, int ACT) {
    if (ACT == 1) return fmaxf(v, 0.0f);
    if (ACT == 2) return v > 0.0f ? v : NEG_SLOPE * v;
    return v;
}

// ---------------- fp32 tiled GEMM (tiny pose layers only) ----------------
template<int ACT, int ACC>
__global__ __launch_bounds__(256) void gemm_kernel(
    const float* __restrict__ A, int lda,
    const float* __restrict__ W, int ldw,
    const float* __restrict__ bias,
    float* __restrict__ C, int ldc,
    int M, int K, int N)
{
    __shared__ float As[32][68];
    __shared__ float Ws[32][68];

    const int tid = threadIdx.x;
    const int tx = tid & 15;
    const int ty = tid >> 4;
    const int m0 = blockIdx.x * 64;
    const int n0 = blockIdx.y * 64;

    float acc[4][4];
#pragma unroll
    for (int i = 0; i < 4; ++i)
#pragma unroll
        for (int j = 0; j < 4; ++j) acc[i][j] = 0.0f;

    const int ktiles = (K + 31) >> 5;
    for (int kt = 0; kt < ktiles; ++kt) {
        const int k0 = kt << 5;
#pragma unroll
        for (int it = 0; it < 8; ++it) {
            int idx = tid + it * 256;
            int kk = idx & 31;
            int r  = idx >> 5;
            float v = 0.0f;
            int gr = m0 + r, gk = k0 + kk;
            if (gr < M && gk < K) v = A[(size_t)gr * lda + gk];
            As[kk][r] = v;
        }
#pragma unroll
        for (int it = 0; it < 8; ++it) {
            int idx = tid + it * 256;
            int c  = idx & 63;
            int kk = idx >> 6;
            float v = 0.0f;
            int gk = k0 + kk, gc = n0 + c;
            if (gk < K && gc < N) v = W[(size_t)gk * ldw + gc];
            Ws[kk][c] = v;
        }
        __syncthreads();
#pragma unroll
        for (int kk = 0; kk < 32; ++kk) {
            float4 av = *(const float4*)&As[kk][ty * 4];
            float4 wv = *(const float4*)&Ws[kk][tx * 4];
            float a[4] = {av.x, av.y, av.z, av.w};
            float w[4] = {wv.x, wv.y, wv.z, wv.w};
#pragma unroll
            for (int i = 0; i < 4; ++i)
#pragma unroll
                for (int j = 0; j < 4; ++j)
                    acc[i][j] = fmaf(a[i], w[j], acc[i][j]);
        }
        __syncthreads();
    }

#pragma unroll
    for (int i = 0; i < 4; ++i) {
        int row = m0 + ty * 4 + i;
        if (row >= M) continue;
#pragma unroll
        for (int j = 0; j < 4; ++j) {
            int col = n0 + tx * 4 + j;
            if (col >= N) continue;
            float v = acc[i][j];
            if (bias) v += bias[col];
            if (ACC) v += C[(size_t)row * ldc + col];
            C[(size_t)row * ldc + col] = act_apply(v, ACT);
        }
    }
}

// ---------------- weight pack: W[K][N] fp32 -> MFMA-fragment-ordered bf16 ----------------
__global__ __launch_bounds__(256) void pack_w_kernel(
    const float* __restrict__ W, __bf16* __restrict__ Wp, int K, int N)
{
    int t = blockIdx.x * 256 + threadIdx.x;
    if (t >= K * N) return;
    int j    = t & 7;
    int lane = (t >> 3) & 63;
    int rkt  = t >> 9;
    int KT = K >> 5;
    int kt = rkt % KT;
    int cf = rkt / KT;
    int k = kt * 32 + (lane >> 4) * 8 + j;
    int n = cf * 16 + (lane & 15);
    Wp[t] = (__bf16)W[(size_t)k * N + n];
}

// same, but hi/lo split pair (fp32-equivalent precision)
__global__ __launch_bounds__(256) void pack_w2_kernel(
    const float* __restrict__ W, __bf16* __restrict__ Wph, __bf16* __restrict__ Wpl,
    int K, int N)
{
    int t = blockIdx.x * 256 + threadIdx.x;
    if (t >= K * N) return;
    int j    = t & 7;
    int lane = (t >> 3) & 63;
    int rkt  = t >> 9;
    int KT = K >> 5;
    int kt = rkt % KT;
    int cf = rkt / KT;
    int k = kt * 32 + (lane >> 4) * 8 + j;
    int n = cf * 16 + (lane & 15);
    float v = W[(size_t)k * N + n];
    __bf16 h = (__bf16)v;
    Wph[t] = h;
    Wpl[t] = (__bf16)(v - (float)h);
}

// ---------------- Y = A @ W -> bf16 out (node-level L1 via linearity) ----------------
template<int K, int BN>
__global__ __launch_bounds__(256) void ygemm_kernel(
    const __bf16* __restrict__ A, const __bf16* __restrict__ Wp,
    __bf16* __restrict__ C, int ldc)
{
    constexpr int NCF = BN / 16;
    __shared__ __bf16 As[128 * 32];

    const int tid  = threadIdx.x;
    const int lane = tid & 63;
    const int w    = tid >> 6;
    const int lg   = lane >> 4;
    const int li   = lane & 15;
    const int n_blk = blockIdx.x * BN;
    const int m_blk = blockIdx.y * 128;

    f32x4 acc[2][NCF];
#pragma unroll
    for (int mf = 0; mf < 2; ++mf)
#pragma unroll
        for (int cf = 0; cf < NCF; ++cf)
#pragma unroll
            for (int r = 0; r < 4; ++r) acc[mf][cf][r] = 0.0f;

    const __bf16* WpBase = Wp + ((size_t)(n_blk / 16) * (K / 32)) * 512 + (size_t)lane * 8;

    for (int kt = 0; kt < K / 32; ++kt) {
#pragma unroll
        for (int i = 0; i < 2; ++i) {
            int slot0 = i * 256 + w * 64;
            int s  = slot0 + lane;
            int r  = s >> 2;
            int sl = s & 3;
            int kb = sl ^ ((r >> 1) & 3);
            const __bf16* g = A + (size_t)(m_blk + r) * K + kt * 32 + kb * 8;
            __builtin_amdgcn_global_load_lds((GVoid*)g,
                                             (LVoid*)((char*)As + (size_t)slot0 * 16),
                                             16, 0, 0);
        }
        bf16x8 bf[NCF];
        const __bf16* Wb = WpBase + (size_t)kt * 512;
#pragma unroll
        for (int cf = 0; cf < NCF; ++cf)
            bf[cf] = *(const bf16x8*)(Wb + (size_t)cf * (K / 32) * 512);

        __syncthreads();

        bf16x8 af[2];
#pragma unroll
        for (int mf = 0; mf < 2; ++mf) {
            int row = w * 32 + mf * 16 + li;
            int sl  = lg ^ ((row >> 1) & 3);
            af[mf] = *(const bf16x8*)((const char*)As + (size_t)row * 64 + sl * 16);
        }
#pragma unroll
        for (int mf = 0; mf < 2; ++mf)
#pragma unroll
            for (int cf = 0; cf < NCF; ++cf)
                acc[mf][cf] = __builtin_amdgcn_mfma_f32_16x16x32_bf16(
                    af[mf], bf[cf], acc[mf][cf], 0, 0, 0);
        __syncthreads();
    }

#pragma unroll
    for (int mf = 0; mf < 2; ++mf) {
        int row0 = m_blk + w * 32 + mf * 16 + lg * 4;
#pragma unroll
        for (int cf = 0; cf < NCF; ++cf) {
            int col = n_blk + cf * 16 + li;
#pragma unroll
            for (int r = 0; r < 4; ++r)
                C[(size_t)(row0 + r) * ldc + col] = (__bf16)acc[mf][cf][r];
        }
    }
}

// ---------------- fused gather + L1 + L2 edge GEMM ----------------
// s2 = lrelu( lrelu(Yb[src]-Yb[dst]+eb1) @ ew2 + eb2 ), 128 edges/block, K=256, N=128.
// A-tile reg-staged into the SAME swizzled LDS layout as the proven kernel:
// As[r][sl] (16B slots) holds k-block kb = sl ^ ((r>>1)&3).
__global__ __launch_bounds__(256) void edge_fused_kernel(
    const __bf16* __restrict__ Yb, const float* __restrict__ eb1,
    const int* __restrict__ src, const int* __restrict__ dst,
    const __bf16* __restrict__ Wp, const float* __restrict__ eb2,
    __bf16* __restrict__ s2, int e0)
{
    constexpr int K = 256, NCF = 8;
    __shared__ __bf16 As[128 * 32];   // 8 KB

    const int tid  = threadIdx.x;
    const int lane = tid & 63;
    const int w    = tid >> 6;
    const int lg   = lane >> 4;
    const int li   = lane & 15;
    const int m_blk = blockIdx.x * 128;

    // staging assignment: thread -> (row, 16-elem half)
    const int sr = tid >> 1;
    const int sh = tid & 1;
    const int e  = e0 + m_blk + sr;
    const __bf16* ys = Yb + (size_t)src[e] * 256;
    const __bf16* yd = Yb + (size_t)dst[e] * 256;
    const int swz = (sr >> 1) & 3;
    char* wp0 = (char*)As + sr * 64 + (((sh * 2)     ^ swz) * 16);
    char* wp1 = (char*)As + sr * 64 + (((sh * 2 + 1) ^ swz) * 16);

    f32x4 acc[2][NCF];
#pragma unroll
    for (int mf = 0; mf < 2; ++mf)
#pragma unroll
        for (int cf = 0; cf < NCF; ++cf)
#pragma unroll
            for (int r = 0; r < 4; ++r) acc[mf][cf][r] = 0.0f;

    const __bf16* WpBase = Wp + (size_t)lane * 8;   // n_blk = 0

    for (int kt = 0; kt < K / 32; ++kt) {
        const int k0 = kt * 32 + sh * 16;
        // gather 16 bf16 from src row and dst row (two 16B loads each)
        bf16x8 a0 = *(const bf16x8*)(ys + k0);
        bf16x8 a1 = *(const bf16x8*)(ys + k0 + 8);
        bf16x8 b0 = *(const bf16x8*)(yd + k0);
        bf16x8 b1 = *(const bf16x8*)(yd + k0 + 8);
        bf16x8 o0, o1;
#pragma unroll
        for (int j = 0; j < 8; ++j) {
            float v0 = (float)a0[j] - (float)b0[j] + eb1[k0 + j];
            float v1 = (float)a1[j] - (float)b1[j] + eb1[k0 + 8 + j];
            v0 = v0 > 0.0f ? v0 : NEG_SLOPE * v0;
            v1 = v1 > 0.0f ? v1 : NEG_SLOPE * v1;
            o0[j] = (__bf16)v0;
            o1[j] = (__bf16)v1;
        }
        *(bf16x8*)wp0 = o0;   // kb = sh*2
        *(bf16x8*)wp1 = o1;   // kb = sh*2+1

        // B fragments (packed weights, L2-resident)
        bf16x8 bf[NCF];
        const __bf16* Wb = WpBase + (size_t)kt * 512;
#pragma unroll
        for (int cf = 0; cf < NCF; ++cf)
            bf[cf] = *(const bf16x8*)(Wb + (size_t)cf * (K / 32) * 512);

        __syncthreads();   // ds_writes visible

        bf16x8 af[2];
#pragma unroll
        for (int mf = 0; mf < 2; ++mf) {
            int row = w * 32 + mf * 16 + li;
            int sl  = lg ^ ((row >> 1) & 3);
            af[mf] = *(const bf16x8*)((const char*)As + (size_t)row * 64 + sl * 16);
        }
#pragma unroll
        for (int mf = 0; mf < 2; ++mf)
#pragma unroll
            for (int cf = 0; cf < NCF; ++cf)
                acc[mf][cf] = __builtin_amdgcn_mfma_f32_16x16x32_bf16(
                    af[mf], bf[cf], acc[mf][cf], 0, 0, 0);
        __syncthreads();   // As reusable next kt
    }

    float bv[NCF];
#pragma unroll
    for (int cf = 0; cf < NCF; ++cf) bv[cf] = eb2[cf * 16 + li];
#pragma unroll
    for (int mf = 0; mf < 2; ++mf) {
        int row0 = m_blk + w * 32 + mf * 16 + lg * 4;
#pragma unroll
        for (int cf = 0; cf < NCF; ++cf) {
            int col = cf * 16 + li;
#pragma unroll
            for (int r = 0; r < 4; ++r) {
                float v = acc[mf][cf][r] + bv[cf];
                v = v > 0.0f ? v : NEG_SLOPE * v;
                s2[(size_t)(row0 + r) * 128 + col] = (__bf16)v;
            }
        }
    }
}

// ---------------- L3 + dot + sigmoid fused: e = sigmoid(lrelu(s2@ew3+eb3)@ew4+eb4) ----------------
__global__ __launch_bounds__(256) void edge_l3e_kernel(
    const __bf16* __restrict__ A, const __bf16* __restrict__ Wp,
    const float* __restrict__ eb3, const float* __restrict__ ew4,
    const float* __restrict__ eb4, float* __restrict__ e_out, int e0)
{
    constexpr int K = 128, NCF = 4;
    __shared__ __bf16 As[128 * 32];

    const int tid  = threadIdx.x;
    const int lane = tid & 63;
    const int w    = tid >> 6;
    const int lg   = lane >> 4;
    const int li   = lane & 15;
    const int m_blk = blockIdx.y * 128;

    f32x4 acc[2][NCF];
#pragma unroll
    for (int mf = 0; mf < 2; ++mf)
#pragma unroll
        for (int cf = 0; cf < NCF; ++cf)
#pragma unroll
            for (int r = 0; r < 4; ++r) acc[mf][cf][r] = 0.0f;

    const __bf16* WpBase = Wp + (size_t)lane * 8;

    for (int kt = 0; kt < K / 32; ++kt) {
#pragma unroll
        for (int i = 0; i < 2; ++i) {
            int slot0 = i * 256 + w * 64;
            int s  = slot0 + lane;
            int r  = s >> 2;
            int sl = s & 3;
            int kb = sl ^ ((r >> 1) & 3);
            const __bf16* g = A + (size_t)(m_blk + r) * K + kt * 32 + kb * 8;
            __builtin_amdgcn_global_load_lds((GVoid*)g,
                                             (LVoid*)((char*)As + (size_t)slot0 * 16),
                                             16, 0, 0);
        }
        bf16x8 bf[NCF];
        const __bf16* Wb = WpBase + (size_t)kt * 512;
#pragma unroll
        for (int cf = 0; cf < NCF; ++cf)
            bf[cf] = *(const bf16x8*)(Wb + (size_t)cf * (K / 32) * 512);

        __syncthreads();

        bf16x8 af[2];
#pragma unroll
        for (int mf = 0; mf < 2; ++mf) {
            int row = w * 32 + mf * 16 + li;
            int sl  = lg ^ ((row >> 1) & 3);
            af[mf] = *(const bf16x8*)((const char*)As + (size_t)row * 64 + sl * 16);
        }
#pragma unroll
        for (int mf = 0; mf < 2; ++mf)
#pragma unroll
            for (int cf = 0; cf < NCF; ++cf)
                acc[mf][cf] = __builtin_amdgcn_mfma_f32_16x16x32_bf16(
                    af[mf], bf[cf], acc[mf][cf], 0, 0, 0);
        __syncthreads();
    }

    float p[2][4];
#pragma unroll
    for (int mf = 0; mf < 2; ++mf)
#pragma unroll
        for (int r = 0; r < 4; ++r) p[mf][r] = 0.0f;
#pragma unroll
    for (int cf = 0; cf < NCF; ++cf) {
        int col = cf * 16 + li;
        float b3 = eb3[col];
        float w4 = ew4[col];
#pragma unroll
        for (int mf = 0; mf < 2; ++mf)
#pragma unroll
            for (int r = 0; r < 4; ++r) {
                float v = acc[mf][cf][r] + b3;
                v = v > 0.0f ? v : NEG_SLOPE * v;
                p[mf][r] = fmaf(v, w4, p[mf][r]);
            }
    }
#pragma unroll
    for (int mf = 0; mf < 2; ++mf)
#pragma unroll
        for (int r = 0; r < 4; ++r) {
#pragma unroll
            for (int m = 1; m < 16; m <<= 1)
                p[mf][r] += __shfl_xor(p[mf][r], m, 16);
        }
    if (li == 0) {
        float b4 = eb4[0];
#pragma unroll
        for (int mf = 0; mf < 2; ++mf)
#pragma unroll
            for (int r = 0; r < 4; ++r) {
                int ei = m_blk + w * 32 + mf * 16 + lg * 4 + r;
                float ev = 1.0f / (1.0f + expf(-(p[mf][r] + b4)));
                e_out[e0 + ei] = ev;
            }
    }
}

// ---------------- split-bf16 MFMA GEMM (fp32-equivalent precision, node path) ----------------
template<int K, int BN, int ACT, int OUT, int ACC>
__global__ __launch_bounds__(256) void mmx_kernel(
    const __bf16* __restrict__ Ah, const __bf16* __restrict__ Al,
    const __bf16* __restrict__ Wph, const __bf16* __restrict__ Wpl,
    const float* __restrict__ bias,
    float* __restrict__ Cf, __bf16* __restrict__ Ch, __bf16* __restrict__ Cl, int ldc)
{
    constexpr int NCF = BN / 16;
    __shared__ __bf16 AsH[128 * 32];
    __shared__ __bf16 AsL[128 * 32];

    const int tid  = threadIdx.x;
    const int lane = tid & 63;
    const int w    = tid >> 6;
    const int lg   = lane >> 4;
    const int li   = lane & 15;
    const int n_blk = blockIdx.x * BN;
    const int m_blk = blockIdx.y * 128;

    f32x4 acc[2][NCF];
#pragma unroll
    for (int mf = 0; mf < 2; ++mf)
#pragma unroll
        for (int cf = 0; cf < NCF; ++cf)
#pragma unroll
            for (int r = 0; r < 4; ++r) acc[mf][cf][r] = 0.0f;

    const size_t wbase = ((size_t)(n_blk / 16) * (K / 32)) * 512 + (size_t)lane * 8;

    for (int kt = 0; kt < K / 32; ++kt) {
#pragma unroll
        for (int i = 0; i < 2; ++i) {
            int slot0 = i * 256 + w * 64;
            int s  = slot0 + lane;
            int r  = s >> 2;
            int sl = s & 3;
            int kb = sl ^ ((r >> 1) & 3);
            size_t goff = (size_t)(m_blk + r) * K + kt * 32 + kb * 8;
            __builtin_amdgcn_global_load_lds((GVoid*)(Ah + goff),
                                             (LVoid*)((char*)AsH + (size_t)slot0 * 16),
                                             16, 0, 0);
            __builtin_amdgcn_global_load_lds((GVoid*)(Al + goff),
                                             (LVoid*)((char*)AsL + (size_t)slot0 * 16),
                                             16, 0, 0);
        }
        bf16x8 bfh[NCF], bfl[NCF];
        const size_t wo = wbase + (size_t)kt * 512;
#pragma unroll
        for (int cf = 0; cf < NCF; ++cf) {
            size_t o = wo + (size_t)cf * (K / 32) * 512;
            bfh[cf] = *(const bf16x8*)(Wph + o);
            bfl[cf] = *(const bf16x8*)(Wpl + o);
        }

        __syncthreads();

        bf16x8 afh[2], afl[2];
#pragma unroll
        for (int mf = 0; mf < 2; ++mf) {
            int row = w * 32 + mf * 16 + li;
            int sl  = lg ^ ((row >> 1) & 3);
            afh[mf] = *(const bf16x8*)((const char*)AsH + (size_t)row * 64 + sl * 16);
            afl[mf] = *(const bf16x8*)((const char*)AsL + (size_t)row * 64 + sl * 16);
        }
#pragma unroll
        for (int mf = 0; mf < 2; ++mf)
#pragma unroll
            for (int cf = 0; cf < NCF; ++cf) {
                acc[mf][cf] = __builtin_amdgcn_mfma_f32_16x16x32_bf16(
                    afh[mf], bfh[cf], acc[mf][cf], 0, 0, 0);
                acc[mf][cf] = __builtin_amdgcn_mfma_f32_16x16x32_bf16(
                    afh[mf], bfl[cf], acc[mf][cf], 0, 0, 0);
                acc[mf][cf] = __builtin_amdgcn_mfma_f32_16x16x32_bf16(
                    afl[mf], bfh[cf], acc[mf][cf], 0, 0, 0);
            }
        __syncthreads();
    }

    float bv[NCF];
#pragma unroll
    for (int cf = 0; cf < NCF; ++cf) bv[cf] = bias ? bias[n_blk + cf * 16 + li] : 0.0f;
#pragma unroll
    for (int mf = 0; mf < 2; ++mf) {
        int row0 = m_blk + w * 32 + mf * 16 + lg * 4;
#pragma unroll
        for (int cf = 0; cf < NCF; ++cf) {
            int col = n_blk + cf * 16 + li;
#pragma unroll
            for (int r = 0; r < 4; ++r) {
                float v = acc[mf][cf][r] + bv[cf];
                size_t idx = (size_t)(row0 + r) * ldc + col;
                if (ACC) v += Cf[idx];
                v = act_apply(v, ACT);
                if (OUT & 1) Cf[idx] = v;
                if (OUT & 2) {
                    __bf16 h = (__bf16)v;
                    Ch[idx] = h;
                    Cl[idx] = (__bf16)(v - (float)h);
                }
            }
        }
    }
}

// ---------------- fp32 -> hi/lo bf16 split (8 elems/thread) ----------------
__global__ __launch_bounds__(256) void split_bf16_kernel(
    const float* __restrict__ in, __bf16* __restrict__ hi, __bf16* __restrict__ lo, int n8)
{
    int i = blockIdx.x * 256 + threadIdx.x;
    if (i >= n8) return;
    const float4* p = (const float4*)in + (size_t)i * 2;
    float4 a = p[0], b = p[1];
    float v[8] = {a.x, a.y, a.z, a.w, b.x, b.y, b.z, b.w};
    bf16x8 oh, ol;
#pragma unroll
    for (int j = 0; j < 8; ++j) {
        __bf16 h = (__bf16)v[j];
        oh[j] = h;
        ol[j] = (__bf16)(v[j] - (float)h);
    }
    *(bf16x8*)(hi + (size_t)i * 8) = oh;
    *(bf16x8*)(lo + (size_t)i * 8) = ol;
}

// ---------------- CSR build: histogram / scan / scatter ----------------
__global__ __launch_bounds__(256) void hist_kernel(
    const int* __restrict__ dst, int* __restrict__ counts)
{
    int e = blockIdx.x * 256 + threadIdx.x;
    if (e < EE) atomicAdd(&counts[dst[e]], 1);
}

__global__ __launch_bounds__(1024) void scan_kernel(
    const int* __restrict__ counts, int* __restrict__ row_start, int* __restrict__ cursor)
{
    __shared__ int buf[1024];
    __shared__ int carry_s;
    int tid = threadIdx.x;
    if (tid == 0) carry_s = 0;
    __syncthreads();
    for (int t0 = 0; t0 < NN; t0 += 1024) {
        int i = t0 + tid;
        int v = (i < NN) ? counts[i] : 0;
        buf[tid] = v;
        __syncthreads();
        int c = carry_s;
        for (int o = 1; o < 1024; o <<= 1) {
            int u = (tid >= o) ? buf[tid - o] : 0;
            __syncthreads();
            buf[tid] += u;
            __syncthreads();
        }
        int excl = buf[tid] - v;
        if (i < NN) { row_start[i] = c + excl; cursor[i] = c + excl; }
        int total = buf[1023];
        __syncthreads();
        if (tid == 0) carry_s = c + total;
        __syncthreads();
    }
}

__global__ __launch_bounds__(256) void scatter_kernel(
    const int* __restrict__ src, const int* __restrict__ dst,
    const float* __restrict__ e_out, int* __restrict__ cursor, int2* __restrict__ bucket)
{
    int e = blockIdx.x * 256 + threadIdx.x;
    if (e >= EE) return;
    int d = dst[e];
    int pos = atomicAdd(&cursor[d], 1);
    bucket[pos] = make_int2(src[e], __float_as_int(e_out[e]));
}

// ---------------- neigh gather: one block per node, thread = feature ----------------
__global__ __launch_bounds__(256) void neigh_gather_kernel(
    const float* __restrict__ xn, const int2* __restrict__ bucket,
    const int* __restrict__ row_start, const int* __restrict__ counts,
    __bf16* __restrict__ nh, __bf16* __restrict__ nl)
{
    __shared__ int2 eb[128];
    int n = blockIdx.x;
    int f = threadIdx.x;
    int s0 = row_start[n];
    int cnt = counts[n];
    float acc = 0.0f;
    for (int t = 0; t < cnt; t += 128) {
        int m = (cnt - t < 128) ? (cnt - t) : 128;
        __syncthreads();
        if (f < m) eb[f] = bucket[s0 + t + f];
        __syncthreads();
        for (int i = 0; i < m; ++i) {
            int2 p = eb[i];
            acc = fmaf(__int_as_float(p.y), xn[(size_t)p.x * 256 + f], acc);
        }
    }
    float dv = (float)(cnt > 0 ? cnt : 1);
    float v = acc / dv;
    __bf16 h = (__bf16)v;
    nh[(size_t)n * 256 + f] = h;
    nl[(size_t)n * 256 + f] = (__bf16)(v - (float)h);
}

// ---------------- pose head ----------------
__global__ __launch_bounds__(128) void pose_kernel(
    const float* __restrict__ A_pre, const float* __restrict__ decw,
    const float* __restrict__ decb, float* __restrict__ pos, float* __restrict__ ori)
{
    __shared__ float arow[128];
    int b = blockIdx.x;
    arow[threadIdx.x] = A_pre[(size_t)(b * S_) * 128 + threadIdx.x];
    __syncthreads();
    int t = threadIdx.x;
    if (t < 7) {
        float s = decb[t];
        for (int c = 0; c < 128; ++c) s = fmaf(arow[c], decw[c * 7 + t], s);
        if (t < 3) pos[b * 3 + t] = s;
        else       ori[b * 4 + (t - 3)] = s;
    }
}

// ---------------- A = lrelu(A_pre); A /= max(||A||_S, eps) ----------------
__global__ __launch_bounds__(128) void norm_kernel(
    const float* __restrict__ A_pre, float* __restrict__ out)
{
    int b = blockIdx.x;
    int c = threadIdx.x;
    size_t base = (size_t)b * S_ * 128 + c;
    float ss = 0.0f;
    for (int s = 0; s < S_; ++s) {
        float v = A_pre[base + (size_t)s * 128];
        v = v > 0.0f ? v : NEG_SLOPE * v;
        ss = fmaf(v, v, ss);
    }
    float nrm = fmaxf(sqrtf(ss), EPS_);
    float inv = 1.0f / nrm;
    for (int s = 0; s < S_; ++s) {
        float v = A_pre[base + (size_t)s * 128];
        v = v > 0.0f ? v : NEG_SLOPE * v;
        out[base + (size_t)s * 128] = v * inv;
    }
}

extern "C" void kernel_launch(void* const* d_in, const int* in_sizes, int n_in,
                              void* d_out, int out_size, void* d_ws, size_t ws_size,
                              hipStream_t stream) {
    const float* x      = (const float*)d_in[0];
    const float* x_pose = (const float*)d_in[1];
    const float* m2w1 = (const float*)d_in[2];
    const float* m2b1 = (const float*)d_in[3];
    const float* m2w2 = (const float*)d_in[4];
    const float* m2b2 = (const float*)d_in[5];
    const float* m2w3 = (const float*)d_in[6];
    const float* m2b3 = (const float*)d_in[7];
    const float* m3w1 = (const float*)d_in[8];
    const float* m3b1 = (const float*)d_in[9];
    const float* m3w2 = (const float*)d_in[10];
    const float* m3b2 = (const float*)d_in[11];
    const float* m3w3 = (const float*)d_in[12];
    const float* m3b3 = (const float*)d_in[13];
    const float* encw = (const float*)d_in[14];
    const float* encb = (const float*)d_in[15];
    const float* ew1  = (const float*)d_in[16];
    const float* eb1  = (const float*)d_in[17];
    const float* ew2  = (const float*)d_in[18];
    const float* eb2  = (const float*)d_in[19];
    const float* ew3  = (const float*)d_in[20];
    const float* eb3  = (const float*)d_in[21];
    const float* ew4  = (const float*)d_in[22];
    const float* eb4  = (const float*)d_in[23];
    const float* wself  = (const float*)d_in[24];
    const float* wneigh = (const float*)d_in[25];
    const float* sageb  = (const float*)d_in[26];
    const float* decw = (const float*)d_in[27];
    const float* decb = (const float*)d_in[28];
    const int* esrc = (const int*)d_in[29];
    const int* edst = (const int*)d_in[30];
    float* out = (float*)d_out;

    // ---- workspace layout (byte allocator, 16B aligned) ----
    char* base = (char*)d_ws;
    size_t off = 0;
    auto alloc = [&](size_t bytes) { char* p = base + off; off += (bytes + 15) & ~15ULL; return p; };
    // fp32 buffers
    float* xn        = (float*)alloc((size_t)NN * 256 * 4);
    float* A_pre     = (float*)alloc((size_t)NN * 128 * 4);
    float* p1        = (float*)alloc((size_t)NN * 16 * 4);
    float* p2        = (float*)alloc((size_t)NN * 32 * 4);
    // CSR buffers
    int*  counts    = (int*)alloc((size_t)NN * 4);
    int*  row_start = (int*)alloc((size_t)NN * 4);
    int*  cursor    = (int*)alloc((size_t)NN * 4);
    int2* bucket    = (int2*)alloc((size_t)EE * 8);
    // bf16 buffers
    __bf16* Yb   = (__bf16*)alloc((size_t)NN * 256 * 2);
    __bf16* xh   = (__bf16*)alloc((size_t)NN * 512 * 2);
    __bf16* xl   = (__bf16*)alloc((size_t)NN * 512 * 2);
    __bf16* t1h  = (__bf16*)alloc((size_t)NN * 256 * 2);
    __bf16* t1l  = (__bf16*)alloc((size_t)NN * 256 * 2);
    __bf16* t2h  = (__bf16*)alloc((size_t)NN * 128 * 2);
    __bf16* t2l  = (__bf16*)alloc((size_t)NN * 128 * 2);
    __bf16* hch  = (__bf16*)alloc((size_t)NN * 128 * 2);
    __bf16* hcl  = (__bf16*)alloc((size_t)NN * 128 * 2);
    __bf16* p2h  = (__bf16*)alloc((size_t)NN * 32 * 2);
    __bf16* p2l  = (__bf16*)alloc((size_t)NN * 32 * 2);
    __bf16* xnh  = (__bf16*)alloc((size_t)NN * 256 * 2);
    __bf16* xnl  = (__bf16*)alloc((size_t)NN * 256 * 2);
    __bf16* ngh  = (__bf16*)alloc((size_t)NN * 256 * 2);
    __bf16* ngl  = (__bf16*)alloc((size_t)NN * 256 * 2);
    // packed weights: node (hi/lo pairs)
    __bf16* wpn1h = (__bf16*)alloc((size_t)512 * 256 * 2);
    __bf16* wpn1l = (__bf16*)alloc((size_t)512 * 256 * 2);
    __bf16* wpn2h = (__bf16*)alloc((size_t)256 * 128 * 2);
    __bf16* wpn2l = (__bf16*)alloc((size_t)256 * 128 * 2);
    __bf16* wpn3h = (__bf16*)alloc((size_t)128 * 64 * 2);
    __bf16* wpn3l = (__bf16*)alloc((size_t)128 * 64 * 2);
    __bf16* wpp3h = (__bf16*)alloc((size_t)32 * 64 * 2);
    __bf16* wpp3l = (__bf16*)alloc((size_t)32 * 64 * 2);
    __bf16* wpenh = (__bf16*)alloc((size_t)128 * 256 * 2);
    __bf16* wpenl = (__bf16*)alloc((size_t)128 * 256 * 2);
    __bf16* wpsfh = (__bf16*)alloc((size_t)256 * 128 * 2);
    __bf16* wpsfl = (__bf16*)alloc((size_t)256 * 128 * 2);
    __bf16* wpngh = (__bf16*)alloc((size_t)256 * 128 * 2);
    __bf16* wpngl = (__bf16*)alloc((size_t)256 * 128 * 2);
    // packed weights: edge (single bf16, proven)
    __bf16* wpe1 = (__bf16*)alloc((size_t)256 * 256 * 2);
    __bf16* wpe2 = (__bf16*)alloc((size_t)256 * 128 * 2);
    __bf16* wpe3 = (__bf16*)alloc((size_t)128 * 64 * 2);

    // edge chunking: per-edge = s2 (128 bf16) only
    long long avail_bytes = (long long)ws_size - (long long)off;
    const long long PER_EDGE_B = 128 * 2;   // 256 bytes
    long long ecmax = avail_bytes / PER_EDGE_B;
    ecmax = (ecmax / 128) * 128;
    if (ecmax > EE) ecmax = EE;
    if (ecmax < 128) ecmax = 128;
    int nchunk = (int)((EE + ecmax - 1) / ecmax);
    long long ec = ((EE + nchunk - 1) / nchunk + 127) / 128 * 128;

    __bf16* s2 = (__bf16*)(base + off);

    hipMemsetAsync(counts, 0, (size_t)NN * sizeof(int), stream);

    // pack node weights (hi/lo)
    pack_w2_kernel<<<(512*256+255)/256, 256, 0, stream>>>(m2w1, wpn1h, wpn1l, 512, 256);
    pack_w2_kernel<<<(256*128+255)/256, 256, 0, stream>>>(m2w2, wpn2h, wpn2l, 256, 128);
    pack_w2_kernel<<<(128*64 +255)/256, 256, 0, stream>>>(m2w3, wpn3h, wpn3l, 128, 64);
    pack_w2_kernel<<<(32*64  +255)/256, 256, 0, stream>>>(m3w3, wpp3h, wpp3l, 32, 64);
    pack_w2_kernel<<<(128*256+255)/256, 256, 0, stream>>>(encw, wpenh, wpenl, 128, 256);
    pack_w2_kernel<<<(256*128+255)/256, 256, 0, stream>>>(wself, wpsfh, wpsfl, 256, 128);
    pack_w2_kernel<<<(256*128+255)/256, 256, 0, stream>>>(wneigh, wpngh, wpngl, 256, 128);
    // pack edge weights (single bf16)
    pack_w_kernel<<<(256*256+255)/256, 256, 0, stream>>>(ew1, wpe1, 256, 256);
    pack_w_kernel<<<(256*128+255)/256, 256, 0, stream>>>(ew2, wpe2, 256, 128);
    pack_w_kernel<<<(128*64 +255)/256, 256, 0, stream>>>(ew3, wpe3, 128, 64);

    // split x -> hi/lo
    split_bf16_kernel<<<(NN*512/8 + 255)/256, 256, 0, stream>>>(x, xh, xl, NN*512/8);

    const dim3 blk(256, 1, 1);
    const int MB = NN / 128;   // 102

    // node MLP branch (split-bf16 MFMA, fp32-equivalent)
    mmx_kernel<512,64,1,2,0><<<dim3(4, MB), blk, 0, stream>>>(xh, xl, wpn1h, wpn1l, m2b1, nullptr, t1h, t1l, 256);
    mmx_kernel<256,64,1,2,0><<<dim3(2, MB), blk, 0, stream>>>(t1h, t1l, wpn2h, wpn2l, m2b2, nullptr, t2h, t2l, 128);
    mmx_kernel<128,64,1,2,0><<<dim3(1, MB), blk, 0, stream>>>(t2h, t2l, wpn3h, wpn3l, m2b3, nullptr, hch, hcl, 128);

    // pose branch: tiny fp32 layers, split, then MFMA layer 3 into hcat cols 64..127
    gemm_kernel<1,0><<<dim3((NN+63)/64, 1), blk, 0, stream>>>(x_pose, 7,  m3w1, 16, m3b1, p1, 16, NN, 7, 16);
    gemm_kernel<1,0><<<dim3((NN+63)/64, 1), blk, 0, stream>>>(p1,    16,  m3w2, 32, m3b2, p2, 32, NN, 16, 32);
    split_bf16_kernel<<<(NN*32/8 + 255)/256, 256, 0, stream>>>(p2, p2h, p2l, NN*32/8);
    mmx_kernel< 32,64,1,2,0><<<dim3(1, MB), blk, 0, stream>>>(p2h, p2l, wpp3h, wpp3l, m3b3, nullptr, hch + 64, hcl + 64, 128);

    // encoder: fp32 xn (for neigh gather) + hi/lo xn (for SAGE, Y)
    mmx_kernel<128,64,1,3,0><<<dim3(4, MB), blk, 0, stream>>>(hch, hcl, wpenh, wpenl, encb, xn, xnh, xnl, 256);

    // Y = xn @ ew1 -> bf16 (node-level L1 via linearity)
    ygemm_kernel<256,128><<<dim3(2, MB), blk, 0, stream>>>(xnh, wpe1, Yb, 256);

    // edge pipeline, chunked: fused gather+L1+L2, then fused L3+dot+sigmoid
    for (int c = 0; c < nchunk; ++c) {
        long long e0 = (long long)c * ec;
        int ecc = (int)((e0 + ec <= EE) ? ec : (EE - e0));   // multiple of 128
        edge_fused_kernel<<<dim3(ecc / 128), blk, 0, stream>>>(
            Yb, eb1, esrc, edst, wpe2, eb2, s2, (int)e0);
        edge_l3e_kernel<<<dim3(1, ecc / 128), blk, 0, stream>>>(
            s2, wpe3, eb3, ew4, eb4, out + E_OFF, (int)e0);
    }

    // CSR build + gather-based segment mean
    hist_kernel<<<(EE + 255) / 256, 256, 0, stream>>>(edst, counts);
    scan_kernel<<<1, 1024, 0, stream>>>(counts, row_start, cursor);
    scatter_kernel<<<(EE + 255) / 256, 256, 0, stream>>>(esrc, edst, out + E_OFF, cursor, bucket);
    neigh_gather_kernel<<<NN, 256, 0, stream>>>(xn, bucket, row_start, counts, ngh, ngl);

    // SAGE: A_pre = xn@wself + sageb; A_pre += neigh@wneigh  (split MFMA, fp32 out)
    mmx_kernel<256,64,0,1,0><<<dim3(2, MB), blk, 0, stream>>>(xnh, xnl, wpsfh, wpsfl, sageb,  A_pre, nullptr, nullptr, 128);
    mmx_kernel<256,64,0,1,1><<<dim3(2, MB), blk, 0, stream>>>(ngh, ngl, wpngh, wpngl, nullptr, A_pre, nullptr, nullptr, 128);

    pose_kernel<<<B_, 128, 0, stream>>>(A_pre, decw, decb, out + POS_OFF, out + ORI_OFF);
    norm_kernel<<<B_, 128, 0, stream>>>(A_pre, out);
}

// Round 10
// 632.004 us; speedup vs baseline: 8.5975x; 1.0011x over previous
//
#include <hip/hip_runtime.h>
#include <math.h>

#define B_ 256
#define S_ 51
#define NN (B_*S_)            // 13056 nodes = 102*128
#define DEG_ 50
#define EE (NN*DEG_)          // 652800 edges = 5100*128
#define NEG_SLOPE 0.01f
#define EPS_ 1e-12f

#define A_SIZE (NN*128)
#define E_OFF  A_SIZE
#define POS_OFF (A_SIZE + EE)
#define ORI_OFF (POS_OFF + B_*3)

typedef __bf16 bf16x8 __attribute__((ext_vector_type(8)));
typedef __bf16 bf16x4 __attribute__((ext_vector_type(4)));
typedef float  f32x4  __attribute__((ext_vector_type(4)));

typedef __attribute__((address_space(1))) const void GVoid;
typedef __attribute__((address_space(3))) void LVoid;

__device__ __forceinline__ float act_apply(float v, int ACT) {
    if (ACT == 1) return fmaxf(v, 0.0f);
    if (ACT == 2) return v > 0.0f ? v : NEG_SLOPE * v;
    return v;
}

// ---------------- fp32 tiled GEMM (tiny pose layers only) ----------------
template<int ACT, int ACC>
__global__ __launch_bounds__(256) void gemm_kernel(
    const float* __restrict__ A, int lda,
    const float* __restrict__ W, int ldw,
    const float* __restrict__ bias,
    float* __restrict__ C, int ldc,
    int M, int K, int N)
{
    __shared__ float As[32][68];
    __shared__ float Ws[32][68];

    const int tid = threadIdx.x;
    const int tx = tid & 15;
    const int ty = tid >> 4;
    const int m0 = blockIdx.x * 64;
    const int n0 = blockIdx.y * 64;

    float acc[4][4];
#pragma unroll
    for (int i = 0; i < 4; ++i)
#pragma unroll
        for (int j = 0; j < 4; ++j) acc[i][j] = 0.0f;

    const int ktiles = (K + 31) >> 5;
    for (int kt = 0; kt < ktiles; ++kt) {
        const int k0 = kt << 5;
#pragma unroll
        for (int it = 0; it < 8; ++it) {
            int idx = tid + it * 256;
            int kk = idx & 31;
            int r  = idx >> 5;
            float v = 0.0f;
            int gr = m0 + r, gk = k0 + kk;
            if (gr < M && gk < K) v = A[(size_t)gr * lda + gk];
            As[kk][r] = v;
        }
#pragma unroll
        for (int it = 0; it < 8; ++it) {
            int idx = tid + it * 256;
            int c  = idx & 63;
            int kk = idx >> 6;
            float v = 0.0f;
            int gk = k0 + kk, gc = n0 + c;
            if (gk < K && gc < N) v = W[(size_t)gk * ldw + gc];
            Ws[kk][c] = v;
        }
        __syncthreads();
#pragma unroll
        for (int kk = 0; kk < 32; ++kk) {
            float4 av = *(const float4*)&As[kk][ty * 4];
            float4 wv = *(const float4*)&Ws[kk][tx * 4];
            float a[4] = {av.x, av.y, av.z, av.w};
            float w[4] = {wv.x, wv.y, wv.z, wv.w};
#pragma unroll
            for (int i = 0; i < 4; ++i)
#pragma unroll
                for (int j = 0; j < 4; ++j)
                    acc[i][j] = fmaf(a[i], w[j], acc[i][j]);
        }
        __syncthreads();
    }

#pragma unroll
    for (int i = 0; i < 4; ++i) {
        int row = m0 + ty * 4 + i;
        if (row >= M) continue;
#pragma unroll
        for (int j = 0; j < 4; ++j) {
            int col = n0 + tx * 4 + j;
            if (col >= N) continue;
            float v = acc[i][j];
            if (bias) v += bias[col];
            if (ACC) v += C[(size_t)row * ldc + col];
            C[(size_t)row * ldc + col] = act_apply(v, ACT);
        }
    }
}

// ---------------- weight pack: W[K][N] fp32 -> MFMA-fragment-ordered bf16 ----------------
__global__ __launch_bounds__(256) void pack_w_kernel(
    const float* __restrict__ W, __bf16* __restrict__ Wp, int K, int N)
{
    int t = blockIdx.x * 256 + threadIdx.x;
    if (t >= K * N) return;
    int j    = t & 7;
    int lane = (t >> 3) & 63;
    int rkt  = t >> 9;
    int KT = K >> 5;
    int kt = rkt % KT;
    int cf = rkt / KT;
    int k = kt * 32 + (lane >> 4) * 8 + j;
    int n = cf * 16 + (lane & 15);
    Wp[t] = (__bf16)W[(size_t)k * N + n];
}

// same, but hi/lo split pair (fp32-equivalent precision)
__global__ __launch_bounds__(256) void pack_w2_kernel(
    const float* __restrict__ W, __bf16* __restrict__ Wph, __bf16* __restrict__ Wpl,
    int K, int N)
{
    int t = blockIdx.x * 256 + threadIdx.x;
    if (t >= K * N) return;
    int j    = t & 7;
    int lane = (t >> 3) & 63;
    int rkt  = t >> 9;
    int KT = K >> 5;
    int kt = rkt % KT;
    int cf = rkt / KT;
    int k = kt * 32 + (lane >> 4) * 8 + j;
    int n = cf * 16 + (lane & 15);
    float v = W[(size_t)k * N + n];
    __bf16 h = (__bf16)v;
    Wph[t] = h;
    Wpl[t] = (__bf16)(v - (float)h);
}

// ---------------- Y = A @ W -> bf16 out (node-level L1 via linearity) ----------------
template<int K, int BN>
__global__ __launch_bounds__(256) void ygemm_kernel(
    const __bf16* __restrict__ A, const __bf16* __restrict__ Wp,
    __bf16* __restrict__ C, int ldc)
{
    constexpr int NCF = BN / 16;
    __shared__ __bf16 As[128 * 32];

    const int tid  = threadIdx.x;
    const int lane = tid & 63;
    const int w    = tid >> 6;
    const int lg   = lane >> 4;
    const int li   = lane & 15;
    const int n_blk = blockIdx.x * BN;
    const int m_blk = blockIdx.y * 128;

    f32x4 acc[2][NCF];
#pragma unroll
    for (int mf = 0; mf < 2; ++mf)
#pragma unroll
        for (int cf = 0; cf < NCF; ++cf)
#pragma unroll
            for (int r = 0; r < 4; ++r) acc[mf][cf][r] = 0.0f;

    const __bf16* WpBase = Wp + ((size_t)(n_blk / 16) * (K / 32)) * 512 + (size_t)lane * 8;

    for (int kt = 0; kt < K / 32; ++kt) {
#pragma unroll
        for (int i = 0; i < 2; ++i) {
            int slot0 = i * 256 + w * 64;
            int s  = slot0 + lane;
            int r  = s >> 2;
            int sl = s & 3;
            int kb = sl ^ ((r >> 1) & 3);
            const __bf16* g = A + (size_t)(m_blk + r) * K + kt * 32 + kb * 8;
            __builtin_amdgcn_global_load_lds((GVoid*)g,
                                             (LVoid*)((char*)As + (size_t)slot0 * 16),
                                             16, 0, 0);
        }
        bf16x8 bf[NCF];
        const __bf16* Wb = WpBase + (size_t)kt * 512;
#pragma unroll
        for (int cf = 0; cf < NCF; ++cf)
            bf[cf] = *(const bf16x8*)(Wb + (size_t)cf * (K / 32) * 512);

        __syncthreads();

        bf16x8 af[2];
#pragma unroll
        for (int mf = 0; mf < 2; ++mf) {
            int row = w * 32 + mf * 16 + li;
            int sl  = lg ^ ((row >> 1) & 3);
            af[mf] = *(const bf16x8*)((const char*)As + (size_t)row * 64 + sl * 16);
        }
#pragma unroll
        for (int mf = 0; mf < 2; ++mf)
#pragma unroll
            for (int cf = 0; cf < NCF; ++cf)
                acc[mf][cf] = __builtin_amdgcn_mfma_f32_16x16x32_bf16(
                    af[mf], bf[cf], acc[mf][cf], 0, 0, 0);
        __syncthreads();
    }

#pragma unroll
    for (int mf = 0; mf < 2; ++mf) {
        int row0 = m_blk + w * 32 + mf * 16 + lg * 4;
#pragma unroll
        for (int cf = 0; cf < NCF; ++cf) {
            int col = n_blk + cf * 16 + li;
#pragma unroll
            for (int r = 0; r < 4; ++r)
                C[(size_t)(row0 + r) * ldc + col] = (__bf16)acc[mf][cf][r];
        }
    }
}

// ---------------- fully fused edge kernel: gather + L1 + L2 + L3 + dot + sigmoid ----------------
// e = sigmoid( lrelu( lrelu( lrelu(Yb[src]-Yb[dst]+eb1) @ ew2 + eb2 ) @ ew3 + eb3 ) @ ew4 + eb4 )
// 128 edges/block, single dispatch over all EE edges. s2 passes L2->L3 via 32 KB LDS tile.
__global__ __launch_bounds__(256) void edge_full_kernel(
    const __bf16* __restrict__ Yb, const float* __restrict__ eb1,
    const int* __restrict__ src, const int* __restrict__ dst,
    const __bf16* __restrict__ Wp2, const float* __restrict__ eb2,
    const __bf16* __restrict__ Wp3, const float* __restrict__ eb3,
    const float* __restrict__ ew4, const float* __restrict__ eb4,
    float* __restrict__ e_out)
{
    constexpr int K = 256, NCF = 8;   // L2 stage
    __shared__ __bf16 As[128 * 32];   // 8 KB A-tile staging
    __shared__ __bf16 S2[128 * 128];  // 32 KB s2 tile (slot-swizzled)

    const int tid  = threadIdx.x;
    const int lane = tid & 63;
    const int w    = tid >> 6;
    const int lg   = lane >> 4;
    const int li   = lane & 15;
    const int m_blk = blockIdx.x * 128;

    // staging assignment: thread -> (row, 16-elem half)
    const int sr = tid >> 1;
    const int sh = tid & 1;
    const int e  = m_blk + sr;
    const __bf16* ys = Yb + (size_t)src[e] * 256;
    const __bf16* yd = Yb + (size_t)dst[e] * 256;
    const int swz = (sr >> 1) & 3;
    char* wp0 = (char*)As + sr * 64 + (((sh * 2)     ^ swz) * 16);
    char* wp1 = (char*)As + sr * 64 + (((sh * 2 + 1) ^ swz) * 16);

    f32x4 acc[2][NCF];
#pragma unroll
    for (int mf = 0; mf < 2; ++mf)
#pragma unroll
        for (int cf = 0; cf < NCF; ++cf)
#pragma unroll
            for (int r = 0; r < 4; ++r) acc[mf][cf][r] = 0.0f;

    const __bf16* WpBase2 = Wp2 + (size_t)lane * 8;

    for (int kt = 0; kt < K / 32; ++kt) {
        const int k0 = kt * 32 + sh * 16;
        bf16x8 a0 = *(const bf16x8*)(ys + k0);
        bf16x8 a1 = *(const bf16x8*)(ys + k0 + 8);
        bf16x8 b0 = *(const bf16x8*)(yd + k0);
        bf16x8 b1 = *(const bf16x8*)(yd + k0 + 8);
        bf16x8 o0, o1;
#pragma unroll
        for (int j = 0; j < 8; ++j) {
            float v0 = (float)a0[j] - (float)b0[j] + eb1[k0 + j];
            float v1 = (float)a1[j] - (float)b1[j] + eb1[k0 + 8 + j];
            v0 = v0 > 0.0f ? v0 : NEG_SLOPE * v0;
            v1 = v1 > 0.0f ? v1 : NEG_SLOPE * v1;
            o0[j] = (__bf16)v0;
            o1[j] = (__bf16)v1;
        }
        *(bf16x8*)wp0 = o0;
        *(bf16x8*)wp1 = o1;

        bf16x8 bf[NCF];
        const __bf16* Wb = WpBase2 + (size_t)kt * 512;
#pragma unroll
        for (int cf = 0; cf < NCF; ++cf)
            bf[cf] = *(const bf16x8*)(Wb + (size_t)cf * (K / 32) * 512);

        __syncthreads();

        bf16x8 af[2];
#pragma unroll
        for (int mf = 0; mf < 2; ++mf) {
            int row = w * 32 + mf * 16 + li;
            int sl  = lg ^ ((row >> 1) & 3);
            af[mf] = *(const bf16x8*)((const char*)As + (size_t)row * 64 + sl * 16);
        }
#pragma unroll
        for (int mf = 0; mf < 2; ++mf)
#pragma unroll
            for (int cf = 0; cf < NCF; ++cf)
                acc[mf][cf] = __builtin_amdgcn_mfma_f32_16x16x32_bf16(
                    af[mf], bf[cf], acc[mf][cf], 0, 0, 0);
        __syncthreads();
    }

    // ---- L2 epilogue -> S2 in LDS (slot-swizzle: sl ^= row&7) ----
#pragma unroll
    for (int mf = 0; mf < 2; ++mf) {
        int row0 = w * 32 + mf * 16 + lg * 4;
#pragma unroll
        for (int cf = 0; cf < NCF; ++cf) {
            int col = cf * 16 + li;
            float bv = eb2[col];
            int sl = col >> 3;
            int sb = col & 7;
#pragma unroll
            for (int r = 0; r < 4; ++r) {
                int row = row0 + r;
                float v = acc[mf][cf][r] + bv;
                v = v > 0.0f ? v : NEG_SLOPE * v;
                S2[row * 128 + ((sl ^ (row & 7)) << 3) + sb] = (__bf16)v;
            }
        }
    }
    __syncthreads();

    // ---- L3 stage: K=128, N=64, A from S2 (swizzled read) ----
    constexpr int NCF3 = 4;
    f32x4 acc3[2][NCF3];
#pragma unroll
    for (int mf = 0; mf < 2; ++mf)
#pragma unroll
        for (int cf = 0; cf < NCF3; ++cf)
#pragma unroll
            for (int r = 0; r < 4; ++r) acc3[mf][cf][r] = 0.0f;

    const __bf16* WpBase3 = Wp3 + (size_t)lane * 8;
#pragma unroll
    for (int kt = 0; kt < 4; ++kt) {
        bf16x8 af[2];
#pragma unroll
        for (int mf = 0; mf < 2; ++mf) {
            int row = w * 32 + mf * 16 + li;
            int sl  = (kt * 4 + lg) ^ (row & 7);
            af[mf] = *(const bf16x8*)&S2[row * 128 + (sl << 3)];
        }
        bf16x8 bf[NCF3];
        const __bf16* Wb = WpBase3 + (size_t)kt * 512;
#pragma unroll
        for (int cf = 0; cf < NCF3; ++cf)
            bf[cf] = *(const bf16x8*)(Wb + (size_t)cf * 4 * 512);
#pragma unroll
        for (int mf = 0; mf < 2; ++mf)
#pragma unroll
            for (int cf = 0; cf < NCF3; ++cf)
                acc3[mf][cf] = __builtin_amdgcn_mfma_f32_16x16x32_bf16(
                    af[mf], bf[cf], acc3[mf][cf], 0, 0, 0);
    }

    // ---- epilogue: s3 = lrelu(acc3 + eb3); dot ew4; 16-lane reduce; sigmoid ----
    float p[2][4];
#pragma unroll
    for (int mf = 0; mf < 2; ++mf)
#pragma unroll
        for (int r = 0; r < 4; ++r) p[mf][r] = 0.0f;
#pragma unroll
    for (int cf = 0; cf < NCF3; ++cf) {
        int col = cf * 16 + li;
        float b3 = eb3[col];
        float w4 = ew4[col];
#pragma unroll
        for (int mf = 0; mf < 2; ++mf)
#pragma unroll
            for (int r = 0; r < 4; ++r) {
                float v = acc3[mf][cf][r] + b3;
                v = v > 0.0f ? v : NEG_SLOPE * v;
                p[mf][r] = fmaf(v, w4, p[mf][r]);
            }
    }
#pragma unroll
    for (int mf = 0; mf < 2; ++mf)
#pragma unroll
        for (int r = 0; r < 4; ++r) {
#pragma unroll
            for (int m = 1; m < 16; m <<= 1)
                p[mf][r] += __shfl_xor(p[mf][r], m, 16);
        }
    if (li == 0) {
        float b4 = eb4[0];
#pragma unroll
        for (int mf = 0; mf < 2; ++mf)
#pragma unroll
            for (int r = 0; r < 4; ++r) {
                int ei = m_blk + w * 32 + mf * 16 + lg * 4 + r;
                float ev = 1.0f / (1.0f + expf(-(p[mf][r] + b4)));
                e_out[ei] = ev;
            }
    }
}

// ---------------- split-bf16 MFMA GEMM (fp32-equivalent precision, node path) ----------------
template<int K, int BN, int ACT, int OUT, int ACC>
__global__ __launch_bounds__(256) void mmx_kernel(
    const __bf16* __restrict__ Ah, const __bf16* __restrict__ Al,
    const __bf16* __restrict__ Wph, const __bf16* __restrict__ Wpl,
    const float* __restrict__ bias,
    float* __restrict__ Cf, __bf16* __restrict__ Ch, __bf16* __restrict__ Cl, int ldc)
{
    constexpr int NCF = BN / 16;
    __shared__ __bf16 AsH[128 * 32];
    __shared__ __bf16 AsL[128 * 32];

    const int tid  = threadIdx.x;
    const int lane = tid & 63;
    const int w    = tid >> 6;
    const int lg   = lane >> 4;
    const int li   = lane & 15;
    const int n_blk = blockIdx.x * BN;
    const int m_blk = blockIdx.y * 128;

    f32x4 acc[2][NCF];
#pragma unroll
    for (int mf = 0; mf < 2; ++mf)
#pragma unroll
        for (int cf = 0; cf < NCF; ++cf)
#pragma unroll
            for (int r = 0; r < 4; ++r) acc[mf][cf][r] = 0.0f;

    const size_t wbase = ((size_t)(n_blk / 16) * (K / 32)) * 512 + (size_t)lane * 8;

    for (int kt = 0; kt < K / 32; ++kt) {
#pragma unroll
        for (int i = 0; i < 2; ++i) {
            int slot0 = i * 256 + w * 64;
            int s  = slot0 + lane;
            int r  = s >> 2;
            int sl = s & 3;
            int kb = sl ^ ((r >> 1) & 3);
            size_t goff = (size_t)(m_blk + r) * K + kt * 32 + kb * 8;
            __builtin_amdgcn_global_load_lds((GVoid*)(Ah + goff),
                                             (LVoid*)((char*)AsH + (size_t)slot0 * 16),
                                             16, 0, 0);
            __builtin_amdgcn_global_load_lds((GVoid*)(Al + goff),
                                             (LVoid*)((char*)AsL + (size_t)slot0 * 16),
                                             16, 0, 0);
        }
        bf16x8 bfh[NCF], bfl[NCF];
        const size_t wo = wbase + (size_t)kt * 512;
#pragma unroll
        for (int cf = 0; cf < NCF; ++cf) {
            size_t o = wo + (size_t)cf * (K / 32) * 512;
            bfh[cf] = *(const bf16x8*)(Wph + o);
            bfl[cf] = *(const bf16x8*)(Wpl + o);
        }

        __syncthreads();

        bf16x8 afh[2], afl[2];
#pragma unroll
        for (int mf = 0; mf < 2; ++mf) {
            int row = w * 32 + mf * 16 + li;
            int sl  = lg ^ ((row >> 1) & 3);
            afh[mf] = *(const bf16x8*)((const char*)AsH + (size_t)row * 64 + sl * 16);
            afl[mf] = *(const bf16x8*)((const char*)AsL + (size_t)row * 64 + sl * 16);
        }
#pragma unroll
        for (int mf = 0; mf < 2; ++mf)
#pragma unroll
            for (int cf = 0; cf < NCF; ++cf) {
                acc[mf][cf] = __builtin_amdgcn_mfma_f32_16x16x32_bf16(
                    afh[mf], bfh[cf], acc[mf][cf], 0, 0, 0);
                acc[mf][cf] = __builtin_amdgcn_mfma_f32_16x16x32_bf16(
                    afh[mf], bfl[cf], acc[mf][cf], 0, 0, 0);
                acc[mf][cf] = __builtin_amdgcn_mfma_f32_16x16x32_bf16(
                    afl[mf], bfh[cf], acc[mf][cf], 0, 0, 0);
            }
        __syncthreads();
    }

    float bv[NCF];
#pragma unroll
    for (int cf = 0; cf < NCF; ++cf) bv[cf] = bias ? bias[n_blk + cf * 16 + li] : 0.0f;
#pragma unroll
    for (int mf = 0; mf < 2; ++mf) {
        int row0 = m_blk + w * 32 + mf * 16 + lg * 4;
#pragma unroll
        for (int cf = 0; cf < NCF; ++cf) {
            int col = n_blk + cf * 16 + li;
#pragma unroll
            for (int r = 0; r < 4; ++r) {
                float v = acc[mf][cf][r] + bv[cf];
                size_t idx = (size_t)(row0 + r) * ldc + col;
                if (ACC) v += Cf[idx];
                v = act_apply(v, ACT);
                if (OUT & 1) Cf[idx] = v;
                if (OUT & 2) {
                    __bf16 h = (__bf16)v;
                    Ch[idx] = h;
                    Cl[idx] = (__bf16)(v - (float)h);
                }
            }
        }
    }
}

// ---------------- fp32 -> hi/lo bf16 split (8 elems/thread) ----------------
__global__ __launch_bounds__(256) void split_bf16_kernel(
    const float* __restrict__ in, __bf16* __restrict__ hi, __bf16* __restrict__ lo, int n8)
{
    int i = blockIdx.x * 256 + threadIdx.x;
    if (i >= n8) return;
    const float4* p = (const float4*)in + (size_t)i * 2;
    float4 a = p[0], b = p[1];
    float v[8] = {a.x, a.y, a.z, a.w, b.x, b.y, b.z, b.w};
    bf16x8 oh, ol;
#pragma unroll
    for (int j = 0; j < 8; ++j) {
        __bf16 h = (__bf16)v[j];
        oh[j] = h;
        ol[j] = (__bf16)(v[j] - (float)h);
    }
    *(bf16x8*)(hi + (size_t)i * 8) = oh;
    *(bf16x8*)(lo + (size_t)i * 8) = ol;
}

// ---------------- CSR build: histogram / scan / scatter ----------------
__global__ __launch_bounds__(256) void hist_kernel(
    const int* __restrict__ dst, int* __restrict__ counts)
{
    int e = blockIdx.x * 256 + threadIdx.x;
    if (e < EE) atomicAdd(&counts[dst[e]], 1);
}

__global__ __launch_bounds__(1024) void scan_kernel(
    const int* __restrict__ counts, int* __restrict__ row_start, int* __restrict__ cursor)
{
    __shared__ int buf[1024];
    __shared__ int carry_s;
    int tid = threadIdx.x;
    if (tid == 0) carry_s = 0;
    __syncthreads();
    for (int t0 = 0; t0 < NN; t0 += 1024) {
        int i = t0 + tid;
        int v = (i < NN) ? counts[i] : 0;
        buf[tid] = v;
        __syncthreads();
        int c = carry_s;
        for (int o = 1; o < 1024; o <<= 1) {
            int u = (tid >= o) ? buf[tid - o] : 0;
            __syncthreads();
            buf[tid] += u;
            __syncthreads();
        }
        int excl = buf[tid] - v;
        if (i < NN) { row_start[i] = c + excl; cursor[i] = c + excl; }
        int total = buf[1023];
        __syncthreads();
        if (tid == 0) carry_s = c + total;
        __syncthreads();
    }
}

__global__ __launch_bounds__(256) void scatter_kernel(
    const int* __restrict__ src, const int* __restrict__ dst,
    const float* __restrict__ e_out, int* __restrict__ cursor, int2* __restrict__ bucket)
{
    int e = blockIdx.x * 256 + threadIdx.x;
    if (e >= EE) return;
    int d = dst[e];
    int pos = atomicAdd(&cursor[d], 1);
    bucket[pos] = make_int2(src[e], __float_as_int(e_out[e]));
}

// ---------------- neigh gather: one block per node, thread = feature ----------------
__global__ __launch_bounds__(256) void neigh_gather_kernel(
    const float* __restrict__ xn, const int2* __restrict__ bucket,
    const int* __restrict__ row_start, const int* __restrict__ counts,
    __bf16* __restrict__ nh, __bf16* __restrict__ nl)
{
    __shared__ int2 eb[128];
    int n = blockIdx.x;
    int f = threadIdx.x;
    int s0 = row_start[n];
    int cnt = counts[n];
    float acc = 0.0f;
    for (int t = 0; t < cnt; t += 128) {
        int m = (cnt - t < 128) ? (cnt - t) : 128;
        __syncthreads();
        if (f < m) eb[f] = bucket[s0 + t + f];
        __syncthreads();
        for (int i = 0; i < m; ++i) {
            int2 p = eb[i];
            acc = fmaf(__int_as_float(p.y), xn[(size_t)p.x * 256 + f], acc);
        }
    }
    float dv = (float)(cnt > 0 ? cnt : 1);
    float v = acc / dv;
    __bf16 h = (__bf16)v;
    nh[(size_t)n * 256 + f] = h;
    nl[(size_t)n * 256 + f] = (__bf16)(v - (float)h);
}

// ---------------- pose head ----------------
__global__ __launch_bounds__(128) void pose_kernel(
    const float* __restrict__ A_pre, const float* __restrict__ decw,
    const float* __restrict__ decb, float* __restrict__ pos, float* __restrict__ ori)
{
    __shared__ float arow[128];
    int b = blockIdx.x;
    arow[threadIdx.x] = A_pre[(size_t)(b * S_) * 128 + threadIdx.x];
    __syncthreads();
    int t = threadIdx.x;
    if (t < 7) {
        float s = decb[t];
        for (int c = 0; c < 128; ++c) s = fmaf(arow[c], decw[c * 7 + t], s);
        if (t < 3) pos[b * 3 + t] = s;
        else       ori[b * 4 + (t - 3)] = s;
    }
}

// ---------------- A = lrelu(A_pre); A /= max(||A||_S, eps) ----------------
__global__ __launch_bounds__(128) void norm_kernel(
    const float* __restrict__ A_pre, float* __restrict__ out)
{
    int b = blockIdx.x;
    int c = threadIdx.x;
    size_t base = (size_t)b * S_ * 128 + c;
    float ss = 0.0f;
    for (int s = 0; s < S_; ++s) {
        float v = A_pre[base + (size_t)s * 128];
        v = v > 0.0f ? v : NEG_SLOPE * v;
        ss = fmaf(v, v, ss);
    }
    float nrm = fmaxf(sqrtf(ss), EPS_);
    float inv = 1.0f / nrm;
    for (int s = 0; s < S_; ++s) {
        float v = A_pre[base + (size_t)s * 128];
        v = v > 0.0f ? v : NEG_SLOPE * v;
        out[base + (size_t)s * 128] = v * inv;
    }
}

extern "C" void kernel_launch(void* const* d_in, const int* in_sizes, int n_in,
                              void* d_out, int out_size, void* d_ws, size_t ws_size,
                              hipStream_t stream) {
    const float* x      = (const float*)d_in[0];
    const float* x_pose = (const float*)d_in[1];
    const float* m2w1 = (const float*)d_in[2];
    const float* m2b1 = (const float*)d_in[3];
    const float* m2w2 = (const float*)d_in[4];
    const float* m2b2 = (const float*)d_in[5];
    const float* m2w3 = (const float*)d_in[6];
    const float* m2b3 = (const float*)d_in[7];
    const float* m3w1 = (const float*)d_in[8];
    const float* m3b1 = (const float*)d_in[9];
    const float* m3w2 = (const float*)d_in[10];
    const float* m3b2 = (const float*)d_in[11];
    const float* m3w3 = (const float*)d_in[12];
    const float* m3b3 = (const float*)d_in[13];
    const float* encw = (const float*)d_in[14];
    const float* encb = (const float*)d_in[15];
    const float* ew1  = (const float*)d_in[16];
    const float* eb1  = (const float*)d_in[17];
    const float* ew2  = (const float*)d_in[18];
    const float* eb2  = (const float*)d_in[19];
    const float* ew3  = (const float*)d_in[20];
    const float* eb3  = (const float*)d_in[21];
    const float* ew4  = (const float*)d_in[22];
    const float* eb4  = (const float*)d_in[23];
    const float* wself  = (const float*)d_in[24];
    const float* wneigh = (const float*)d_in[25];
    const float* sageb  = (const float*)d_in[26];
    const float* decw = (const float*)d_in[27];
    const float* decb = (const float*)d_in[28];
    const int* esrc = (const int*)d_in[29];
    const int* edst = (const int*)d_in[30];
    float* out = (float*)d_out;

    // ---- workspace layout (byte allocator, 16B aligned) ----
    char* base = (char*)d_ws;
    size_t off = 0;
    auto alloc = [&](size_t bytes) { char* p = base + off; off += (bytes + 15) & ~15ULL; return p; };
    // fp32 buffers
    float* xn        = (float*)alloc((size_t)NN * 256 * 4);
    float* A_pre     = (float*)alloc((size_t)NN * 128 * 4);
    float* p1        = (float*)alloc((size_t)NN * 16 * 4);
    float* p2        = (float*)alloc((size_t)NN * 32 * 4);
    // CSR buffers
    int*  counts    = (int*)alloc((size_t)NN * 4);
    int*  row_start = (int*)alloc((size_t)NN * 4);
    int*  cursor    = (int*)alloc((size_t)NN * 4);
    int2* bucket    = (int2*)alloc((size_t)EE * 8);
    // bf16 buffers
    __bf16* Yb   = (__bf16*)alloc((size_t)NN * 256 * 2);
    __bf16* xh   = (__bf16*)alloc((size_t)NN * 512 * 2);
    __bf16* xl   = (__bf16*)alloc((size_t)NN * 512 * 2);
    __bf16* t1h  = (__bf16*)alloc((size_t)NN * 256 * 2);
    __bf16* t1l  = (__bf16*)alloc((size_t)NN * 256 * 2);
    __bf16* t2h  = (__bf16*)alloc((size_t)NN * 128 * 2);
    __bf16* t2l  = (__bf16*)alloc((size_t)NN * 128 * 2);
    __bf16* hch  = (__bf16*)alloc((size_t)NN * 128 * 2);
    __bf16* hcl  = (__bf16*)alloc((size_t)NN * 128 * 2);
    __bf16* p2h  = (__bf16*)alloc((size_t)NN * 32 * 2);
    __bf16* p2l  = (__bf16*)alloc((size_t)NN * 32 * 2);
    __bf16* xnh  = (__bf16*)alloc((size_t)NN * 256 * 2);
    __bf16* xnl  = (__bf16*)alloc((size_t)NN * 256 * 2);
    __bf16* ngh  = (__bf16*)alloc((size_t)NN * 256 * 2);
    __bf16* ngl  = (__bf16*)alloc((size_t)NN * 256 * 2);
    // packed weights: node (hi/lo pairs)
    __bf16* wpn1h = (__bf16*)alloc((size_t)512 * 256 * 2);
    __bf16* wpn1l = (__bf16*)alloc((size_t)512 * 256 * 2);
    __bf16* wpn2h = (__bf16*)alloc((size_t)256 * 128 * 2);
    __bf16* wpn2l = (__bf16*)alloc((size_t)256 * 128 * 2);
    __bf16* wpn3h = (__bf16*)alloc((size_t)128 * 64 * 2);
    __bf16* wpn3l = (__bf16*)alloc((size_t)128 * 64 * 2);
    __bf16* wpp3h = (__bf16*)alloc((size_t)32 * 64 * 2);
    __bf16* wpp3l = (__bf16*)alloc((size_t)32 * 64 * 2);
    __bf16* wpenh = (__bf16*)alloc((size_t)128 * 256 * 2);
    __bf16* wpenl = (__bf16*)alloc((size_t)128 * 256 * 2);
    __bf16* wpsfh = (__bf16*)alloc((size_t)256 * 128 * 2);
    __bf16* wpsfl = (__bf16*)alloc((size_t)256 * 128 * 2);
    __bf16* wpngh = (__bf16*)alloc((size_t)256 * 128 * 2);
    __bf16* wpngl = (__bf16*)alloc((size_t)256 * 128 * 2);
    // packed weights: edge (single bf16, proven)
    __bf16* wpe1 = (__bf16*)alloc((size_t)256 * 256 * 2);
    __bf16* wpe2 = (__bf16*)alloc((size_t)256 * 128 * 2);
    __bf16* wpe3 = (__bf16*)alloc((size_t)128 * 64 * 2);

    hipMemsetAsync(counts, 0, (size_t)NN * sizeof(int), stream);

    // pack node weights (hi/lo)
    pack_w2_kernel<<<(512*256+255)/256, 256, 0, stream>>>(m2w1, wpn1h, wpn1l, 512, 256);
    pack_w2_kernel<<<(256*128+255)/256, 256, 0, stream>>>(m2w2, wpn2h, wpn2l, 256, 128);
    pack_w2_kernel<<<(128*64 +255)/256, 256, 0, stream>>>(m2w3, wpn3h, wpn3l, 128, 64);
    pack_w2_kernel<<<(32*64  +255)/256, 256, 0, stream>>>(m3w3, wpp3h, wpp3l, 32, 64);
    pack_w2_kernel<<<(128*256+255)/256, 256, 0, stream>>>(encw, wpenh, wpenl, 128, 256);
    pack_w2_kernel<<<(256*128+255)/256, 256, 0, stream>>>(wself, wpsfh, wpsfl, 256, 128);
    pack_w2_kernel<<<(256*128+255)/256, 256, 0, stream>>>(wneigh, wpngh, wpngl, 256, 128);
    // pack edge weights (single bf16)
    pack_w_kernel<<<(256*256+255)/256, 256, 0, stream>>>(ew1, wpe1, 256, 256);
    pack_w_kernel<<<(256*128+255)/256, 256, 0, stream>>>(ew2, wpe2, 256, 128);
    pack_w_kernel<<<(128*64 +255)/256, 256, 0, stream>>>(ew3, wpe3, 128, 64);

    // split x -> hi/lo
    split_bf16_kernel<<<(NN*512/8 + 255)/256, 256, 0, stream>>>(x, xh, xl, NN*512/8);

    const dim3 blk(256, 1, 1);
    const int MB = NN / 128;   // 102

    // node MLP branch (split-bf16 MFMA, fp32-equivalent)
    mmx_kernel<512,64,1,2,0><<<dim3(4, MB), blk, 0, stream>>>(xh, xl, wpn1h, wpn1l, m2b1, nullptr, t1h, t1l, 256);
    mmx_kernel<256,64,1,2,0><<<dim3(2, MB), blk, 0, stream>>>(t1h, t1l, wpn2h, wpn2l, m2b2, nullptr, t2h, t2l, 128);
    mmx_kernel<128,64,1,2,0><<<dim3(1, MB), blk, 0, stream>>>(t2h, t2l, wpn3h, wpn3l, m2b3, nullptr, hch, hcl, 128);

    // pose branch: tiny fp32 layers, split, then MFMA layer 3 into hcat cols 64..127
    gemm_kernel<1,0><<<dim3((NN+63)/64, 1), blk, 0, stream>>>(x_pose, 7,  m3w1, 16, m3b1, p1, 16, NN, 7, 16);
    gemm_kernel<1,0><<<dim3((NN+63)/64, 1), blk, 0, stream>>>(p1,    16,  m3w2, 32, m3b2, p2, 32, NN, 16, 32);
    split_bf16_kernel<<<(NN*32/8 + 255)/256, 256, 0, stream>>>(p2, p2h, p2l, NN*32/8);
    mmx_kernel< 32,64,1,2,0><<<dim3(1, MB), blk, 0, stream>>>(p2h, p2l, wpp3h, wpp3l, m3b3, nullptr, hch + 64, hcl + 64, 128);

    // encoder: fp32 xn (for neigh gather) + hi/lo xn (for SAGE, Y)
    mmx_kernel<128,64,1,3,0><<<dim3(4, MB), blk, 0, stream>>>(hch, hcl, wpenh, wpenl, encb, xn, xnh, xnl, 256);

    // Y = xn @ ew1 -> bf16 (node-level L1 via linearity)
    ygemm_kernel<256,128><<<dim3(2, MB), blk, 0, stream>>>(xnh, wpe1, Yb, 256);

    // fully fused edge pipeline: single dispatch over all edges
    edge_full_kernel<<<dim3(EE / 128), blk, 0, stream>>>(
        Yb, eb1, esrc, edst, wpe2, eb2, wpe3, eb3, ew4, eb4, out + E_OFF);

    // CSR build + gather-based segment mean
    hist_kernel<<<(EE + 255) / 256, 256, 0, stream>>>(edst, counts);
    scan_kernel<<<1, 1024, 0, stream>>>(counts, row_start, cursor);
    scatter_kernel<<<(EE + 255) / 256, 256, 0, stream>>>(esrc, edst, out + E_OFF, cursor, bucket);
    neigh_gather_kernel<<<NN, 256, 0, stream>>>(xn, bucket, row_start, counts, ngh, ngl);

    // SAGE: A_pre = xn@wself + sageb; A_pre += neigh@wneigh  (split MFMA, fp32 out)
    mmx_kernel<256,64,0,1,0><<<dim3(2, MB), blk, 0, stream>>>(xnh, xnl, wpsfh, wpsfl, sageb,  A_pre, nullptr, nullptr, 128);
    mmx_kernel<256,64,0,1,1><<<dim3(2, MB), blk, 0, stream>>>(ngh, ngl, wpngh, wpngl, nullptr, A_pre, nullptr, nullptr, 128);

    pose_kernel<<<B_, 128, 0, stream>>>(A_pre, decw, decb, out + POS_OFF, out + ORI_OFF);
    norm_kernel<<<B_, 128, 0, stream>>>(A_pre, out);
}

// Round 11
// 580.914 us; speedup vs baseline: 9.3537x; 1.0879x over previous
//
#include <hip/hip_runtime.h>
#include <math.h>

#define B_ 256
#define S_ 51
#define NN (B_*S_)            // 13056 nodes = 102*128 = 51*256
#define DEG_ 50
#define EE (NN*DEG_)          // 652800 edges = 5100*128
#define NEG_SLOPE 0.01f
#define EPS_ 1e-12f

#define A_SIZE (NN*128)
#define E_OFF  A_SIZE
#define POS_OFF (A_SIZE + EE)
#define ORI_OFF (POS_OFF + B_*3)

typedef __bf16 bf16x8 __attribute__((ext_vector_type(8)));
typedef __bf16 bf16x4 __attribute__((ext_vector_type(4)));
typedef float  f32x4  __attribute__((ext_vector_type(4)));

typedef __attribute__((address_space(1))) const void GVoid;
typedef __attribute__((address_space(3))) void LVoid;

__device__ __forceinline__ float act_apply(float v, int ACT) {
    if (ACT == 1) return fmaxf(v, 0.0f);
    if (ACT == 2) return v > 0.0f ? v : NEG_SLOPE * v;
    return v;
}

// ---------------- unified weight pack (all 10 weights in one dispatch) ----------------
// layout per weight: flat idx t = ((cf*KT + kt)*64 + lane)*8 + j
// holds W[kt*32 + (lane>>4)*8 + j][cf*16 + (lane&15)];  KT = K/32 (power of 2)
struct PackDesc { const float* src; __bf16* dh; __bf16* dl; int kts; int N; int start; };
struct PackArgs { PackDesc d[10]; int total; };

__global__ __launch_bounds__(256) void pack_all_kernel(PackArgs a)
{
    int idx = blockIdx.x * 256 + threadIdx.x;
    if (idx >= a.total) return;
    int e = 0;
    while (e < 9 && idx >= a.d[e + 1].start) ++e;
    PackDesc pd = a.d[e];
    int t = idx - pd.start;
    int j    = t & 7;
    int lane = (t >> 3) & 63;
    int rkt  = t >> 9;
    int kt = rkt & ((1 << pd.kts) - 1);
    int cf = rkt >> pd.kts;
    int k = kt * 32 + (lane >> 4) * 8 + j;
    int n = cf * 16 + (lane & 15);
    float v = pd.src[(size_t)k * pd.N + n];
    __bf16 h = (__bf16)v;
    pd.dh[t] = h;
    if (pd.dl) pd.dl[t] = (__bf16)(v - (float)h);
}

// ---------------- fused pose branch: p2 = relu(relu(xp@w1+b1)@w2+b2), hi/lo out ----------------
__global__ __launch_bounds__(256) void pose_fused_kernel(
    const float* __restrict__ xp,
    const float* __restrict__ w1, const float* __restrict__ b1,
    const float* __restrict__ w2, const float* __restrict__ b2,
    __bf16* __restrict__ p2h, __bf16* __restrict__ p2l)
{
    int n = blockIdx.x * 256 + threadIdx.x;
    if (n >= NN) return;
    float xv[7];
#pragma unroll
    for (int c = 0; c < 7; ++c) xv[c] = xp[(size_t)n * 7 + c];
    float p1[16];
#pragma unroll
    for (int j = 0; j < 16; ++j) {
        float s = b1[j];
#pragma unroll
        for (int c = 0; c < 7; ++c) s = fmaf(xv[c], w1[c * 16 + j], s);
        p1[j] = fmaxf(s, 0.0f);
    }
#pragma unroll
    for (int j = 0; j < 32; ++j) {
        float s = b2[j];
#pragma unroll
        for (int c = 0; c < 16; ++c) s = fmaf(p1[c], w2[c * 32 + j], s);
        s = fmaxf(s, 0.0f);
        __bf16 h = (__bf16)s;
        p2h[(size_t)n * 32 + j] = h;
        p2l[(size_t)n * 32 + j] = (__bf16)(s - (float)h);
    }
}

// ---------------- Y = A @ W -> bf16 out (node-level L1 via linearity) ----------------
template<int K, int BN>
__global__ __launch_bounds__(256) void ygemm_kernel(
    const __bf16* __restrict__ A, const __bf16* __restrict__ Wp,
    __bf16* __restrict__ C, int ldc)
{
    constexpr int NCF = BN / 16;
    __shared__ __bf16 As[128 * 32];

    const int tid  = threadIdx.x;
    const int lane = tid & 63;
    const int w    = tid >> 6;
    const int lg   = lane >> 4;
    const int li   = lane & 15;
    const int n_blk = blockIdx.x * BN;
    const int m_blk = blockIdx.y * 128;

    f32x4 acc[2][NCF];
#pragma unroll
    for (int mf = 0; mf < 2; ++mf)
#pragma unroll
        for (int cf = 0; cf < NCF; ++cf)
#pragma unroll
            for (int r = 0; r < 4; ++r) acc[mf][cf][r] = 0.0f;

    const __bf16* WpBase = Wp + ((size_t)(n_blk / 16) * (K / 32)) * 512 + (size_t)lane * 8;

    for (int kt = 0; kt < K / 32; ++kt) {
#pragma unroll
        for (int i = 0; i < 2; ++i) {
            int slot0 = i * 256 + w * 64;
            int s  = slot0 + lane;
            int r  = s >> 2;
            int sl = s & 3;
            int kb = sl ^ ((r >> 1) & 3);
            const __bf16* g = A + (size_t)(m_blk + r) * K + kt * 32 + kb * 8;
            __builtin_amdgcn_global_load_lds((GVoid*)g,
                                             (LVoid*)((char*)As + (size_t)slot0 * 16),
                                             16, 0, 0);
        }
        bf16x8 bf[NCF];
        const __bf16* Wb = WpBase + (size_t)kt * 512;
#pragma unroll
        for (int cf = 0; cf < NCF; ++cf)
            bf[cf] = *(const bf16x8*)(Wb + (size_t)cf * (K / 32) * 512);

        __syncthreads();

        bf16x8 af[2];
#pragma unroll
        for (int mf = 0; mf < 2; ++mf) {
            int row = w * 32 + mf * 16 + li;
            int sl  = lg ^ ((row >> 1) & 3);
            af[mf] = *(const bf16x8*)((const char*)As + (size_t)row * 64 + sl * 16);
        }
#pragma unroll
        for (int mf = 0; mf < 2; ++mf)
#pragma unroll
            for (int cf = 0; cf < NCF; ++cf)
                acc[mf][cf] = __builtin_amdgcn_mfma_f32_16x16x32_bf16(
                    af[mf], bf[cf], acc[mf][cf], 0, 0, 0);
        __syncthreads();
    }

#pragma unroll
    for (int mf = 0; mf < 2; ++mf) {
        int row0 = m_blk + w * 32 + mf * 16 + lg * 4;
#pragma unroll
        for (int cf = 0; cf < NCF; ++cf) {
            int col = n_blk + cf * 16 + li;
#pragma unroll
            for (int r = 0; r < 4; ++r)
                C[(size_t)(row0 + r) * ldc + col] = (__bf16)acc[mf][cf][r];
        }
    }
}

// ---------------- fully fused edge kernel (direct-gather, no A-staging) ----------------
// e = sigmoid( lrelu( lrelu( lrelu(Yb[src]-Yb[dst]+eb1) @ ew2 + eb2 ) @ ew3 + eb3 ) @ ew4 + eb4 )
// 128 edges/block, 4 waves. Each wave gathers its OWN rows' A-fragments directly
// from global into registers (no cross-wave reuse -> LDS staging was pure overhead).
// Only the L2->L3 relayout (S2) goes through LDS; single barrier.
__global__ __launch_bounds__(256) void edge_full_kernel(
    const __bf16* __restrict__ Yb, const float* __restrict__ eb1,
    const int* __restrict__ src, const int* __restrict__ dst,
    const __bf16* __restrict__ Wp2, const float* __restrict__ eb2,
    const __bf16* __restrict__ Wp3, const float* __restrict__ eb3,
    const float* __restrict__ ew4, const float* __restrict__ eb4,
    float* __restrict__ e_out)
{
    constexpr int NCF = 8;            // L2: K=256, N=128
    __shared__ __bf16 S2[128 * 128];  // 32 KB s2 tile (slot-swizzled)

    const int tid  = threadIdx.x;
    const int lane = tid & 63;
    const int w    = tid >> 6;
    const int lg   = lane >> 4;
    const int li   = lane & 15;
    const int m_blk = blockIdx.x * 128;

    // per-lane row pointers (each wave owns rows w*32 .. w*32+31)
    const int row0 = w * 32 + li;          // mf = 0
    const int row1 = row0 + 16;            // mf = 1
    const __bf16* ys0 = Yb + (size_t)src[m_blk + row0] * 256;
    const __bf16* yd0 = Yb + (size_t)dst[m_blk + row0] * 256;
    const __bf16* ys1 = Yb + (size_t)src[m_blk + row1] * 256;
    const __bf16* yd1 = Yb + (size_t)dst[m_blk + row1] * 256;
    const int ko = lg * 8;

    f32x4 acc[2][NCF];
#pragma unroll
    for (int mf = 0; mf < 2; ++mf)
#pragma unroll
        for (int cf = 0; cf < NCF; ++cf)
#pragma unroll
            for (int r = 0; r < 4; ++r) acc[mf][cf][r] = 0.0f;

    const __bf16* WpBase2 = Wp2 + (size_t)lane * 8;

#pragma unroll
    for (int kt = 0; kt < 8; ++kt) {
        const int k0 = kt * 32 + ko;
        // direct gather -> A fragments (row = li, k = lg*8+j)
        bf16x8 a0 = *(const bf16x8*)(ys0 + k0);
        bf16x8 b0 = *(const bf16x8*)(yd0 + k0);
        bf16x8 a1 = *(const bf16x8*)(ys1 + k0);
        bf16x8 b1 = *(const bf16x8*)(yd1 + k0);
        bf16x8 af0, af1;
#pragma unroll
        for (int j = 0; j < 8; ++j) {
            float bias = eb1[k0 + j];
            float v0 = (float)a0[j] - (float)b0[j] + bias;
            float v1 = (float)a1[j] - (float)b1[j] + bias;
            v0 = v0 > 0.0f ? v0 : NEG_SLOPE * v0;
            v1 = v1 > 0.0f ? v1 : NEG_SLOPE * v1;
            af0[j] = (__bf16)v0;
            af1[j] = (__bf16)v1;
        }
        const __bf16* Wb = WpBase2 + (size_t)kt * 512;
#pragma unroll
        for (int cf = 0; cf < NCF; ++cf) {
            bf16x8 bf = *(const bf16x8*)(Wb + (size_t)cf * 8 * 512);
            acc[0][cf] = __builtin_amdgcn_mfma_f32_16x16x32_bf16(af0, bf, acc[0][cf], 0, 0, 0);
            acc[1][cf] = __builtin_amdgcn_mfma_f32_16x16x32_bf16(af1, bf, acc[1][cf], 0, 0, 0);
        }
    }

    // ---- L2 epilogue -> S2 in LDS (slot-swizzle: sl ^= row&7) ----
#pragma unroll
    for (int mf = 0; mf < 2; ++mf) {
        int r0 = w * 32 + mf * 16 + lg * 4;
#pragma unroll
        for (int cf = 0; cf < NCF; ++cf) {
            int col = cf * 16 + li;
            float bv = eb2[col];
            int sl = col >> 3;
            int sb = col & 7;
#pragma unroll
            for (int r = 0; r < 4; ++r) {
                int row = r0 + r;
                float v = acc[mf][cf][r] + bv;
                v = v > 0.0f ? v : NEG_SLOPE * v;
                S2[row * 128 + ((sl ^ (row & 7)) << 3) + sb] = (__bf16)v;
            }
        }
    }
    __syncthreads();

    // ---- L3 stage: K=128, N=64, A from S2 (swizzled read) ----
    constexpr int NCF3 = 4;
    f32x4 acc3[2][NCF3];
#pragma unroll
    for (int mf = 0; mf < 2; ++mf)
#pragma unroll
        for (int cf = 0; cf < NCF3; ++cf)
#pragma unroll
            for (int r = 0; r < 4; ++r) acc3[mf][cf][r] = 0.0f;

    const __bf16* WpBase3 = Wp3 + (size_t)lane * 8;
#pragma unroll
    for (int kt = 0; kt < 4; ++kt) {
        bf16x8 af[2];
#pragma unroll
        for (int mf = 0; mf < 2; ++mf) {
            int row = w * 32 + mf * 16 + li;
            int sl  = (kt * 4 + lg) ^ (row & 7);
            af[mf] = *(const bf16x8*)&S2[row * 128 + (sl << 3)];
        }
        bf16x8 bf[NCF3];
        const __bf16* Wb = WpBase3 + (size_t)kt * 512;
#pragma unroll
        for (int cf = 0; cf < NCF3; ++cf)
            bf[cf] = *(const bf16x8*)(Wb + (size_t)cf * 4 * 512);
#pragma unroll
        for (int mf = 0; mf < 2; ++mf)
#pragma unroll
            for (int cf = 0; cf < NCF3; ++cf)
                acc3[mf][cf] = __builtin_amdgcn_mfma_f32_16x16x32_bf16(
                    af[mf], bf[cf], acc3[mf][cf], 0, 0, 0);
    }

    // ---- epilogue: s3 = lrelu(acc3 + eb3); dot ew4; 16-lane reduce; sigmoid ----
    float p[2][4];
#pragma unroll
    for (int mf = 0; mf < 2; ++mf)
#pragma unroll
        for (int r = 0; r < 4; ++r) p[mf][r] = 0.0f;
#pragma unroll
    for (int cf = 0; cf < NCF3; ++cf) {
        int col = cf * 16 + li;
        float b3 = eb3[col];
        float w4 = ew4[col];
#pragma unroll
        for (int mf = 0; mf < 2; ++mf)
#pragma unroll
            for (int r = 0; r < 4; ++r) {
                float v = acc3[mf][cf][r] + b3;
                v = v > 0.0f ? v : NEG_SLOPE * v;
                p[mf][r] = fmaf(v, w4, p[mf][r]);
            }
    }
#pragma unroll
    for (int mf = 0; mf < 2; ++mf)
#pragma unroll
        for (int r = 0; r < 4; ++r) {
#pragma unroll
            for (int m = 1; m < 16; m <<= 1)
                p[mf][r] += __shfl_xor(p[mf][r], m, 16);
        }
    if (li == 0) {
        float b4 = eb4[0];
#pragma unroll
        for (int mf = 0; mf < 2; ++mf)
#pragma unroll
            for (int r = 0; r < 4; ++r) {
                int ei = m_blk + w * 32 + mf * 16 + lg * 4 + r;
                float ev = 1.0f / (1.0f + expf(-(p[mf][r] + b4)));
                e_out[ei] = ev;
            }
    }
}

// ---------------- split-bf16 MFMA GEMM (fp32-equivalent precision, node path) ----------------
template<int K, int BN, int ACT, int OUT, int ACC>
__global__ __launch_bounds__(256) void mmx_kernel(
    const __bf16* __restrict__ Ah, const __bf16* __restrict__ Al,
    const __bf16* __restrict__ Wph, const __bf16* __restrict__ Wpl,
    const float* __restrict__ bias,
    float* __restrict__ Cf, __bf16* __restrict__ Ch, __bf16* __restrict__ Cl, int ldc)
{
    constexpr int NCF = BN / 16;
    __shared__ __bf16 AsH[128 * 32];
    __shared__ __bf16 AsL[128 * 32];

    const int tid  = threadIdx.x;
    const int lane = tid & 63;
    const int w    = tid >> 6;
    const int lg   = lane >> 4;
    const int li   = lane & 15;
    const int n_blk = blockIdx.x * BN;
    const int m_blk = blockIdx.y * 128;

    f32x4 acc[2][NCF];
#pragma unroll
    for (int mf = 0; mf < 2; ++mf)
#pragma unroll
        for (int cf = 0; cf < NCF; ++cf)
#pragma unroll
            for (int r = 0; r < 4; ++r) acc[mf][cf][r] = 0.0f;

    const size_t wbase = ((size_t)(n_blk / 16) * (K / 32)) * 512 + (size_t)lane * 8;

    for (int kt = 0; kt < K / 32; ++kt) {
#pragma unroll
        for (int i = 0; i < 2; ++i) {
            int slot0 = i * 256 + w * 64;
            int s  = slot0 + lane;
            int r  = s >> 2;
            int sl = s & 3;
            int kb = sl ^ ((r >> 1) & 3);
            size_t goff = (size_t)(m_blk + r) * K + kt * 32 + kb * 8;
            __builtin_amdgcn_global_load_lds((GVoid*)(Ah + goff),
                                             (LVoid*)((char*)AsH + (size_t)slot0 * 16),
                                             16, 0, 0);
            __builtin_amdgcn_global_load_lds((GVoid*)(Al + goff),
                                             (LVoid*)((char*)AsL + (size_t)slot0 * 16),
                                             16, 0, 0);
        }
        bf16x8 bfh[NCF], bfl[NCF];
        const size_t wo = wbase + (size_t)kt * 512;
#pragma unroll
        for (int cf = 0; cf < NCF; ++cf) {
            size_t o = wo + (size_t)cf * (K / 32) * 512;
            bfh[cf] = *(const bf16x8*)(Wph + o);
            bfl[cf] = *(const bf16x8*)(Wpl + o);
        }

        __syncthreads();

        bf16x8 afh[2], afl[2];
#pragma unroll
        for (int mf = 0; mf < 2; ++mf) {
            int row = w * 32 + mf * 16 + li;
            int sl  = lg ^ ((row >> 1) & 3);
            afh[mf] = *(const bf16x8*)((const char*)AsH + (size_t)row * 64 + sl * 16);
            afl[mf] = *(const bf16x8*)((const char*)AsL + (size_t)row * 64 + sl * 16);
        }
#pragma unroll
        for (int mf = 0; mf < 2; ++mf)
#pragma unroll
            for (int cf = 0; cf < NCF; ++cf) {
                acc[mf][cf] = __builtin_amdgcn_mfma_f32_16x16x32_bf16(
                    afh[mf], bfh[cf], acc[mf][cf], 0, 0, 0);
                acc[mf][cf] = __builtin_amdgcn_mfma_f32_16x16x32_bf16(
                    afh[mf], bfl[cf], acc[mf][cf], 0, 0, 0);
                acc[mf][cf] = __builtin_amdgcn_mfma_f32_16x16x32_bf16(
                    afl[mf], bfh[cf], acc[mf][cf], 0, 0, 0);
            }
        __syncthreads();
    }

    float bv[NCF];
#pragma unroll
    for (int cf = 0; cf < NCF; ++cf) bv[cf] = bias ? bias[n_blk + cf * 16 + li] : 0.0f;
#pragma unroll
    for (int mf = 0; mf < 2; ++mf) {
        int row0 = m_blk + w * 32 + mf * 16 + lg * 4;
#pragma unroll
        for (int cf = 0; cf < NCF; ++cf) {
            int col = n_blk + cf * 16 + li;
#pragma unroll
            for (int r = 0; r < 4; ++r) {
                float v = acc[mf][cf][r] + bv[cf];
                size_t idx = (size_t)(row0 + r) * ldc + col;
                if (ACC) v += Cf[idx];
                v = act_apply(v, ACT);
                if (OUT & 1) Cf[idx] = v;
                if (OUT & 2) {
                    __bf16 h = (__bf16)v;
                    Ch[idx] = h;
                    Cl[idx] = (__bf16)(v - (float)h);
                }
            }
        }
    }
}

// ---------------- fp32 -> hi/lo bf16 split (8 elems/thread) ----------------
__global__ __launch_bounds__(256) void split_bf16_kernel(
    const float* __restrict__ in, __bf16* __restrict__ hi, __bf16* __restrict__ lo, int n8)
{
    int i = blockIdx.x * 256 + threadIdx.x;
    if (i >= n8) return;
    const float4* p = (const float4*)in + (size_t)i * 2;
    float4 a = p[0], b = p[1];
    float v[8] = {a.x, a.y, a.z, a.w, b.x, b.y, b.z, b.w};
    bf16x8 oh, ol;
#pragma unroll
    for (int j = 0; j < 8; ++j) {
        __bf16 h = (__bf16)v[j];
        oh[j] = h;
        ol[j] = (__bf16)(v[j] - (float)h);
    }
    *(bf16x8*)(hi + (size_t)i * 8) = oh;
    *(bf16x8*)(lo + (size_t)i * 8) = ol;
}

// ---------------- CSR build: histogram / scan / scatter ----------------
__global__ __launch_bounds__(256) void hist_kernel(
    const int* __restrict__ dst, int* __restrict__ counts)
{
    int e = blockIdx.x * 256 + threadIdx.x;
    if (e < EE) atomicAdd(&counts[dst[e]], 1);
}

__global__ __launch_bounds__(1024) void scan_kernel(
    const int* __restrict__ counts, int* __restrict__ row_start, int* __restrict__ cursor)
{
    __shared__ int buf[1024];
    __shared__ int carry_s;
    int tid = threadIdx.x;
    if (tid == 0) carry_s = 0;
    __syncthreads();
    for (int t0 = 0; t0 < NN; t0 += 1024) {
        int i = t0 + tid;
        int v = (i < NN) ? counts[i] : 0;
        buf[tid] = v;
        __syncthreads();
        int c = carry_s;
        for (int o = 1; o < 1024; o <<= 1) {
            int u = (tid >= o) ? buf[tid - o] : 0;
            __syncthreads();
            buf[tid] += u;
            __syncthreads();
        }
        int excl = buf[tid] - v;
        if (i < NN) { row_start[i] = c + excl; cursor[i] = c + excl; }
        int total = buf[1023];
        __syncthreads();
        if (tid == 0) carry_s = c + total;
        __syncthreads();
    }
}

__global__ __launch_bounds__(256) void scatter_kernel(
    const int* __restrict__ src, const int* __restrict__ dst,
    const float* __restrict__ e_out, int* __restrict__ cursor, int2* __restrict__ bucket)
{
    int e = blockIdx.x * 256 + threadIdx.x;
    if (e >= EE) return;
    int d = dst[e];
    int pos = atomicAdd(&cursor[d], 1);
    bucket[pos] = make_int2(src[e], __float_as_int(e_out[e]));
}

// ---------------- neigh gather: one block per node, thread = feature ----------------
__global__ __launch_bounds__(256) void neigh_gather_kernel(
    const float* __restrict__ xn, const int2* __restrict__ bucket,
    const int* __restrict__ row_start, const int* __restrict__ counts,
    __bf16* __restrict__ nh, __bf16* __restrict__ nl)
{
    __shared__ int2 eb[128];
    int n = blockIdx.x;
    int f = threadIdx.x;
    int s0 = row_start[n];
    int cnt = counts[n];
    float acc = 0.0f;
    for (int t = 0; t < cnt; t += 128) {
        int m = (cnt - t < 128) ? (cnt - t) : 128;
        __syncthreads();
        if (f < m) eb[f] = bucket[s0 + t + f];
        __syncthreads();
        for (int i = 0; i < m; ++i) {
            int2 p = eb[i];
            acc = fmaf(__int_as_float(p.y), xn[(size_t)p.x * 256 + f], acc);
        }
    }
    float dv = (float)(cnt > 0 ? cnt : 1);
    float v = acc / dv;
    __bf16 h = (__bf16)v;
    nh[(size_t)n * 256 + f] = h;
    nl[(size_t)n * 256 + f] = (__bf16)(v - (float)h);
}

// ---------------- pose head ----------------
__global__ __launch_bounds__(128) void pose_kernel(
    const float* __restrict__ A_pre, const float* __restrict__ decw,
    const float* __restrict__ decb, float* __restrict__ pos, float* __restrict__ ori)
{
    __shared__ float arow[128];
    int b = blockIdx.x;
    arow[threadIdx.x] = A_pre[(size_t)(b * S_) * 128 + threadIdx.x];
    __syncthreads();
    int t = threadIdx.x;
    if (t < 7) {
        float s = decb[t];
        for (int c = 0; c < 128; ++c) s = fmaf(arow[c], decw[c * 7 + t], s);
        if (t < 3) pos[b * 3 + t] = s;
        else       ori[b * 4 + (t - 3)] = s;
    }
}

// ---------------- A = lrelu(A_pre); A /= max(||A||_S, eps) ----------------
__global__ __launch_bounds__(128) void norm_kernel(
    const float* __restrict__ A_pre, float* __restrict__ out)
{
    int b = blockIdx.x;
    int c = threadIdx.x;
    size_t base = (size_t)b * S_ * 128 + c;
    float ss = 0.0f;
    for (int s = 0; s < S_; ++s) {
        float v = A_pre[base + (size_t)s * 128];
        v = v > 0.0f ? v : NEG_SLOPE * v;
        ss = fmaf(v, v, ss);
    }
    float nrm = fmaxf(sqrtf(ss), EPS_);
    float inv = 1.0f / nrm;
    for (int s = 0; s < S_; ++s) {
        float v = A_pre[base + (size_t)s * 128];
        v = v > 0.0f ? v : NEG_SLOPE * v;
        out[base + (size_t)s * 128] = v * inv;
    }
}

extern "C" void kernel_launch(void* const* d_in, const int* in_sizes, int n_in,
                              void* d_out, int out_size, void* d_ws, size_t ws_size,
                              hipStream_t stream) {
    const float* x      = (const float*)d_in[0];
    const float* x_pose = (const float*)d_in[1];
    const float* m2w1 = (const float*)d_in[2];
    const float* m2b1 = (const float*)d_in[3];
    const float* m2w2 = (const float*)d_in[4];
    const float* m2b2 = (const float*)d_in[5];
    const float* m2w3 = (const float*)d_in[6];
    const float* m2b3 = (const float*)d_in[7];
    const float* m3w1 = (const float*)d_in[8];
    const float* m3b1 = (const float*)d_in[9];
    const float* m3w2 = (const float*)d_in[10];
    const float* m3b2 = (const float*)d_in[11];
    const float* m3w3 = (const float*)d_in[12];
    const float* m3b3 = (const float*)d_in[13];
    const float* encw = (const float*)d_in[14];
    const float* encb = (const float*)d_in[15];
    const float* ew1  = (const float*)d_in[16];
    const float* eb1  = (const float*)d_in[17];
    const float* ew2  = (const float*)d_in[18];
    const float* eb2  = (const float*)d_in[19];
    const float* ew3  = (const float*)d_in[20];
    const float* eb3  = (const float*)d_in[21];
    const float* ew4  = (const float*)d_in[22];
    const float* eb4  = (const float*)d_in[23];
    const float* wself  = (const float*)d_in[24];
    const float* wneigh = (const float*)d_in[25];
    const float* sageb  = (const float*)d_in[26];
    const float* decw = (const float*)d_in[27];
    const float* decb = (const float*)d_in[28];
    const int* esrc = (const int*)d_in[29];
    const int* edst = (const int*)d_in[30];
    float* out = (float*)d_out;

    // ---- workspace layout (byte allocator, 16B aligned) ----
    char* base = (char*)d_ws;
    size_t off = 0;
    auto alloc = [&](size_t bytes) { char* p = base + off; off += (bytes + 15) & ~15ULL; return p; };
    // fp32 buffers
    float* xn        = (float*)alloc((size_t)NN * 256 * 4);
    float* A_pre     = (float*)alloc((size_t)NN * 128 * 4);
    // CSR buffers
    int*  counts    = (int*)alloc((size_t)NN * 4);
    int*  row_start = (int*)alloc((size_t)NN * 4);
    int*  cursor    = (int*)alloc((size_t)NN * 4);
    int2* bucket    = (int2*)alloc((size_t)EE * 8);
    // bf16 buffers
    __bf16* Yb   = (__bf16*)alloc((size_t)NN * 256 * 2);
    __bf16* xh   = (__bf16*)alloc((size_t)NN * 512 * 2);
    __bf16* xl   = (__bf16*)alloc((size_t)NN * 512 * 2);
    __bf16* t1h  = (__bf16*)alloc((size_t)NN * 256 * 2);
    __bf16* t1l  = (__bf16*)alloc((size_t)NN * 256 * 2);
    __bf16* t2h  = (__bf16*)alloc((size_t)NN * 128 * 2);
    __bf16* t2l  = (__bf16*)alloc((size_t)NN * 128 * 2);
    __bf16* hch  = (__bf16*)alloc((size_t)NN * 128 * 2);
    __bf16* hcl  = (__bf16*)alloc((size_t)NN * 128 * 2);
    __bf16* p2h  = (__bf16*)alloc((size_t)NN * 32 * 2);
    __bf16* p2l  = (__bf16*)alloc((size_t)NN * 32 * 2);
    __bf16* xnh  = (__bf16*)alloc((size_t)NN * 256 * 2);
    __bf16* xnl  = (__bf16*)alloc((size_t)NN * 256 * 2);
    __bf16* ngh  = (__bf16*)alloc((size_t)NN * 256 * 2);
    __bf16* ngl  = (__bf16*)alloc((size_t)NN * 256 * 2);
    // packed weights: node (hi/lo pairs)
    __bf16* wpn1h = (__bf16*)alloc((size_t)512 * 256 * 2);
    __bf16* wpn1l = (__bf16*)alloc((size_t)512 * 256 * 2);
    __bf16* wpn2h = (__bf16*)alloc((size_t)256 * 128 * 2);
    __bf16* wpn2l = (__bf16*)alloc((size_t)256 * 128 * 2);
    __bf16* wpn3h = (__bf16*)alloc((size_t)128 * 64 * 2);
    __bf16* wpn3l = (__bf16*)alloc((size_t)128 * 64 * 2);
    __bf16* wpp3h = (__bf16*)alloc((size_t)32 * 64 * 2);
    __bf16* wpp3l = (__bf16*)alloc((size_t)32 * 64 * 2);
    __bf16* wpenh = (__bf16*)alloc((size_t)128 * 256 * 2);
    __bf16* wpenl = (__bf16*)alloc((size_t)128 * 256 * 2);
    __bf16* wpsfh = (__bf16*)alloc((size_t)256 * 128 * 2);
    __bf16* wpsfl = (__bf16*)alloc((size_t)256 * 128 * 2);
    __bf16* wpngh = (__bf16*)alloc((size_t)256 * 128 * 2);
    __bf16* wpngl = (__bf16*)alloc((size_t)256 * 128 * 2);
    // packed weights: edge (single bf16)
    __bf16* wpe1 = (__bf16*)alloc((size_t)256 * 256 * 2);
    __bf16* wpe2 = (__bf16*)alloc((size_t)256 * 128 * 2);
    __bf16* wpe3 = (__bf16*)alloc((size_t)128 * 64 * 2);

    hipMemsetAsync(counts, 0, (size_t)NN * sizeof(int), stream);

    // ---- unified weight pack: one dispatch for all 10 weights ----
    PackArgs pa;
    int st = 0;
    auto addp = [&](int i, const float* s, __bf16* dh, __bf16* dl, int K, int N) {
        int kts = 0;
        while ((32 << kts) < K) ++kts;   // log2(K/32)
        pa.d[i] = PackDesc{s, dh, dl, kts, N, st};
        st += K * N;
    };
    addp(0, m2w1,  wpn1h, wpn1l, 512, 256);
    addp(1, m2w2,  wpn2h, wpn2l, 256, 128);
    addp(2, m2w3,  wpn3h, wpn3l, 128, 64);
    addp(3, m3w3,  wpp3h, wpp3l, 32, 64);
    addp(4, encw,  wpenh, wpenl, 128, 256);
    addp(5, wself, wpsfh, wpsfl, 256, 128);
    addp(6, wneigh,wpngh, wpngl, 256, 128);
    addp(7, ew1,   wpe1,  nullptr, 256, 256);
    addp(8, ew2,   wpe2,  nullptr, 256, 128);
    addp(9, ew3,   wpe3,  nullptr, 128, 64);
    pa.total = st;
    pack_all_kernel<<<(st + 255) / 256, 256, 0, stream>>>(pa);

    // split x -> hi/lo ; fused pose branch
    split_bf16_kernel<<<(NN*512/8 + 255)/256, 256, 0, stream>>>(x, xh, xl, NN*512/8);
    pose_fused_kernel<<<NN / 256, 256, 0, stream>>>(x_pose, m3w1, m3b1, m3w2, m3b2, p2h, p2l);

    const dim3 blk(256, 1, 1);
    const int MB = NN / 128;   // 102

    // node MLP branch (split-bf16 MFMA, fp32-equivalent)
    mmx_kernel<512,64,1,2,0><<<dim3(4, MB), blk, 0, stream>>>(xh, xl, wpn1h, wpn1l, m2b1, nullptr, t1h, t1l, 256);
    mmx_kernel<256,64,1,2,0><<<dim3(2, MB), blk, 0, stream>>>(t1h, t1l, wpn2h, wpn2l, m2b2, nullptr, t2h, t2l, 128);
    mmx_kernel<128,64,1,2,0><<<dim3(1, MB), blk, 0, stream>>>(t2h, t2l, wpn3h, wpn3l, m2b3, nullptr, hch, hcl, 128);
    mmx_kernel< 32,64,1,2,0><<<dim3(1, MB), blk, 0, stream>>>(p2h, p2l, wpp3h, wpp3l, m3b3, nullptr, hch + 64, hcl + 64, 128);

    // encoder: fp32 xn (for neigh gather) + hi/lo xn (for SAGE, Y)
    mmx_kernel<128,64,1,3,0><<<dim3(4, MB), blk, 0, stream>>>(hch, hcl, wpenh, wpenl, encb, xn, xnh, xnl, 256);

    // Y = xn @ ew1 -> bf16 (node-level L1 via linearity)
    ygemm_kernel<256,128><<<dim3(2, MB), blk, 0, stream>>>(xnh, wpe1, Yb, 256);

    // fully fused edge pipeline: single dispatch, direct-gather A-fragments
    edge_full_kernel<<<dim3(EE / 128), blk, 0, stream>>>(
        Yb, eb1, esrc, edst, wpe2, eb2, wpe3, eb3, ew4, eb4, out + E_OFF);

    // CSR build + gather-based segment mean
    hist_kernel<<<(EE + 255) / 256, 256, 0, stream>>>(edst, counts);
    scan_kernel<<<1, 1024, 0, stream>>>(counts, row_start, cursor);
    scatter_kernel<<<(EE + 255) / 256, 256, 0, stream>>>(esrc, edst, out + E_OFF, cursor, bucket);
    neigh_gather_kernel<<<NN, 256, 0, stream>>>(xn, bucket, row_start, counts, ngh, ngl);

    // SAGE: A_pre = xn@wself + sageb; A_pre += neigh@wneigh  (split MFMA, fp32 out)
    mmx_kernel<256,64,0,1,0><<<dim3(2, MB), blk, 0, stream>>>(xnh, xnl, wpsfh, wpsfl, sageb,  A_pre, nullptr, nullptr, 128);
    mmx_kernel<256,64,0,1,1><<<dim3(2, MB), blk, 0, stream>>>(ngh, ngl, wpngh, wpngl, nullptr, A_pre, nullptr, nullptr, 128);

    pose_kernel<<<B_, 128, 0, stream>>>(A_pre, decw, decb, out + POS_OFF, out + ORI_OFF);
    norm_kernel<<<B_, 128, 0, stream>>>(A_pre, out);
}